// Round 1
// baseline (919.740 us; speedup 1.0000x reference)
//
#include <hip/hip_runtime.h>
#include <hip/hip_fp16.h>

// UnifiedTransformerBlock on MI355X.
// Pre-gating path in split-fp16 (fp32-class precision, needed so MoE top-2
// selection matches the np reference).  MoE FFN routed, plain fp16 MFMA.
// Workspace need: ~265 MB (aliased phases).

typedef _Float16 half8 __attribute__((ext_vector_type(8)));
typedef float f32x4 __attribute__((ext_vector_type(4)));

#define DI __device__ __forceinline__

union H8 { uint u[4]; half8 h; };

struct Desc { int e, base, rows; };

// ---------- split-fp16 packing: value ~= hi + lo * 2^-11 ----------
DI uint pack_split(float v) {
    __half hh = __float2half(v);
    float hf = __half2float(hh);
    __half ll = __float2half((v - hf) * 2048.0f);
    return (uint)__half_as_ushort(hh) | ((uint)__half_as_ushort(ll) << 16);
}

DI void unpk(uint4 r0, uint4 r1, H8 &hi, H8 &lo) {
    hi.u[0] = (r0.x & 0xffffu) | (r0.y << 16);
    hi.u[1] = (r0.z & 0xffffu) | (r0.w << 16);
    hi.u[2] = (r1.x & 0xffffu) | (r1.y << 16);
    hi.u[3] = (r1.z & 0xffffu) | (r1.w << 16);
    lo.u[0] = (r0.x >> 16) | (r0.y & 0xffff0000u);
    lo.u[1] = (r0.z >> 16) | (r0.w & 0xffff0000u);
    lo.u[2] = (r1.x >> 16) | (r1.y & 0xffff0000u);
    lo.u[3] = (r1.z >> 16) | (r1.w & 0xffff0000u);
}

DI float blockReduceSum(float v, float* red) {
#pragma unroll
    for (int m = 32; m; m >>= 1) v += __shfl_xor(v, m);
    int w = threadIdx.x >> 6;
    if ((threadIdx.x & 63) == 0) red[w] = v;
    __syncthreads();
    v = red[0] + red[1] + red[2] + red[3];
    __syncthreads();
    return v;
}

// ---------- split-fp16 GEMM: C = alpha * A(MxK) * B^T(NxK) [+ resid] ----------
// A,B packed u32 (hi|lo fp16).  EPI: 0=f32 store, 1=pack-split store into o
// with per-head addressing, 2=f32 + residual.
enum { EPI_F32 = 0, EPI_PACK_O = 1, EPI_RESID = 2 };

template<int WM, int WN, int FM, int FN, int EPI>
__global__ __launch_bounds__(256, 2)
void k_gemm_pk(const uint* __restrict__ A, int lda, long sA,
               const uint* __restrict__ B, int ldb, long sB,
               void* __restrict__ Cv, int ldc, long sC,
               int M, int N, int K, float alpha,
               const float* __restrict__ resid, int bh0)
{
    constexpr int BM = WM * FM * 16, BN = WN * FN * 16;
    constexpr int PITCH = 36;                  // 32 k-elems + 4 pad (uint)
    __shared__ uint As[BM * PITCH];
    __shared__ uint Bs[BN * PITCH];
    const int tid = threadIdx.x;
    const int lane = tid & 63, w = tid >> 6;
    const int wm = w / WN, wn = w % WN;
    const int m0 = blockIdx.x * BM, n0 = blockIdx.y * BN;
    const int z = blockIdx.z;
    A += (long)z * sA; B += (long)z * sB;

    f32x4 acc0[FM][FN] = {}; f32x4 acc1[FM][FN] = {};

    for (int k0 = 0; k0 < K; k0 += 32) {
        __syncthreads();
#pragma unroll
        for (int it = 0; it < BM / 32; ++it) {
            int c = it * 256 + tid, row = c >> 3, kg = c & 7;
            int gr = m0 + row;
            uint4 v = make_uint4(0, 0, 0, 0);
            if (gr < M) v = *(const uint4*)(A + (long)gr * lda + k0 + kg * 4);
            *(uint4*)&As[row * PITCH + kg * 4] = v;
        }
#pragma unroll
        for (int it = 0; it < BN / 32; ++it) {
            int c = it * 256 + tid, row = c >> 3, kg = c & 7;
            int gr = n0 + row;
            uint4 v = make_uint4(0, 0, 0, 0);
            if (gr < N) v = *(const uint4*)(B + (long)gr * ldb + k0 + kg * 4);
            *(uint4*)&Bs[row * PITCH + kg * 4] = v;
        }
        __syncthreads();
        H8 ah[FM], al[FM];
#pragma unroll
        for (int i = 0; i < FM; ++i) {
            const uint* p = &As[(wm * FM * 16 + i * 16 + (lane & 15)) * PITCH + (lane >> 4) * 8];
            unpk(*(const uint4*)p, *(const uint4*)(p + 4), ah[i], al[i]);
        }
#pragma unroll
        for (int n = 0; n < FN; ++n) {
            const uint* p = &Bs[(wn * FN * 16 + n * 16 + (lane & 15)) * PITCH + (lane >> 4) * 8];
            H8 bh_, bl_;
            unpk(*(const uint4*)p, *(const uint4*)(p + 4), bh_, bl_);
#pragma unroll
            for (int i = 0; i < FM; ++i) {
                acc0[i][n] = __builtin_amdgcn_mfma_f32_16x16x32_f16(ah[i].h, bh_.h, acc0[i][n], 0, 0, 0);
                acc1[i][n] = __builtin_amdgcn_mfma_f32_16x16x32_f16(ah[i].h, bl_.h, acc1[i][n], 0, 0, 0);
                acc1[i][n] = __builtin_amdgcn_mfma_f32_16x16x32_f16(al[i].h, bh_.h, acc1[i][n], 0, 0, 0);
            }
        }
    }

    float* Cf = nullptr; uint* Cu = nullptr;
    if constexpr (EPI == EPI_PACK_O) {
        int bh = bh0 + z;
        Cu = (uint*)Cv + (long)(bh >> 4) * 1048576 + (bh & 15) * 64;
    } else {
        Cf = (float*)Cv + (long)z * sC;
    }
#pragma unroll
    for (int i = 0; i < FM; ++i)
#pragma unroll
    for (int n = 0; n < FN; ++n)
#pragma unroll
    for (int j = 0; j < 4; ++j) {
        float v = (acc0[i][n][j] + acc1[i][n][j] * (1.0f / 2048.0f)) * alpha;
        int gm = m0 + wm * FM * 16 + i * 16 + (lane >> 4) * 4 + j;
        int gn = n0 + wn * FN * 16 + n * 16 + (lane & 15);
        if (gm < M && gn < N) {
            if constexpr (EPI == EPI_F32)
                Cf[(long)gm * ldc + gn] = v;
            else if constexpr (EPI == EPI_RESID)
                Cf[(long)gm * ldc + gn] = v + resid[(long)gm * ldc + gn];
            else
                Cu[(long)gm * ldc + gn] = pack_split(v);
        }
    }
}

// ---------- plain fp16 MoE grouped GEMM (desc-driven, 128x128 tile) ----------
template<bool GATHER, bool OUTHALF>
__global__ __launch_bounds__(256, 2)
void k_gemm_moe(const __half* __restrict__ A, int lda, const int* __restrict__ rowidx,
                const Desc* __restrict__ desc, const int* __restrict__ ntiles,
                const __half* __restrict__ Bbase, long sB, int ldb,
                void* __restrict__ Cv, int ldc, int N, int K)
{
    if ((int)blockIdx.x >= *ntiles) return;
    Desc d = desc[blockIdx.x];
    const __half* Bp = Bbase + (long)d.e * sB;
    constexpr int PITCH = 40;                  // halves: 32 + 8 pad
    __shared__ __half As[128 * PITCH];
    __shared__ __half Bs[128 * PITCH];
    const int tid = threadIdx.x, lane = tid & 63, w = tid >> 6;
    const int wm = w >> 1, wn = w & 1;
    const int n0 = blockIdx.y * 128;

    f32x4 acc[4][4] = {};
    for (int k0 = 0; k0 < K; k0 += 32) {
        __syncthreads();
#pragma unroll
        for (int it = 0; it < 2; ++it) {
            int c = it * 256 + tid, row = c >> 2, kg = c & 3;
            uint4 v = make_uint4(0, 0, 0, 0);
            if constexpr (GATHER) {
                if (row < d.rows) {
                    int ar = rowidx[d.base + row];
                    v = *(const uint4*)(A + (long)ar * lda + k0 + kg * 8);
                }
            } else {
                v = *(const uint4*)(A + (long)(d.base + row) * lda + k0 + kg * 8);
            }
            *(uint4*)&As[row * PITCH + kg * 8] = v;
        }
#pragma unroll
        for (int it = 0; it < 2; ++it) {
            int c = it * 256 + tid, row = c >> 2, kg = c & 3;
            uint4 v = *(const uint4*)(Bp + (long)(n0 + row) * ldb + k0 + kg * 8);
            *(uint4*)&Bs[row * PITCH + kg * 8] = v;
        }
        __syncthreads();
        half8 a[4];
#pragma unroll
        for (int i = 0; i < 4; ++i)
            a[i] = *(const half8*)&As[(wm * 64 + i * 16 + (lane & 15)) * PITCH + (lane >> 4) * 8];
#pragma unroll
        for (int n = 0; n < 4; ++n) {
            half8 b = *(const half8*)&Bs[(wn * 64 + n * 16 + (lane & 15)) * PITCH + (lane >> 4) * 8];
#pragma unroll
            for (int i = 0; i < 4; ++i)
                acc[i][n] = __builtin_amdgcn_mfma_f32_16x16x32_f16(a[i], b, acc[i][n], 0, 0, 0);
        }
    }
#pragma unroll
    for (int i = 0; i < 4; ++i)
#pragma unroll
    for (int n = 0; n < 4; ++n)
#pragma unroll
    for (int j = 0; j < 4; ++j) {
        int rl = wm * 64 + i * 16 + (lane >> 4) * 4 + j;
        int gn = n0 + wn * 64 + n * 16 + (lane & 15);
        float v = acc[i][n][j];
        if constexpr (OUTHALF) {
            if (rl >= d.rows) v = 0.0f;
            ((__half*)Cv)[(long)(d.base + rl) * ldc + gn] = __float2half(v);
        } else {
            ((float*)Cv)[(long)(d.base + rl) * ldc + gn] = v;
        }
    }
}

// ---------- transpose fp32 [R][C] -> [C][R], output packed u32 or fp16 ----------
template<bool PACK>
__global__ __launch_bounds__(256) void k_transpose(const float* __restrict__ src,
                                                   void* __restrict__ dst, int R, int C)
{
    src += (long)blockIdx.z * R * C;
    const long doff = (long)blockIdx.z * R * C;
    __shared__ float t[64][65];
    const int tid = threadIdx.x;
    const int c0 = blockIdx.x * 64, r0 = blockIdx.y * 64;
#pragma unroll
    for (int it = 0; it < 4; ++it) {
        int idx = it * 256 + tid;
        int r = idx >> 4, c4 = (idx & 15) * 4;
        float4 v = *(const float4*)(src + (long)(r0 + r) * C + c0 + c4);
        t[r][c4] = v.x; t[r][c4 + 1] = v.y; t[r][c4 + 2] = v.z; t[r][c4 + 3] = v.w;
    }
    __syncthreads();
    if constexpr (PACK) {
        uint* out = (uint*)dst + doff;
#pragma unroll
        for (int it = 0; it < 4; ++it) {
            int idx = it * 256 + tid;
            int orow = idx >> 4, oc = (idx & 15) * 4;
            uint4 v;
            v.x = pack_split(t[oc + 0][orow]);
            v.y = pack_split(t[oc + 1][orow]);
            v.z = pack_split(t[oc + 2][orow]);
            v.w = pack_split(t[oc + 3][orow]);
            *(uint4*)(out + (long)(c0 + orow) * R + r0 + oc) = v;
        }
    } else {
        __half* out = (__half*)dst + doff;
#pragma unroll
        for (int it = 0; it < 2; ++it) {
            int idx = it * 256 + tid;
            int orow = idx >> 3, oc = (idx & 7) * 8;
            H8 v;
#pragma unroll
            for (int j = 0; j < 8; ++j) v.h[j] = (_Float16)t[oc + j][orow];
            *(uint4*)(out + (long)(c0 + orow) * R + r0 + oc) = *(uint4*)&v;
        }
    }
}

// ---------- LayerNorm (D=1024, one block per row) ----------
template<int MODE> // 0: packed-split out; 1: f32 + fp16 out
__global__ __launch_bounds__(256) void k_ln(const float* __restrict__ X,
    const float* __restrict__ g, const float* __restrict__ bta,
    void* __restrict__ o1, void* __restrict__ o2)
{
    __shared__ float red[4];
    const long row = blockIdx.x;
    const float* xr = X + row * 1024;
    const int c = threadIdx.x * 4;
    float4 v = *(const float4*)(xr + c);
    float mu = blockReduceSum(v.x + v.y + v.z + v.w, red) * (1.0f / 1024.0f);
    float d0 = v.x - mu, d1 = v.y - mu, d2 = v.z - mu, d3 = v.w - mu;
    float var = blockReduceSum(d0 * d0 + d1 * d1 + d2 * d2 + d3 * d3, red) * (1.0f / 1024.0f);
    float rs = 1.0f / sqrtf(var + 1e-5f);
    float4 gv = *(const float4*)(g + c);
    float4 bv = *(const float4*)(bta + c);
    float y0 = d0 * rs * gv.x + bv.x;
    float y1 = d1 * rs * gv.y + bv.y;
    float y2 = d2 * rs * gv.z + bv.z;
    float y3 = d3 * rs * gv.w + bv.w;
    if constexpr (MODE == 0) {
        *(uint4*)((uint*)o1 + row * 1024 + c) =
            make_uint4(pack_split(y0), pack_split(y1), pack_split(y2), pack_split(y3));
    } else {
        *(float4*)((float*)o1 + row * 1024 + c) = make_float4(y0, y1, y2, y3);
        uint lo_ = (uint)__half_as_ushort(__float2half(y0)) | ((uint)__half_as_ushort(__float2half(y1)) << 16);
        uint hi_ = (uint)__half_as_ushort(__float2half(y2)) | ((uint)__half_as_ushort(__float2half(y3)) << 16);
        *(uint2*)((__half*)o2 + row * 1024 + c) = make_uint2(lo_, hi_);
    }
}

// ---------- RoPE cos/sin table (fp32, replicating np's fp32 quantization) ----------
__global__ __launch_bounds__(256) void k_rope_table(float* __restrict__ ct, float* __restrict__ st)
{
    int idx = blockIdx.x * 256 + threadIdx.x; // 32768 = 1024 t x 32 i
    int t = idx >> 5, i = idx & 31;
    float inv = 1.0f / (float)pow(10000.0, (double)i / 32.0);
    float ang = (float)t * inv;
    ct[idx] = cosf(ang);
    st[idx] = sinf(ang);
}

// ---------- qkv [2048][3072] f32 -> roped q,k packed [b,h,t,d]; v^T packed ----------
__global__ __launch_bounds__(256) void k_rearrange(const float* __restrict__ qkv,
    const float* __restrict__ ct, const float* __restrict__ st,
    uint* __restrict__ qp, uint* __restrict__ kp, uint* __restrict__ vtp)
{
    int gid = blockIdx.x * 256 + threadIdx.x; // 1,048,576
    int i = gid & 31;
    int h = (gid >> 5) & 15;
    int t = (gid >> 9) & 1023;
    int b = gid >> 19;
    long row = (long)(b * 1024 + t) * 3072;
    int col = h * 64 + 2 * i;
    float q0 = qkv[row + col], q1 = qkv[row + col + 1];
    float kk0 = qkv[row + 1024 + col], kk1 = qkv[row + 1024 + col + 1];
    float v0 = qkv[row + 2048 + col], v1 = qkv[row + 2048 + col + 1];
    float cv = ct[t * 32 + i], sv = st[t * 32 + i];
    long bh = b * 16 + h;
    long qo = (bh * 1024 + t) * 64 + 2 * i;
    qp[qo] = pack_split(q0 * cv - q1 * sv);
    qp[qo + 1] = pack_split(q1 * cv + q0 * sv);
    kp[qo] = pack_split(kk0 * cv - kk1 * sv);
    kp[qo + 1] = pack_split(kk1 * cv + kk0 * sv);
    long vo = (bh * 64 + 2 * i) * 1024 + t;
    vtp[vo] = pack_split(v0);
    vtp[vo + 1024] = pack_split(v1);
}

// ---------- row softmax over S (fp32), writes packed-split P in place ----------
__global__ __launch_bounds__(256) void k_softmax(float* __restrict__ S)
{
    __shared__ float red[4];
    const long row = blockIdx.x;
    float* sr = S + row * 1024;
    const int c = threadIdx.x * 4;
    float4 v = *(const float4*)(sr + c);
    float mx = fmaxf(fmaxf(v.x, v.y), fmaxf(v.z, v.w));
#pragma unroll
    for (int m = 32; m; m >>= 1) mx = fmaxf(mx, __shfl_xor(mx, m));
    int w = threadIdx.x >> 6;
    if ((threadIdx.x & 63) == 0) red[w] = mx;
    __syncthreads();
    mx = fmaxf(fmaxf(red[0], red[1]), fmaxf(red[2], red[3]));
    __syncthreads();
    float p0 = expf(v.x - mx), p1 = expf(v.y - mx), p2 = expf(v.z - mx), p3 = expf(v.w - mx);
    float s = blockReduceSum(p0 + p1 + p2 + p3, red);
    float inv = 1.0f / s;
    *(uint4*)((uint*)sr + c) =
        make_uint4(pack_split(p0 * inv), pack_split(p1 * inv), pack_split(p2 * inv), pack_split(p3 * inv));
}

// ---------- gating: fp32 scores, top-2 (lowest-index tie-break), atomics ----------
__global__ __launch_bounds__(256) void k_gate(const float* __restrict__ xn2,
    const float* __restrict__ gw, const float* __restrict__ eb,
    int* __restrict__ topidx, float* __restrict__ gates,
    int* __restrict__ cnt, float* __restrict__ probs)
{
    const int lane = threadIdx.x & 63, w = threadIdx.x >> 6;
    const int t = blockIdx.x * 4 + w;
    const float* xr = xn2 + (long)t * 1024;
    float sc[8] = {0, 0, 0, 0, 0, 0, 0, 0};
#pragma unroll
    for (int i = 0; i < 4; ++i) {
        int d = i * 256 + lane * 4;
        float4 xv = *(const float4*)(xr + d);
        float xa[4] = {xv.x, xv.y, xv.z, xv.w};
#pragma unroll
        for (int j = 0; j < 4; ++j) {
            float xx = xa[j];
            const float4* gp = (const float4*)(gw + (long)(d + j) * 8);
            float4 g0 = gp[0], g1 = gp[1];
            sc[0] += xx * g0.x; sc[1] += xx * g0.y; sc[2] += xx * g0.z; sc[3] += xx * g0.w;
            sc[4] += xx * g1.x; sc[5] += xx * g1.y; sc[6] += xx * g1.z; sc[7] += xx * g1.w;
        }
    }
#pragma unroll
    for (int e = 0; e < 8; ++e) {
#pragma unroll
        for (int m = 32; m; m >>= 1) sc[e] += __shfl_xor(sc[e], m);
        sc[e] += eb[e];
    }
    if (lane == 0) {
        int i1 = 0; float v1 = sc[0];
        for (int e = 1; e < 8; ++e) if (sc[e] > v1) { v1 = sc[e]; i1 = e; }
        int i2 = (i1 == 0) ? 1 : 0; float v2 = sc[i2];
        for (int e = 0; e < 8; ++e) if (e != i1 && sc[e] > v2) { v2 = sc[e]; i2 = e; }
        float e2 = expf(v2 - v1);
        gates[t * 2] = 1.0f / (1.0f + e2);
        gates[t * 2 + 1] = e2 / (1.0f + e2);
        topidx[t * 2] = i1; topidx[t * 2 + 1] = i2;
        atomicAdd(&cnt[i1], 1); atomicAdd(&cnt[i2], 1);
        float mxx = sc[0];
        for (int e = 1; e < 8; ++e) mxx = fmaxf(mxx, sc[e]);
        float se = 0.0f, pe[8];
        for (int e = 0; e < 8; ++e) { pe[e] = expf(sc[e] - mxx); se += pe[e]; }
        float inv = 1.0f / se;
        for (int e = 0; e < 8; ++e) atomicAdd(&probs[e], pe[e] * inv);
    }
}

// ---------- routing: padded per-expert bases, tile descs, permutation ----------
__global__ __launch_bounds__(256) void k_route(const int* __restrict__ cnt, const int* __restrict__ topidx,
    int* __restrict__ rowidx, int* __restrict__ invpos,
    int* __restrict__ ntiles, Desc* __restrict__ desc)
{
    __shared__ int base_s[8], fill[8];
    const int tid = threadIdx.x;
    if (tid < 8) fill[tid] = 0;
    if (tid == 0) {
        int nt = 0, running = 0;
        for (int e = 0; e < 8; ++e) {
            int ce = cnt[e];
            base_s[e] = running;
            int tl = (ce + 127) >> 7;
            for (int j = 0; j < tl; ++j) {
                desc[nt].e = e; desc[nt].base = running + j * 128;
                desc[nt].rows = min(128, ce - j * 128);
                ++nt;
            }
            running += tl * 128;
        }
        *ntiles = nt;
    }
    __syncthreads();
    for (int t = tid; t < 2048; t += 256) {
#pragma unroll
        for (int s = 0; s < 2; ++s) {
            int e = topidx[t * 2 + s];
            int p = base_s[e] + atomicAdd(&fill[e], 1);
            rowidx[p] = t;
            invpos[t * 2 + s] = p;
        }
    }
}

// ---------- SwiGLU activation: act = silu(h1)*h2 ----------
__global__ __launch_bounds__(256) void k_act(const __half* __restrict__ h, __half* __restrict__ act)
{
    long idx = (long)blockIdx.x * 256 + threadIdx.x;
    long row = idx >> 8; int c8 = (int)(idx & 255) * 8;
    H8 a, b2, o;
    *(uint4*)&a = *(const uint4*)(h + row * 4096 + c8);
    *(uint4*)&b2 = *(const uint4*)(h + row * 4096 + 2048 + c8);
#pragma unroll
    for (int j = 0; j < 8; ++j) {
        float x = (float)a.h[j], y = (float)b2.h[j];
        o.h[j] = (_Float16)(x / (1.0f + expf(-x)) * y);
    }
    *(uint4*)(act + row * 2048 + c8) = *(uint4*)&o;
}

// ---------- combine: out = x1 + g0*eo[p0] + g1*eo[p1] ----------
__global__ __launch_bounds__(256) void k_combine(const float* __restrict__ x1,
    const float* __restrict__ eo, const int* __restrict__ invpos,
    const float* __restrict__ gates, float* __restrict__ out)
{
    const int t = blockIdx.x, c = threadIdx.x * 4;
    float g0 = gates[t * 2], g1 = gates[t * 2 + 1];
    int p0 = invpos[t * 2], p1 = invpos[t * 2 + 1];
    float4 xv = *(const float4*)(x1 + (long)t * 1024 + c);
    float4 e0 = *(const float4*)(eo + (long)p0 * 1024 + c);
    float4 e1 = *(const float4*)(eo + (long)p1 * 1024 + c);
    float4 o;
    o.x = xv.x + g0 * e0.x + g1 * e1.x;
    o.y = xv.y + g0 * e0.y + g1 * e1.y;
    o.z = xv.z + g0 * e0.z + g1 * e1.z;
    o.w = xv.w + g0 * e0.w + g1 * e1.w;
    *(float4*)(out + (long)t * 1024 + c) = o;
}

__global__ __launch_bounds__(64) void k_loss(const int* __restrict__ cnt,
                                             const float* __restrict__ probs, float* __restrict__ out)
{
    if (threadIdx.x == 0) {
        float us = 0, ps = 0;
        for (int e = 0; e < 8; ++e) { us += (float)cnt[e]; ps += probs[e]; }
        float lb = 0;
        for (int e = 0; e < 8; ++e) lb += ((float)cnt[e] / us) * (probs[e] / ps);
        out[2097152] = lb * 8.0f;
    }
}

// =====================  launch  =====================
extern "C" void kernel_launch(void* const* d_in, const int* in_sizes, int n_in,
                              void* d_out, int out_size, void* d_ws, size_t ws_size,
                              hipStream_t stream)
{
    const float* x    = (const float*)d_in[0];
    const float* ln1g = (const float*)d_in[1];
    const float* ln1b = (const float*)d_in[2];
    const float* qkvw = (const float*)d_in[3];
    const float* outw = (const float*)d_in[4];
    const float* ln2g = (const float*)d_in[5];
    const float* ln2b = (const float*)d_in[6];
    const float* gw   = (const float*)d_in[7];
    const float* eb   = (const float*)d_in[8];
    const float* w1   = (const float*)d_in[9];
    const float* w2   = (const float*)d_in[10];
    float* out = (float*)d_out;
    char* ws = (char*)d_ws;

    // ---- workspace map (bytes); total need ~264.6 MB, region R aliased by phase
    constexpr size_t OFF_QKVWT = 0;                 // u32 [3072][1024]
    constexpr size_t OFF_OUTWT = 12582912;          // u32 [1024][1024]
    constexpr size_t OFF_XN1   = 16777216;          // u32 [2048][1024]
    constexpr size_t OFF_QPK   = 25165824;          // u32 [32][1024][64]
    constexpr size_t OFF_KPK   = 33554432;
    constexpr size_t OFF_VTPK  = 41943040;          // u32 [32][64][1024]
    constexpr size_t OFF_OPK   = 50331648;          // u32 [2048][1024]
    constexpr size_t OFF_X1    = 58720256;          // f32 [2048][1024]
    constexpr size_t OFF_XN2F  = 67108864;          // f32
    constexpr size_t OFF_XN2H  = 75497472;          // half [2048][1024]
    constexpr size_t OFF_RC    = 79691776;          // f32 [1024][32]
    constexpr size_t OFF_RS    = 79822848;
    constexpr size_t OFF_IDX   = 79953920;          // int [2048][2]
    constexpr size_t OFF_GATES = 79970304;          // f32 [2048][2]
    constexpr size_t OFF_INVP  = 79986688;          // int [2048][2]
    constexpr size_t OFF_ROWI  = 80003072;          // int [5120]
    constexpr size_t OFF_CNT   = 80023552;          // int [8]
    constexpr size_t OFF_PROBS = 80023584;          // f32 [8]
    constexpr size_t OFF_NT    = 80023616;          // int
    constexpr size_t OFF_DESC  = 80023680;          // Desc [40]
    constexpr size_t OFF_R     = 80024704;          // aliased region
    constexpr size_t OFF_QKVF  = OFF_R;                      // f32 [2048][3072] (phase 1)
    constexpr size_t OFF_S     = OFF_R;                      // f32 [32][1024][1024] (phase 2)
    constexpr size_t OFF_W1T   = OFF_R;                      // half [8][4096][1024] (phase 3)
    constexpr size_t OFF_W2T   = OFF_R + 67108864;           // half [8][1024][2048]
    constexpr size_t OFF_H     = OFF_R + 100663296;          // half [5120][4096]
    constexpr size_t OFF_ACT   = OFF_R + 142606336;          // half [5120][2048]
    constexpr size_t OFF_EO    = OFF_R + 163577856;          // f32 [5120][1024]

    uint*  qkvwt = (uint*)(ws + OFF_QKVWT);
    uint*  outwt = (uint*)(ws + OFF_OUTWT);
    uint*  xn1   = (uint*)(ws + OFF_XN1);
    uint*  qpk   = (uint*)(ws + OFF_QPK);
    uint*  kpk   = (uint*)(ws + OFF_KPK);
    uint*  vtpk  = (uint*)(ws + OFF_VTPK);
    uint*  opk   = (uint*)(ws + OFF_OPK);
    float* x1    = (float*)(ws + OFF_X1);
    float* xn2f  = (float*)(ws + OFF_XN2F);
    __half* xn2h = (__half*)(ws + OFF_XN2H);
    float* rc    = (float*)(ws + OFF_RC);
    float* rs    = (float*)(ws + OFF_RS);
    int*   idx   = (int*)(ws + OFF_IDX);
    float* gates = (float*)(ws + OFF_GATES);
    int*   invp  = (int*)(ws + OFF_INVP);
    int*   rowi  = (int*)(ws + OFF_ROWI);
    int*   cnt   = (int*)(ws + OFF_CNT);
    float* probs = (float*)(ws + OFF_PROBS);
    int*   nt    = (int*)(ws + OFF_NT);
    Desc*  desc  = (Desc*)(ws + OFF_DESC);
    float* qkvf  = (float*)(ws + OFF_QKVF);
    float* S     = (float*)(ws + OFF_S);
    __half* w1t  = (__half*)(ws + OFF_W1T);
    __half* w2t  = (__half*)(ws + OFF_W2T);
    __half* h    = (__half*)(ws + OFF_H);
    __half* act  = (__half*)(ws + OFF_ACT);
    float* eo    = (float*)(ws + OFF_EO);

    hipMemsetAsync(ws + OFF_CNT, 0, 64, stream);   // cnt + probs

    // weight transposes (pre-gating, packed split-fp16)
    k_transpose<true><<<dim3(48, 16, 1), 256, 0, stream>>>(qkvw, qkvwt, 1024, 3072);
    k_transpose<true><<<dim3(16, 16, 1), 256, 0, stream>>>(outw, outwt, 1024, 1024);
    k_rope_table<<<dim3(128), 256, 0, stream>>>(rc, rs);

    // LN1 -> packed xn1
    k_ln<0><<<dim3(2048), 256, 0, stream>>>(x, ln1g, ln1b, xn1, nullptr);

    // QKV GEMM: [2048x1024] x [1024x3072] -> f32
    k_gemm_pk<2, 2, 4, 4, EPI_F32><<<dim3(16, 24, 1), 256, 0, stream>>>(
        xn1, 1024, 0, qkvwt, 1024, 0, qkvf, 3072, 0, 2048, 3072, 1024, 1.0f, nullptr, 0);

    // RoPE + layout: q,k packed [bh][t][64]; v^T packed [bh][64][1024]
    k_rearrange<<<dim3(4096), 256, 0, stream>>>(qkvf, rc, rs, qpk, kpk, vtpk);

    // S = 0.125 * q k^T  (batched over 32 heads)
    k_gemm_pk<2, 2, 4, 4, EPI_F32><<<dim3(8, 8, 32), 256, 0, stream>>>(
        qpk, 64, 65536, kpk, 64, 65536, S, 1024, 1048576, 1024, 1024, 64, 0.125f, nullptr, 0);

    // softmax rows, pack P in place
    k_softmax<<<dim3(32768), 256, 0, stream>>>(S);

    // O = P V  -> o packed, head-interleaved layout
    k_gemm_pk<2, 2, 2, 2, EPI_PACK_O><<<dim3(16, 1, 32), 256, 0, stream>>>(
        (const uint*)S, 1024, 1048576, vtpk, 1024, 65536, opk, 1024, 0, 1024, 64, 1024, 1.0f, nullptr, 0);

    // x1 = x + o @ out_w
    k_gemm_pk<2, 2, 4, 4, EPI_RESID><<<dim3(16, 8, 1), 256, 0, stream>>>(
        opk, 1024, 0, outwt, 1024, 0, x1, 1024, 0, 2048, 1024, 1024, 1.0f, x, 0);

    // LN2 -> xn2 (f32 for gating, fp16 for MoE)
    k_ln<1><<<dim3(2048), 256, 0, stream>>>(x1, ln2g, ln2b, xn2f, xn2h);

    // gating + routing
    k_gate<<<dim3(512), 256, 0, stream>>>(xn2f, gw, eb, idx, gates, cnt, probs);
    k_route<<<dim3(1), 256, 0, stream>>>(cnt, idx, rowi, invp, nt, desc);

    // MoE weight transposes (region R now free of S)
    k_transpose<false><<<dim3(64, 16, 8), 256, 0, stream>>>(w1, w1t, 1024, 4096);
    k_transpose<false><<<dim3(16, 32, 8), 256, 0, stream>>>(w2, w2t, 2048, 1024);

    // MoE GEMM1 (gathered rows): h = xn2 @ w1[e]
    k_gemm_moe<true, true><<<dim3(40, 32, 1), 256, 0, stream>>>(
        xn2h, 1024, rowi, desc, nt, w1t, 4194304, 1024, h, 4096, 4096, 1024);

    // SwiGLU
    k_act<<<dim3(5120), 256, 0, stream>>>(h, act);

    // MoE GEMM2: eo = act @ w2[e]
    k_gemm_moe<false, false><<<dim3(40, 8, 1), 256, 0, stream>>>(
        act, 2048, nullptr, desc, nt, w2t, 2097152, 2048, eo, 1024, 1024, 2048);

    // combine + loss
    k_combine<<<dim3(2048), 256, 0, stream>>>(x1, eo, invp, gates, out);
    k_loss<<<dim3(1), 64, 0, stream>>>(cnt, probs, out);
}

// Round 2
// 667.252 us; speedup vs baseline: 1.3784x; 1.3784x over previous
//
#include <hip/hip_runtime.h>
#include <hip/hip_fp16.h>

// UnifiedTransformerBlock on MI355X.
// Pre-gating path in split-fp16 (fp32-class precision, needed so MoE top-2
// selection matches the np reference).  MoE FFN routed, plain fp16 MFMA.
// R2: removed device-wide atomics from gating (was 262us of serialized
// hot-address RMWs) -> per-block LDS partials + single-block reductions.

typedef _Float16 half8 __attribute__((ext_vector_type(8)));
typedef float f32x4 __attribute__((ext_vector_type(4)));

#define DI __device__ __forceinline__

union H8 { uint u[4]; half8 h; };

struct Desc { int e, base, rows; };

// ---------- split-fp16 packing: value ~= hi + lo * 2^-11 ----------
DI uint pack_split(float v) {
    __half hh = __float2half(v);
    float hf = __half2float(hh);
    __half ll = __float2half((v - hf) * 2048.0f);
    return (uint)__half_as_ushort(hh) | ((uint)__half_as_ushort(ll) << 16);
}

DI void unpk(uint4 r0, uint4 r1, H8 &hi, H8 &lo) {
    hi.u[0] = (r0.x & 0xffffu) | (r0.y << 16);
    hi.u[1] = (r0.z & 0xffffu) | (r0.w << 16);
    hi.u[2] = (r1.x & 0xffffu) | (r1.y << 16);
    hi.u[3] = (r1.z & 0xffffu) | (r1.w << 16);
    lo.u[0] = (r0.x >> 16) | (r0.y & 0xffff0000u);
    lo.u[1] = (r0.z >> 16) | (r0.w & 0xffff0000u);
    lo.u[2] = (r1.x >> 16) | (r1.w & 0xffff0000u);
    lo.u[2] = (r1.x >> 16) | (r1.y & 0xffff0000u);
    lo.u[3] = (r1.z >> 16) | (r1.w & 0xffff0000u);
}

DI float blockReduceSum(float v, float* red) {
#pragma unroll
    for (int m = 32; m; m >>= 1) v += __shfl_xor(v, m);
    int w = threadIdx.x >> 6;
    if ((threadIdx.x & 63) == 0) red[w] = v;
    __syncthreads();
    v = red[0] + red[1] + red[2] + red[3];
    __syncthreads();
    return v;
}

// ---------- split-fp16 GEMM: C = alpha * A(MxK) * B^T(NxK) [+ resid] ----------
enum { EPI_F32 = 0, EPI_PACK_O = 1, EPI_RESID = 2 };

template<int WM, int WN, int FM, int FN, int EPI>
__global__ __launch_bounds__(256, 2)
void k_gemm_pk(const uint* __restrict__ A, int lda, long sA,
               const uint* __restrict__ B, int ldb, long sB,
               void* __restrict__ Cv, int ldc, long sC,
               int M, int N, int K, float alpha,
               const float* __restrict__ resid, int bh0)
{
    constexpr int BM = WM * FM * 16, BN = WN * FN * 16;
    constexpr int PITCH = 36;                  // 32 k-elems + 4 pad (uint)
    __shared__ uint As[BM * PITCH];
    __shared__ uint Bs[BN * PITCH];
    const int tid = threadIdx.x;
    const int lane = tid & 63, w = tid >> 6;
    const int wm = w / WN, wn = w % WN;
    const int m0 = blockIdx.x * BM, n0 = blockIdx.y * BN;
    const int z = blockIdx.z;
    A += (long)z * sA; B += (long)z * sB;

    f32x4 acc0[FM][FN] = {}; f32x4 acc1[FM][FN] = {};

    for (int k0 = 0; k0 < K; k0 += 32) {
        __syncthreads();
#pragma unroll
        for (int it = 0; it < BM / 32; ++it) {
            int c = it * 256 + tid, row = c >> 3, kg = c & 7;
            int gr = m0 + row;
            uint4 v = make_uint4(0, 0, 0, 0);
            if (gr < M) v = *(const uint4*)(A + (long)gr * lda + k0 + kg * 4);
            *(uint4*)&As[row * PITCH + kg * 4] = v;
        }
#pragma unroll
        for (int it = 0; it < BN / 32; ++it) {
            int c = it * 256 + tid, row = c >> 3, kg = c & 7;
            int gr = n0 + row;
            uint4 v = make_uint4(0, 0, 0, 0);
            if (gr < N) v = *(const uint4*)(B + (long)gr * ldb + k0 + kg * 4);
            *(uint4*)&Bs[row * PITCH + kg * 4] = v;
        }
        __syncthreads();
        H8 ah[FM], al[FM];
#pragma unroll
        for (int i = 0; i < FM; ++i) {
            const uint* p = &As[(wm * FM * 16 + i * 16 + (lane & 15)) * PITCH + (lane >> 4) * 8];
            unpk(*(const uint4*)p, *(const uint4*)(p + 4), ah[i], al[i]);
        }
#pragma unroll
        for (int n = 0; n < FN; ++n) {
            const uint* p = &Bs[(wn * FN * 16 + n * 16 + (lane & 15)) * PITCH + (lane >> 4) * 8];
            H8 bh_, bl_;
            unpk(*(const uint4*)p, *(const uint4*)(p + 4), bh_, bl_);
#pragma unroll
            for (int i = 0; i < FM; ++i) {
                acc0[i][n] = __builtin_amdgcn_mfma_f32_16x16x32_f16(ah[i].h, bh_.h, acc0[i][n], 0, 0, 0);
                acc1[i][n] = __builtin_amdgcn_mfma_f32_16x16x32_f16(ah[i].h, bl_.h, acc1[i][n], 0, 0, 0);
                acc1[i][n] = __builtin_amdgcn_mfma_f32_16x16x32_f16(al[i].h, bh_.h, acc1[i][n], 0, 0, 0);
            }
        }
    }

    float* Cf = nullptr; uint* Cu = nullptr;
    if constexpr (EPI == EPI_PACK_O) {
        int bh = bh0 + z;
        Cu = (uint*)Cv + (long)(bh >> 4) * 1048576 + (bh & 15) * 64;
    } else {
        Cf = (float*)Cv + (long)z * sC;
    }
#pragma unroll
    for (int i = 0; i < FM; ++i)
#pragma unroll
    for (int n = 0; n < FN; ++n)
#pragma unroll
    for (int j = 0; j < 4; ++j) {
        float v = (acc0[i][n][j] + acc1[i][n][j] * (1.0f / 2048.0f)) * alpha;
        int gm = m0 + wm * FM * 16 + i * 16 + (lane >> 4) * 4 + j;
        int gn = n0 + wn * FN * 16 + n * 16 + (lane & 15);
        if (gm < M && gn < N) {
            if constexpr (EPI == EPI_F32)
                Cf[(long)gm * ldc + gn] = v;
            else if constexpr (EPI == EPI_RESID)
                Cf[(long)gm * ldc + gn] = v + resid[(long)gm * ldc + gn];
            else
                Cu[(long)gm * ldc + gn] = pack_split(v);
        }
    }
}

// ---------- plain fp16 MoE grouped GEMM (desc-driven, 128x128 tile) ----------
template<bool GATHER, bool OUTHALF>
__global__ __launch_bounds__(256, 2)
void k_gemm_moe(const __half* __restrict__ A, int lda, const int* __restrict__ rowidx,
                const Desc* __restrict__ desc, const int* __restrict__ ntiles,
                const __half* __restrict__ Bbase, long sB, int ldb,
                void* __restrict__ Cv, int ldc, int N, int K)
{
    if ((int)blockIdx.x >= *ntiles) return;
    Desc d = desc[blockIdx.x];
    const __half* Bp = Bbase + (long)d.e * sB;
    constexpr int PITCH = 40;                  // halves: 32 + 8 pad
    __shared__ __half As[128 * PITCH];
    __shared__ __half Bs[128 * PITCH];
    const int tid = threadIdx.x, lane = tid & 63, w = tid >> 6;
    const int wm = w >> 1, wn = w & 1;
    const int n0 = blockIdx.y * 128;

    f32x4 acc[4][4] = {};
    for (int k0 = 0; k0 < K; k0 += 32) {
        __syncthreads();
#pragma unroll
        for (int it = 0; it < 2; ++it) {
            int c = it * 256 + tid, row = c >> 2, kg = c & 3;
            uint4 v = make_uint4(0, 0, 0, 0);
            if constexpr (GATHER) {
                if (row < d.rows) {
                    int ar = rowidx[d.base + row];
                    v = *(const uint4*)(A + (long)ar * lda + k0 + kg * 8);
                }
            } else {
                v = *(const uint4*)(A + (long)(d.base + row) * lda + k0 + kg * 8);
            }
            *(uint4*)&As[row * PITCH + kg * 8] = v;
        }
#pragma unroll
        for (int it = 0; it < 2; ++it) {
            int c = it * 256 + tid, row = c >> 2, kg = c & 3;
            uint4 v = *(const uint4*)(Bp + (long)(n0 + row) * ldb + k0 + kg * 8);
            *(uint4*)&Bs[row * PITCH + kg * 8] = v;
        }
        __syncthreads();
        half8 a[4];
#pragma unroll
        for (int i = 0; i < 4; ++i)
            a[i] = *(const half8*)&As[(wm * 64 + i * 16 + (lane & 15)) * PITCH + (lane >> 4) * 8];
#pragma unroll
        for (int n = 0; n < 4; ++n) {
            half8 b = *(const half8*)&Bs[(wn * 64 + n * 16 + (lane & 15)) * PITCH + (lane >> 4) * 8];
#pragma unroll
            for (int i = 0; i < 4; ++i)
                acc[i][n] = __builtin_amdgcn_mfma_f32_16x16x32_f16(a[i], b, acc[i][n], 0, 0, 0);
        }
    }
#pragma unroll
    for (int i = 0; i < 4; ++i)
#pragma unroll
    for (int n = 0; n < 4; ++n)
#pragma unroll
    for (int j = 0; j < 4; ++j) {
        int rl = wm * 64 + i * 16 + (lane >> 4) * 4 + j;
        int gn = n0 + wn * 64 + n * 16 + (lane & 15);
        float v = acc[i][n][j];
        if constexpr (OUTHALF) {
            if (rl >= d.rows) v = 0.0f;
            ((__half*)Cv)[(long)(d.base + rl) * ldc + gn] = __float2half(v);
        } else {
            ((float*)Cv)[(long)(d.base + rl) * ldc + gn] = v;
        }
    }
}

// ---------- transpose fp32 [R][C] -> [C][R], output packed u32 or fp16 ----------
template<bool PACK>
__global__ __launch_bounds__(256) void k_transpose(const float* __restrict__ src,
                                                   void* __restrict__ dst, int R, int C)
{
    src += (long)blockIdx.z * R * C;
    const long doff = (long)blockIdx.z * R * C;
    __shared__ float t[64][65];
    const int tid = threadIdx.x;
    const int c0 = blockIdx.x * 64, r0 = blockIdx.y * 64;
#pragma unroll
    for (int it = 0; it < 4; ++it) {
        int idx = it * 256 + tid;
        int r = idx >> 4, c4 = (idx & 15) * 4;
        float4 v = *(const float4*)(src + (long)(r0 + r) * C + c0 + c4);
        t[r][c4] = v.x; t[r][c4 + 1] = v.y; t[r][c4 + 2] = v.z; t[r][c4 + 3] = v.w;
    }
    __syncthreads();
    if constexpr (PACK) {
        uint* out = (uint*)dst + doff;
#pragma unroll
        for (int it = 0; it < 4; ++it) {
            int idx = it * 256 + tid;
            int orow = idx >> 4, oc = (idx & 15) * 4;
            uint4 v;
            v.x = pack_split(t[oc + 0][orow]);
            v.y = pack_split(t[oc + 1][orow]);
            v.z = pack_split(t[oc + 2][orow]);
            v.w = pack_split(t[oc + 3][orow]);
            *(uint4*)(out + (long)(c0 + orow) * R + r0 + oc) = v;
        }
    } else {
        __half* out = (__half*)dst + doff;
#pragma unroll
        for (int it = 0; it < 2; ++it) {
            int idx = it * 256 + tid;
            int orow = idx >> 3, oc = (idx & 7) * 8;
            H8 v;
#pragma unroll
            for (int j = 0; j < 8; ++j) v.h[j] = (_Float16)t[oc + j][orow];
            *(uint4*)(out + (long)(c0 + orow) * R + r0 + oc) = *(uint4*)&v;
        }
    }
}

// ---------- LayerNorm (D=1024, one block per row) ----------
template<int MODE> // 0: packed-split out; 1: f32 + fp16 out
__global__ __launch_bounds__(256) void k_ln(const float* __restrict__ X,
    const float* __restrict__ g, const float* __restrict__ bta,
    void* __restrict__ o1, void* __restrict__ o2)
{
    __shared__ float red[4];
    const long row = blockIdx.x;
    const float* xr = X + row * 1024;
    const int c = threadIdx.x * 4;
    float4 v = *(const float4*)(xr + c);
    float mu = blockReduceSum(v.x + v.y + v.z + v.w, red) * (1.0f / 1024.0f);
    float d0 = v.x - mu, d1 = v.y - mu, d2 = v.z - mu, d3 = v.w - mu;
    float var = blockReduceSum(d0 * d0 + d1 * d1 + d2 * d2 + d3 * d3, red) * (1.0f / 1024.0f);
    float rs = 1.0f / sqrtf(var + 1e-5f);
    float4 gv = *(const float4*)(g + c);
    float4 bv = *(const float4*)(bta + c);
    float y0 = d0 * rs * gv.x + bv.x;
    float y1 = d1 * rs * gv.y + bv.y;
    float y2 = d2 * rs * gv.z + bv.z;
    float y3 = d3 * rs * gv.w + bv.w;
    if constexpr (MODE == 0) {
        *(uint4*)((uint*)o1 + row * 1024 + c) =
            make_uint4(pack_split(y0), pack_split(y1), pack_split(y2), pack_split(y3));
    } else {
        *(float4*)((float*)o1 + row * 1024 + c) = make_float4(y0, y1, y2, y3);
        uint lo_ = (uint)__half_as_ushort(__float2half(y0)) | ((uint)__half_as_ushort(__float2half(y1)) << 16);
        uint hi_ = (uint)__half_as_ushort(__float2half(y2)) | ((uint)__half_as_ushort(__float2half(y3)) << 16);
        *(uint2*)((__half*)o2 + row * 1024 + c) = make_uint2(lo_, hi_);
    }
}

// ---------- RoPE cos/sin table (fp32, replicating np's fp32 quantization) ----------
__global__ __launch_bounds__(256) void k_rope_table(float* __restrict__ ct, float* __restrict__ st)
{
    int idx = blockIdx.x * 256 + threadIdx.x; // 32768 = 1024 t x 32 i
    int t = idx >> 5, i = idx & 31;
    float inv = 1.0f / (float)pow(10000.0, (double)i / 32.0);
    float ang = (float)t * inv;
    ct[idx] = cosf(ang);
    st[idx] = sinf(ang);
}

// ---------- qkv [2048][3072] f32 -> roped q,k packed [b,h,t,d]; v^T packed ----------
__global__ __launch_bounds__(256) void k_rearrange(const float* __restrict__ qkv,
    const float* __restrict__ ct, const float* __restrict__ st,
    uint* __restrict__ qp, uint* __restrict__ kp, uint* __restrict__ vtp)
{
    int gid = blockIdx.x * 256 + threadIdx.x; // 1,048,576
    int i = gid & 31;
    int h = (gid >> 5) & 15;
    int t = (gid >> 9) & 1023;
    int b = gid >> 19;
    long row = (long)(b * 1024 + t) * 3072;
    int col = h * 64 + 2 * i;
    float q0 = qkv[row + col], q1 = qkv[row + col + 1];
    float kk0 = qkv[row + 1024 + col], kk1 = qkv[row + 1024 + col + 1];
    float v0 = qkv[row + 2048 + col], v1 = qkv[row + 2048 + col + 1];
    float cv = ct[t * 32 + i], sv = st[t * 32 + i];
    long bh = b * 16 + h;
    long qo = (bh * 1024 + t) * 64 + 2 * i;
    qp[qo] = pack_split(q0 * cv - q1 * sv);
    qp[qo + 1] = pack_split(q1 * cv + q0 * sv);
    kp[qo] = pack_split(kk0 * cv - kk1 * sv);
    kp[qo + 1] = pack_split(kk1 * cv + kk0 * sv);
    long vo = (bh * 64 + 2 * i) * 1024 + t;
    vtp[vo] = pack_split(v0);
    vtp[vo + 1024] = pack_split(v1);
}

// ---------- row softmax over S (fp32), writes packed-split P in place ----------
__global__ __launch_bounds__(256) void k_softmax(float* __restrict__ S)
{
    __shared__ float red[4];
    const long row = blockIdx.x;
    float* sr = S + row * 1024;
    const int c = threadIdx.x * 4;
    float4 v = *(const float4*)(sr + c);
    float mx = fmaxf(fmaxf(v.x, v.y), fmaxf(v.z, v.w));
#pragma unroll
    for (int m = 32; m; m >>= 1) mx = fmaxf(mx, __shfl_xor(mx, m));
    int w = threadIdx.x >> 6;
    if ((threadIdx.x & 63) == 0) red[w] = mx;
    __syncthreads();
    mx = fmaxf(fmaxf(red[0], red[1]), fmaxf(red[2], red[3]));
    __syncthreads();
    float p0 = expf(v.x - mx), p1 = expf(v.y - mx), p2 = expf(v.z - mx), p3 = expf(v.w - mx);
    float s = blockReduceSum(p0 + p1 + p2 + p3, red);
    float inv = 1.0f / s;
    *(uint4*)((uint*)sr + c) =
        make_uint4(pack_split(p0 * inv), pack_split(p1 * inv), pack_split(p2 * inv), pack_split(p3 * inv));
}

// ---------- gating: fp32 scores, top-2, NO global atomics ----------
// Per-block (4 tokens) softmax-prob partials -> pprob[block][8].
__global__ __launch_bounds__(256) void k_gate(const float* __restrict__ xn2,
    const float* __restrict__ gw, const float* __restrict__ eb,
    int* __restrict__ topidx, float* __restrict__ gates,
    float* __restrict__ pprob)
{
    __shared__ float pp[4][8];
    const int lane = threadIdx.x & 63, w = threadIdx.x >> 6;
    const int t = blockIdx.x * 4 + w;
    const float* xr = xn2 + (long)t * 1024;
    float sc[8] = {0, 0, 0, 0, 0, 0, 0, 0};
#pragma unroll
    for (int i = 0; i < 4; ++i) {
        int d = i * 256 + lane * 4;
        float4 xv = *(const float4*)(xr + d);
        float xa[4] = {xv.x, xv.y, xv.z, xv.w};
#pragma unroll
        for (int j = 0; j < 4; ++j) {
            float xx = xa[j];
            const float4* gp = (const float4*)(gw + (long)(d + j) * 8);
            float4 g0 = gp[0], g1 = gp[1];
            sc[0] += xx * g0.x; sc[1] += xx * g0.y; sc[2] += xx * g0.z; sc[3] += xx * g0.w;
            sc[4] += xx * g1.x; sc[5] += xx * g1.y; sc[6] += xx * g1.z; sc[7] += xx * g1.w;
        }
    }
#pragma unroll
    for (int e = 0; e < 8; ++e) {
#pragma unroll
        for (int m = 32; m; m >>= 1) sc[e] += __shfl_xor(sc[e], m);
        sc[e] += eb[e];
    }
    if (lane == 0) {
        int i1 = 0; float v1 = sc[0];
        for (int e = 1; e < 8; ++e) if (sc[e] > v1) { v1 = sc[e]; i1 = e; }
        int i2 = (i1 == 0) ? 1 : 0; float v2 = sc[i2];
        for (int e = 0; e < 8; ++e) if (e != i1 && sc[e] > v2) { v2 = sc[e]; i2 = e; }
        float e2 = expf(v2 - v1);
        gates[t * 2] = 1.0f / (1.0f + e2);
        gates[t * 2 + 1] = e2 / (1.0f + e2);
        topidx[t * 2] = i1; topidx[t * 2 + 1] = i2;
        float mxx = sc[0];
        for (int e = 1; e < 8; ++e) mxx = fmaxf(mxx, sc[e]);
        float se = 0.0f, pe[8];
        for (int e = 0; e < 8; ++e) { pe[e] = expf(sc[e] - mxx); se += pe[e]; }
        float inv = 1.0f / se;
        for (int e = 0; e < 8; ++e) pp[w][e] = pe[e] * inv;
    }
    __syncthreads();
    if (threadIdx.x < 8)
        pprob[(long)blockIdx.x * 8 + threadIdx.x] =
            pp[0][threadIdx.x] + pp[1][threadIdx.x] + pp[2][threadIdx.x] + pp[3][threadIdx.x];
}

// ---------- routing: LDS histogram + padded per-expert bases, descs, perm ----------
__global__ __launch_bounds__(256) void k_route(const int* __restrict__ topidx,
    int* __restrict__ rowidx, int* __restrict__ invpos,
    int* __restrict__ ntiles, Desc* __restrict__ desc, int* __restrict__ cnt)
{
    __shared__ int cnt_s[8], base_s[8], fill[8];
    const int tid = threadIdx.x;
    if (tid < 8) { cnt_s[tid] = 0; fill[tid] = 0; }
    __syncthreads();
    for (int i = tid; i < 4096; i += 256)
        atomicAdd(&cnt_s[topidx[i]], 1);
    __syncthreads();
    if (tid == 0) {
        int nt = 0, running = 0;
        for (int e = 0; e < 8; ++e) {
            int ce = cnt_s[e];
            cnt[e] = ce;
            base_s[e] = running;
            int tl = (ce + 127) >> 7;
            for (int j = 0; j < tl; ++j) {
                desc[nt].e = e; desc[nt].base = running + j * 128;
                desc[nt].rows = min(128, ce - j * 128);
                ++nt;
            }
            running += tl * 128;
        }
        *ntiles = nt;
    }
    __syncthreads();
    for (int t = tid; t < 2048; t += 256) {
#pragma unroll
        for (int s = 0; s < 2; ++s) {
            int e = topidx[t * 2 + s];
            int p = base_s[e] + atomicAdd(&fill[e], 1);
            rowidx[p] = t;
            invpos[t * 2 + s] = p;
        }
    }
}

// ---------- SwiGLU activation: act = silu(h1)*h2 ----------
__global__ __launch_bounds__(256) void k_act(const __half* __restrict__ h, __half* __restrict__ act)
{
    long idx = (long)blockIdx.x * 256 + threadIdx.x;
    long row = idx >> 8; int c8 = (int)(idx & 255) * 8;
    H8 a, b2, o;
    *(uint4*)&a = *(const uint4*)(h + row * 4096 + c8);
    *(uint4*)&b2 = *(const uint4*)(h + row * 4096 + 2048 + c8);
#pragma unroll
    for (int j = 0; j < 8; ++j) {
        float x = (float)a.h[j], y = (float)b2.h[j];
        o.h[j] = (_Float16)(x / (1.0f + expf(-x)) * y);
    }
    *(uint4*)(act + row * 2048 + c8) = *(uint4*)&o;
}

// ---------- combine: out = x1 + g0*eo[p0] + g1*eo[p1] ----------
__global__ __launch_bounds__(256) void k_combine(const float* __restrict__ x1,
    const float* __restrict__ eo, const int* __restrict__ invpos,
    const float* __restrict__ gates, float* __restrict__ out)
{
    const int t = blockIdx.x, c = threadIdx.x * 4;
    float g0 = gates[t * 2], g1 = gates[t * 2 + 1];
    int p0 = invpos[t * 2], p1 = invpos[t * 2 + 1];
    float4 xv = *(const float4*)(x1 + (long)t * 1024 + c);
    float4 e0 = *(const float4*)(eo + (long)p0 * 1024 + c);
    float4 e1 = *(const float4*)(eo + (long)p1 * 1024 + c);
    float4 o;
    o.x = xv.x + g0 * e0.x + g1 * e1.x;
    o.y = xv.y + g0 * e0.y + g1 * e1.y;
    o.z = xv.z + g0 * e0.z + g1 * e1.z;
    o.w = xv.w + g0 * e0.w + g1 * e1.w;
    *(float4*)(out + (long)t * 1024 + c) = o;
}

// ---------- loss: reduce pprob[512][8] + cnt -> lb_loss ----------
__global__ __launch_bounds__(256) void k_loss(const int* __restrict__ cnt,
    const float* __restrict__ pprob, float* __restrict__ out)
{
    __shared__ float m[32][8];
    const int tid = threadIdx.x;
    const int e = tid & 7, g = tid >> 3;      // g in 0..31
    float local = 0.0f;
    for (int b = g; b < 512; b += 32) local += pprob[b * 8 + e];
    m[g][e] = local;
    __syncthreads();
    if (tid == 0) {
        float us = 0, ps = 0, pe[8], ue[8];
        for (int ee = 0; ee < 8; ++ee) {
            float s = 0;
            for (int gg = 0; gg < 32; ++gg) s += m[gg][ee];
            pe[ee] = s; ps += s;
            ue[ee] = (float)cnt[ee]; us += ue[ee];
        }
        float lb = 0;
        for (int ee = 0; ee < 8; ++ee) lb += (ue[ee] / us) * (pe[ee] / ps);
        out[2097152] = lb * 8.0f;
    }
}

// =====================  launch  =====================
extern "C" void kernel_launch(void* const* d_in, const int* in_sizes, int n_in,
                              void* d_out, int out_size, void* d_ws, size_t ws_size,
                              hipStream_t stream)
{
    const float* x    = (const float*)d_in[0];
    const float* ln1g = (const float*)d_in[1];
    const float* ln1b = (const float*)d_in[2];
    const float* qkvw = (const float*)d_in[3];
    const float* outw = (const float*)d_in[4];
    const float* ln2g = (const float*)d_in[5];
    const float* ln2b = (const float*)d_in[6];
    const float* gw   = (const float*)d_in[7];
    const float* eb   = (const float*)d_in[8];
    const float* w1   = (const float*)d_in[9];
    const float* w2   = (const float*)d_in[10];
    float* out = (float*)d_out;
    char* ws = (char*)d_ws;

    // ---- workspace map (bytes); total need ~264.6 MB, region R aliased by phase
    constexpr size_t OFF_QKVWT = 0;                 // u32 [3072][1024]
    constexpr size_t OFF_OUTWT = 12582912;          // u32 [1024][1024]
    constexpr size_t OFF_XN1   = 16777216;          // u32 [2048][1024]; pprob aliases after QKV GEMM
    constexpr size_t OFF_QPK   = 25165824;          // u32 [32][1024][64]
    constexpr size_t OFF_KPK   = 33554432;
    constexpr size_t OFF_VTPK  = 41943040;          // u32 [32][64][1024]
    constexpr size_t OFF_OPK   = 50331648;          // u32 [2048][1024]
    constexpr size_t OFF_X1    = 58720256;          // f32 [2048][1024]
    constexpr size_t OFF_XN2F  = 67108864;          // f32
    constexpr size_t OFF_XN2H  = 75497472;          // half [2048][1024]
    constexpr size_t OFF_RC    = 79691776;          // f32 [1024][32]
    constexpr size_t OFF_RS    = 79822848;
    constexpr size_t OFF_IDX   = 79953920;          // int [2048][2]
    constexpr size_t OFF_GATES = 79970304;          // f32 [2048][2]
    constexpr size_t OFF_INVP  = 79986688;          // int [2048][2]
    constexpr size_t OFF_ROWI  = 80003072;          // int [5120]
    constexpr size_t OFF_CNT   = 80023552;          // int [8]
    constexpr size_t OFF_NT    = 80023616;          // int
    constexpr size_t OFF_DESC  = 80023680;          // Desc [40]
    constexpr size_t OFF_R     = 80024704;          // aliased region
    constexpr size_t OFF_QKVF  = OFF_R;                      // f32 [2048][3072] (phase 1)
    constexpr size_t OFF_S     = OFF_R;                      // f32 [32][1024][1024] (phase 2)
    constexpr size_t OFF_W1T   = OFF_R;                      // half [8][4096][1024] (phase 3)
    constexpr size_t OFF_W2T   = OFF_R + 67108864;           // half [8][1024][2048]
    constexpr size_t OFF_H     = OFF_R + 100663296;          // half [5120][4096]
    constexpr size_t OFF_ACT   = OFF_R + 142606336;          // half [5120][2048]
    constexpr size_t OFF_EO    = OFF_R + 163577856;          // f32 [5120][1024]
    constexpr size_t OFF_PPROB = OFF_XN1;                    // f32 [512][8] (xn1 dead by then)

    uint*  qkvwt = (uint*)(ws + OFF_QKVWT);
    uint*  outwt = (uint*)(ws + OFF_OUTWT);
    uint*  xn1   = (uint*)(ws + OFF_XN1);
    uint*  qpk   = (uint*)(ws + OFF_QPK);
    uint*  kpk   = (uint*)(ws + OFF_KPK);
    uint*  vtpk  = (uint*)(ws + OFF_VTPK);
    uint*  opk   = (uint*)(ws + OFF_OPK);
    float* x1    = (float*)(ws + OFF_X1);
    float* xn2f  = (float*)(ws + OFF_XN2F);
    __half* xn2h = (__half*)(ws + OFF_XN2H);
    float* rc    = (float*)(ws + OFF_RC);
    float* rs    = (float*)(ws + OFF_RS);
    int*   idx   = (int*)(ws + OFF_IDX);
    float* gates = (float*)(ws + OFF_GATES);
    int*   invp  = (int*)(ws + OFF_INVP);
    int*   rowi  = (int*)(ws + OFF_ROWI);
    int*   cnt   = (int*)(ws + OFF_CNT);
    int*   nt    = (int*)(ws + OFF_NT);
    Desc*  desc  = (Desc*)(ws + OFF_DESC);
    float* pprob = (float*)(ws + OFF_PPROB);
    float* qkvf  = (float*)(ws + OFF_QKVF);
    float* S     = (float*)(ws + OFF_S);
    __half* w1t  = (__half*)(ws + OFF_W1T);
    __half* w2t  = (__half*)(ws + OFF_W2T);
    __half* h    = (__half*)(ws + OFF_H);
    __half* act  = (__half*)(ws + OFF_ACT);
    float* eo    = (float*)(ws + OFF_EO);

    // weight transposes (pre-gating, packed split-fp16)
    k_transpose<true><<<dim3(48, 16, 1), 256, 0, stream>>>(qkvw, qkvwt, 1024, 3072);
    k_transpose<true><<<dim3(16, 16, 1), 256, 0, stream>>>(outw, outwt, 1024, 1024);
    k_rope_table<<<dim3(128), 256, 0, stream>>>(rc, rs);

    // LN1 -> packed xn1
    k_ln<0><<<dim3(2048), 256, 0, stream>>>(x, ln1g, ln1b, xn1, nullptr);

    // QKV GEMM: [2048x1024] x [1024x3072] -> f32
    k_gemm_pk<2, 2, 4, 4, EPI_F32><<<dim3(16, 24, 1), 256, 0, stream>>>(
        xn1, 1024, 0, qkvwt, 1024, 0, qkvf, 3072, 0, 2048, 3072, 1024, 1.0f, nullptr, 0);

    // RoPE + layout: q,k packed [bh][t][64]; v^T packed [bh][64][1024]
    k_rearrange<<<dim3(4096), 256, 0, stream>>>(qkvf, rc, rs, qpk, kpk, vtpk);

    // S = 0.125 * q k^T  (batched over 32 heads)
    k_gemm_pk<2, 2, 4, 4, EPI_F32><<<dim3(8, 8, 32), 256, 0, stream>>>(
        qpk, 64, 65536, kpk, 64, 65536, S, 1024, 1048576, 1024, 1024, 64, 0.125f, nullptr, 0);

    // softmax rows, pack P in place
    k_softmax<<<dim3(32768), 256, 0, stream>>>(S);

    // O = P V  -> o packed, head-interleaved layout
    k_gemm_pk<2, 2, 2, 2, EPI_PACK_O><<<dim3(16, 1, 32), 256, 0, stream>>>(
        (const uint*)S, 1024, 1048576, vtpk, 1024, 65536, opk, 1024, 0, 1024, 64, 1024, 1.0f, nullptr, 0);

    // x1 = x + o @ out_w
    k_gemm_pk<2, 2, 4, 4, EPI_RESID><<<dim3(16, 8, 1), 256, 0, stream>>>(
        opk, 1024, 0, outwt, 1024, 0, x1, 1024, 0, 2048, 1024, 1024, 1.0f, x, 0);

    // LN2 -> xn2 (f32 for gating, fp16 for MoE)
    k_ln<1><<<dim3(2048), 256, 0, stream>>>(x1, ln2g, ln2b, xn2f, xn2h);

    // gating + routing (no global atomics)
    k_gate<<<dim3(512), 256, 0, stream>>>(xn2f, gw, eb, idx, gates, pprob);
    k_route<<<dim3(1), 256, 0, stream>>>(idx, rowi, invp, nt, desc, cnt);

    // MoE weight transposes (region R now free of S)
    k_transpose<false><<<dim3(64, 16, 8), 256, 0, stream>>>(w1, w1t, 1024, 4096);
    k_transpose<false><<<dim3(16, 32, 8), 256, 0, stream>>>(w2, w2t, 2048, 1024);

    // MoE GEMM1 (gathered rows): h = xn2 @ w1[e]
    k_gemm_moe<true, true><<<dim3(40, 32, 1), 256, 0, stream>>>(
        xn2h, 1024, rowi, desc, nt, w1t, 4194304, 1024, h, 4096, 4096, 1024);

    // SwiGLU
    k_act<<<dim3(5120), 256, 0, stream>>>(h, act);

    // MoE GEMM2: eo = act @ w2[e]
    k_gemm_moe<false, false><<<dim3(40, 8, 1), 256, 0, stream>>>(
        act, 2048, nullptr, desc, nt, w2t, 2097152, 2048, eo, 1024, 1024, 2048);

    // combine + loss
    k_combine<<<dim3(2048), 256, 0, stream>>>(x1, eo, invp, gates, out);
    k_loss<<<dim3(1), 256, 0, stream>>>(cnt, pprob, out);
}

// Round 3
// 567.004 us; speedup vs baseline: 1.6221x; 1.1768x over previous
//
#include <hip/hip_runtime.h>
#include <hip/hip_fp16.h>

// UnifiedTransformerBlock on MI355X.
// Pre-gating path in split-fp16 (fp32-class precision, needed so MoE top-2
// selection matches the np reference).  MoE FFN routed, plain fp16 MFMA.
// R3: flash-fused attention (removes S materialization: S-GEMM + softmax +
// PV kernels and ~400MB of L2/L3 traffic); residual GEMM regridded 128->512
// blocks (was half-idle, occupancy 5.4%).

typedef _Float16 half8 __attribute__((ext_vector_type(8)));
typedef float f32x4 __attribute__((ext_vector_type(4)));

#define DI __device__ __forceinline__

union H8 { uint u[4]; half8 h; };

struct Desc { int e, base, rows; };

// ---------- split-fp16 packing: value ~= hi + lo * 2^-11 ----------
DI uint pack_split(float v) {
    __half hh = __float2half(v);
    float hf = __half2float(hh);
    __half ll = __float2half((v - hf) * 2048.0f);
    return (uint)__half_as_ushort(hh) | ((uint)__half_as_ushort(ll) << 16);
}

DI void unpk(uint4 r0, uint4 r1, H8 &hi, H8 &lo) {
    hi.u[0] = (r0.x & 0xffffu) | (r0.y << 16);
    hi.u[1] = (r0.z & 0xffffu) | (r0.w << 16);
    hi.u[2] = (r1.x & 0xffffu) | (r1.y << 16);
    hi.u[3] = (r1.z & 0xffffu) | (r1.w << 16);
    lo.u[0] = (r0.x >> 16) | (r0.y & 0xffff0000u);
    lo.u[1] = (r0.z >> 16) | (r0.w & 0xffff0000u);
    lo.u[2] = (r1.x >> 16) | (r1.y & 0xffff0000u);
    lo.u[3] = (r1.z >> 16) | (r1.w & 0xffff0000u);
}

DI float blockReduceSum(float v, float* red) {
#pragma unroll
    for (int m = 32; m; m >>= 1) v += __shfl_xor(v, m);
    int w = threadIdx.x >> 6;
    if ((threadIdx.x & 63) == 0) red[w] = v;
    __syncthreads();
    v = red[0] + red[1] + red[2] + red[3];
    __syncthreads();
    return v;
}

// ---------- split-fp16 GEMM: C = alpha * A(MxK) * B^T(NxK) [+ resid] ----------
enum { EPI_F32 = 0, EPI_RESID = 2 };

template<int WM, int WN, int FM, int FN, int EPI>
__global__ __launch_bounds__(256, 2)
void k_gemm_pk(const uint* __restrict__ A, int lda, long sA,
               const uint* __restrict__ B, int ldb, long sB,
               void* __restrict__ Cv, int ldc, long sC,
               int M, int N, int K, float alpha,
               const float* __restrict__ resid)
{
    constexpr int BM = WM * FM * 16, BN = WN * FN * 16;
    constexpr int PITCH = 36;                  // 32 k-elems + 4 pad (uint)
    __shared__ uint As[BM * PITCH];
    __shared__ uint Bs[BN * PITCH];
    const int tid = threadIdx.x;
    const int lane = tid & 63, w = tid >> 6;
    const int wm = w / WN, wn = w % WN;
    const int m0 = blockIdx.x * BM, n0 = blockIdx.y * BN;
    const int z = blockIdx.z;
    A += (long)z * sA; B += (long)z * sB;

    f32x4 acc0[FM][FN] = {}; f32x4 acc1[FM][FN] = {};

    for (int k0 = 0; k0 < K; k0 += 32) {
        __syncthreads();
#pragma unroll
        for (int it = 0; it < BM / 32; ++it) {
            int c = it * 256 + tid, row = c >> 3, kg = c & 7;
            int gr = m0 + row;
            uint4 v = make_uint4(0, 0, 0, 0);
            if (gr < M) v = *(const uint4*)(A + (long)gr * lda + k0 + kg * 4);
            *(uint4*)&As[row * PITCH + kg * 4] = v;
        }
#pragma unroll
        for (int it = 0; it < BN / 32; ++it) {
            int c = it * 256 + tid, row = c >> 3, kg = c & 7;
            int gr = n0 + row;
            uint4 v = make_uint4(0, 0, 0, 0);
            if (gr < N) v = *(const uint4*)(B + (long)gr * ldb + k0 + kg * 4);
            *(uint4*)&Bs[row * PITCH + kg * 4] = v;
        }
        __syncthreads();
        H8 ah[FM], al[FM];
#pragma unroll
        for (int i = 0; i < FM; ++i) {
            const uint* p = &As[(wm * FM * 16 + i * 16 + (lane & 15)) * PITCH + (lane >> 4) * 8];
            unpk(*(const uint4*)p, *(const uint4*)(p + 4), ah[i], al[i]);
        }
#pragma unroll
        for (int n = 0; n < FN; ++n) {
            const uint* p = &Bs[(wn * FN * 16 + n * 16 + (lane & 15)) * PITCH + (lane >> 4) * 8];
            H8 bh_, bl_;
            unpk(*(const uint4*)p, *(const uint4*)(p + 4), bh_, bl_);
#pragma unroll
            for (int i = 0; i < FM; ++i) {
                acc0[i][n] = __builtin_amdgcn_mfma_f32_16x16x32_f16(ah[i].h, bh_.h, acc0[i][n], 0, 0, 0);
                acc1[i][n] = __builtin_amdgcn_mfma_f32_16x16x32_f16(ah[i].h, bl_.h, acc1[i][n], 0, 0, 0);
                acc1[i][n] = __builtin_amdgcn_mfma_f32_16x16x32_f16(al[i].h, bh_.h, acc1[i][n], 0, 0, 0);
            }
        }
    }

    float* Cf = (float*)Cv + (long)z * sC;
#pragma unroll
    for (int i = 0; i < FM; ++i)
#pragma unroll
    for (int n = 0; n < FN; ++n)
#pragma unroll
    for (int j = 0; j < 4; ++j) {
        float v = (acc0[i][n][j] + acc1[i][n][j] * (1.0f / 2048.0f)) * alpha;
        int gm = m0 + wm * FM * 16 + i * 16 + (lane >> 4) * 4 + j;
        int gn = n0 + wn * FN * 16 + n * 16 + (lane & 15);
        if (gm < M && gn < N) {
            if constexpr (EPI == EPI_F32)
                Cf[(long)gm * ldc + gn] = v;
            else
                Cf[(long)gm * ldc + gn] = v + resid[(long)gm * ldc + gn];
        }
    }
}

// ---------- flash attention: split-fp16 QK^T + fp32 online softmax + split PV
// grid (16 q-tiles, 32 heads); block 256 = 4 waves; wave owns 16 q-rows.
__global__ __launch_bounds__(256, 2)
void k_flash(const uint* __restrict__ qpk, const uint* __restrict__ kpk,
             const uint* __restrict__ vtpk, uint* __restrict__ opk)
{
    __shared__ uint Ks[64 * 68];   // [kv][d] packed
    __shared__ uint Vs[64 * 68];   // [d][kv] packed
    __shared__ uint Ps[64 * 68];   // [q][kv] packed
    const int tid = threadIdx.x, lane = tid & 63, w = tid >> 6;
    const int l15 = lane & 15, g = lane >> 4;
    const int q0 = blockIdx.x * 64;
    const int bh = blockIdx.y;
    const uint* Qp = qpk + (long)bh * 65536;
    const uint* Kp = kpk + (long)bh * 65536;
    const uint* Vt = vtpk + (long)bh * 65536;

    // Q fragments (A-operand): row = l15 (q local), k = g*8+e (+32 for kstep 1)
    H8 qh[2], ql[2];
    {
        const uint* qr = Qp + (long)(q0 + w * 16 + l15) * 64 + g * 8;
        unpk(*(const uint4*)qr, *(const uint4*)(qr + 4), qh[0], ql[0]);
        unpk(*(const uint4*)(qr + 32), *(const uint4*)(qr + 36), qh[1], ql[1]);
    }

    float m_[4] = {-1e30f, -1e30f, -1e30f, -1e30f};
    float l_[4] = {0.f, 0.f, 0.f, 0.f};
    f32x4 o0[4] = {}, o1[4] = {};

    for (int kt = 0; kt < 16; ++kt) {
        __syncthreads();                       // prev PV reads done
#pragma unroll
        for (int it = 0; it < 4; ++it) {
            int c = it * 256 + tid, row = c >> 4, kg = c & 15;
            *(uint4*)&Ks[row * 68 + kg * 4] =
                *(const uint4*)(Kp + (long)(kt * 64 + row) * 64 + kg * 4);
        }
#pragma unroll
        for (int it = 0; it < 4; ++it) {
            int c = it * 256 + tid, row = c >> 4, kg = c & 15;   // row = d
            *(uint4*)&Vs[row * 68 + kg * 4] =
                *(const uint4*)(Vt + (long)row * 1024 + kt * 64 + kg * 4);
        }
        __syncthreads();

        // S-tile: q(16 rows of this wave) x kv(64)
        f32x4 s0[4] = {}, s1[4] = {};
#pragma unroll
        for (int cf = 0; cf < 4; ++cf) {
            const uint* kr = &Ks[(cf * 16 + l15) * 68 + g * 8];
            H8 kh0, kl0, kh1, kl1;
            unpk(*(const uint4*)kr, *(const uint4*)(kr + 4), kh0, kl0);
            unpk(*(const uint4*)(kr + 32), *(const uint4*)(kr + 36), kh1, kl1);
            s0[cf] = __builtin_amdgcn_mfma_f32_16x16x32_f16(qh[0].h, kh0.h, s0[cf], 0, 0, 0);
            s1[cf] = __builtin_amdgcn_mfma_f32_16x16x32_f16(qh[0].h, kl0.h, s1[cf], 0, 0, 0);
            s1[cf] = __builtin_amdgcn_mfma_f32_16x16x32_f16(ql[0].h, kh0.h, s1[cf], 0, 0, 0);
            s0[cf] = __builtin_amdgcn_mfma_f32_16x16x32_f16(qh[1].h, kh1.h, s0[cf], 0, 0, 0);
            s1[cf] = __builtin_amdgcn_mfma_f32_16x16x32_f16(qh[1].h, kl1.h, s1[cf], 0, 0, 0);
            s1[cf] = __builtin_amdgcn_mfma_f32_16x16x32_f16(ql[1].h, kh1.h, s1[cf], 0, 0, 0);
        }

        // online softmax; lane holds rows g*4+j, cols cf*16+l15
        float pj[4][4];
#pragma unroll
        for (int j = 0; j < 4; ++j) {
            float sv[4];
#pragma unroll
            for (int cf = 0; cf < 4; ++cf)
                sv[cf] = (s0[cf][j] + s1[cf][j] * (1.0f / 2048.0f)) * 0.125f;
            float mx = fmaxf(fmaxf(sv[0], sv[1]), fmaxf(sv[2], sv[3]));
#pragma unroll
            for (int msk = 8; msk; msk >>= 1) mx = fmaxf(mx, __shfl_xor(mx, msk));
            float mn = fmaxf(m_[j], mx);
            float r = expf(m_[j] - mn);
            m_[j] = mn;
            float rs = 0.f;
#pragma unroll
            for (int cf = 0; cf < 4; ++cf) { float p = expf(sv[cf] - mn); pj[j][cf] = p; rs += p; }
#pragma unroll
            for (int msk = 8; msk; msk >>= 1) rs += __shfl_xor(rs, msk);
            l_[j] = l_[j] * r + rs;
#pragma unroll
            for (int df = 0; df < 4; ++df) { o0[df][j] *= r; o1[df][j] *= r; }
        }
        // pack P (wave-local rows)
#pragma unroll
        for (int j = 0; j < 4; ++j)
#pragma unroll
        for (int cf = 0; cf < 4; ++cf)
            Ps[(w * 16 + g * 4 + j) * 68 + cf * 16 + l15] = pack_split(pj[j][cf]);
        __syncthreads();

        // PV: contraction over kv (2 ksteps of 32)
        const uint* pr = &Ps[(w * 16 + l15) * 68 + g * 8];
        H8 ph0, pl0, ph1, pl1;
        unpk(*(const uint4*)pr, *(const uint4*)(pr + 4), ph0, pl0);
        unpk(*(const uint4*)(pr + 32), *(const uint4*)(pr + 36), ph1, pl1);
#pragma unroll
        for (int df = 0; df < 4; ++df) {
            const uint* vr = &Vs[(df * 16 + l15) * 68 + g * 8];
            H8 vh0, vl0, vh1, vl1;
            unpk(*(const uint4*)vr, *(const uint4*)(vr + 4), vh0, vl0);
            unpk(*(const uint4*)(vr + 32), *(const uint4*)(vr + 36), vh1, vl1);
            o0[df] = __builtin_amdgcn_mfma_f32_16x16x32_f16(ph0.h, vh0.h, o0[df], 0, 0, 0);
            o1[df] = __builtin_amdgcn_mfma_f32_16x16x32_f16(ph0.h, vl0.h, o1[df], 0, 0, 0);
            o1[df] = __builtin_amdgcn_mfma_f32_16x16x32_f16(pl0.h, vh0.h, o1[df], 0, 0, 0);
            o0[df] = __builtin_amdgcn_mfma_f32_16x16x32_f16(ph1.h, vh1.h, o0[df], 0, 0, 0);
            o1[df] = __builtin_amdgcn_mfma_f32_16x16x32_f16(ph1.h, vl1.h, o1[df], 0, 0, 0);
            o1[df] = __builtin_amdgcn_mfma_f32_16x16x32_f16(pl1.h, vh1.h, o1[df], 0, 0, 0);
        }
    }

    // epilogue: normalize, pack, store to opk [b][t][h*64+d]
    const long obase = (long)(bh >> 4) * 1048576 + (bh & 15) * 64;
    float invl[4];
#pragma unroll
    for (int j = 0; j < 4; ++j) invl[j] = 1.0f / l_[j];
#pragma unroll
    for (int df = 0; df < 4; ++df)
#pragma unroll
    for (int j = 0; j < 4; ++j) {
        float v = (o0[df][j] + o1[df][j] * (1.0f / 2048.0f)) * invl[j];
        opk[obase + (long)(q0 + w * 16 + g * 4 + j) * 1024 + df * 16 + l15] = pack_split(v);
    }
}

// ---------- plain fp16 MoE grouped GEMM (desc-driven, 128x128 tile) ----------
template<bool GATHER, bool OUTHALF>
__global__ __launch_bounds__(256, 2)
void k_gemm_moe(const __half* __restrict__ A, int lda, const int* __restrict__ rowidx,
                const Desc* __restrict__ desc, const int* __restrict__ ntiles,
                const __half* __restrict__ Bbase, long sB, int ldb,
                void* __restrict__ Cv, int ldc, int N, int K)
{
    if ((int)blockIdx.x >= *ntiles) return;
    Desc d = desc[blockIdx.x];
    const __half* Bp = Bbase + (long)d.e * sB;
    constexpr int PITCH = 40;                  // halves: 32 + 8 pad
    __shared__ __half As[128 * PITCH];
    __shared__ __half Bs[128 * PITCH];
    const int tid = threadIdx.x, lane = tid & 63, w = tid >> 6;
    const int wm = w >> 1, wn = w & 1;
    const int n0 = blockIdx.y * 128;

    f32x4 acc[4][4] = {};
    for (int k0 = 0; k0 < K; k0 += 32) {
        __syncthreads();
#pragma unroll
        for (int it = 0; it < 2; ++it) {
            int c = it * 256 + tid, row = c >> 2, kg = c & 3;
            uint4 v = make_uint4(0, 0, 0, 0);
            if constexpr (GATHER) {
                if (row < d.rows) {
                    int ar = rowidx[d.base + row];
                    v = *(const uint4*)(A + (long)ar * lda + k0 + kg * 8);
                }
            } else {
                v = *(const uint4*)(A + (long)(d.base + row) * lda + k0 + kg * 8);
            }
            *(uint4*)&As[row * PITCH + kg * 8] = v;
        }
#pragma unroll
        for (int it = 0; it < 2; ++it) {
            int c = it * 256 + tid, row = c >> 2, kg = c & 3;
            uint4 v = *(const uint4*)(Bp + (long)(n0 + row) * ldb + k0 + kg * 8);
            *(uint4*)&Bs[row * PITCH + kg * 8] = v;
        }
        __syncthreads();
        half8 a[4];
#pragma unroll
        for (int i = 0; i < 4; ++i)
            a[i] = *(const half8*)&As[(wm * 64 + i * 16 + (lane & 15)) * PITCH + (lane >> 4) * 8];
#pragma unroll
        for (int n = 0; n < 4; ++n) {
            half8 b = *(const half8*)&Bs[(wn * 64 + n * 16 + (lane & 15)) * PITCH + (lane >> 4) * 8];
#pragma unroll
            for (int i = 0; i < 4; ++i)
                acc[i][n] = __builtin_amdgcn_mfma_f32_16x16x32_f16(a[i], b, acc[i][n], 0, 0, 0);
        }
    }
#pragma unroll
    for (int i = 0; i < 4; ++i)
#pragma unroll
    for (int n = 0; n < 4; ++n)
#pragma unroll
    for (int j = 0; j < 4; ++j) {
        int rl = wm * 64 + i * 16 + (lane >> 4) * 4 + j;
        int gn = n0 + wn * 64 + n * 16 + (lane & 15);
        float v = acc[i][n][j];
        if constexpr (OUTHALF) {
            if (rl >= d.rows) v = 0.0f;
            ((__half*)Cv)[(long)(d.base + rl) * ldc + gn] = __float2half(v);
        } else {
            ((float*)Cv)[(long)(d.base + rl) * ldc + gn] = v;
        }
    }
}

// ---------- transpose fp32 [R][C] -> [C][R], output packed u32 or fp16 ----------
template<bool PACK>
__global__ __launch_bounds__(256) void k_transpose(const float* __restrict__ src,
                                                   void* __restrict__ dst, int R, int C)
{
    src += (long)blockIdx.z * R * C;
    const long doff = (long)blockIdx.z * R * C;
    __shared__ float t[64][65];
    const int tid = threadIdx.x;
    const int c0 = blockIdx.x * 64, r0 = blockIdx.y * 64;
#pragma unroll
    for (int it = 0; it < 4; ++it) {
        int idx = it * 256 + tid;
        int r = idx >> 4, c4 = (idx & 15) * 4;
        float4 v = *(const float4*)(src + (long)(r0 + r) * C + c0 + c4);
        t[r][c4] = v.x; t[r][c4 + 1] = v.y; t[r][c4 + 2] = v.z; t[r][c4 + 3] = v.w;
    }
    __syncthreads();
    if constexpr (PACK) {
        uint* out = (uint*)dst + doff;
#pragma unroll
        for (int it = 0; it < 4; ++it) {
            int idx = it * 256 + tid;
            int orow = idx >> 4, oc = (idx & 15) * 4;
            uint4 v;
            v.x = pack_split(t[oc + 0][orow]);
            v.y = pack_split(t[oc + 1][orow]);
            v.z = pack_split(t[oc + 2][orow]);
            v.w = pack_split(t[oc + 3][orow]);
            *(uint4*)(out + (long)(c0 + orow) * R + r0 + oc) = v;
        }
    } else {
        __half* out = (__half*)dst + doff;
#pragma unroll
        for (int it = 0; it < 2; ++it) {
            int idx = it * 256 + tid;
            int orow = idx >> 3, oc = (idx & 7) * 8;
            H8 v;
#pragma unroll
            for (int j = 0; j < 8; ++j) v.h[j] = (_Float16)t[oc + j][orow];
            *(uint4*)(out + (long)(c0 + orow) * R + r0 + oc) = *(uint4*)&v;
        }
    }
}

// ---------- LayerNorm (D=1024, one block per row) ----------
template<int MODE> // 0: packed-split out; 1: f32 + fp16 out
__global__ __launch_bounds__(256) void k_ln(const float* __restrict__ X,
    const float* __restrict__ g, const float* __restrict__ bta,
    void* __restrict__ o1, void* __restrict__ o2)
{
    __shared__ float red[4];
    const long row = blockIdx.x;
    const float* xr = X + row * 1024;
    const int c = threadIdx.x * 4;
    float4 v = *(const float4*)(xr + c);
    float mu = blockReduceSum(v.x + v.y + v.z + v.w, red) * (1.0f / 1024.0f);
    float d0 = v.x - mu, d1 = v.y - mu, d2 = v.z - mu, d3 = v.w - mu;
    float var = blockReduceSum(d0 * d0 + d1 * d1 + d2 * d2 + d3 * d3, red) * (1.0f / 1024.0f);
    float rs = 1.0f / sqrtf(var + 1e-5f);
    float4 gv = *(const float4*)(g + c);
    float4 bv = *(const float4*)(bta + c);
    float y0 = d0 * rs * gv.x + bv.x;
    float y1 = d1 * rs * gv.y + bv.y;
    float y2 = d2 * rs * gv.z + bv.z;
    float y3 = d3 * rs * gv.w + bv.w;
    if constexpr (MODE == 0) {
        *(uint4*)((uint*)o1 + row * 1024 + c) =
            make_uint4(pack_split(y0), pack_split(y1), pack_split(y2), pack_split(y3));
    } else {
        *(float4*)((float*)o1 + row * 1024 + c) = make_float4(y0, y1, y2, y3);
        uint lo_ = (uint)__half_as_ushort(__float2half(y0)) | ((uint)__half_as_ushort(__float2half(y1)) << 16);
        uint hi_ = (uint)__half_as_ushort(__float2half(y2)) | ((uint)__half_as_ushort(__float2half(y3)) << 16);
        *(uint2*)((__half*)o2 + row * 1024 + c) = make_uint2(lo_, hi_);
    }
}

// ---------- RoPE cos/sin table ----------
__global__ __launch_bounds__(256) void k_rope_table(float* __restrict__ ct, float* __restrict__ st)
{
    int idx = blockIdx.x * 256 + threadIdx.x; // 32768 = 1024 t x 32 i
    int t = idx >> 5, i = idx & 31;
    float inv = 1.0f / (float)pow(10000.0, (double)i / 32.0);
    float ang = (float)t * inv;
    ct[idx] = cosf(ang);
    st[idx] = sinf(ang);
}

// ---------- qkv [2048][3072] f32 -> roped q,k packed [bh][t][64]; v^T packed ----------
__global__ __launch_bounds__(256) void k_rearrange(const float* __restrict__ qkv,
    const float* __restrict__ ct, const float* __restrict__ st,
    uint* __restrict__ qp, uint* __restrict__ kp, uint* __restrict__ vtp)
{
    int gid = blockIdx.x * 256 + threadIdx.x; // 1,048,576
    int i = gid & 31;
    int h = (gid >> 5) & 15;
    int t = (gid >> 9) & 1023;
    int b = gid >> 19;
    long row = (long)(b * 1024 + t) * 3072;
    int col = h * 64 + 2 * i;
    float q0 = qkv[row + col], q1 = qkv[row + col + 1];
    float kk0 = qkv[row + 1024 + col], kk1 = qkv[row + 1024 + col + 1];
    float v0 = qkv[row + 2048 + col], v1 = qkv[row + 2048 + col + 1];
    float cv = ct[t * 32 + i], sv = st[t * 32 + i];
    long bh = b * 16 + h;
    long qo = (bh * 1024 + t) * 64 + 2 * i;
    qp[qo] = pack_split(q0 * cv - q1 * sv);
    qp[qo + 1] = pack_split(q1 * cv + q0 * sv);
    kp[qo] = pack_split(kk0 * cv - kk1 * sv);
    kp[qo + 1] = pack_split(kk1 * cv + kk0 * sv);
    long vo = (bh * 64 + 2 * i) * 1024 + t;
    vtp[vo] = pack_split(v0);
    vtp[vo + 1024] = pack_split(v1);
}

// ---------- gating: fp32 scores, top-2, NO global atomics ----------
__global__ __launch_bounds__(256) void k_gate(const float* __restrict__ xn2,
    const float* __restrict__ gw, const float* __restrict__ eb,
    int* __restrict__ topidx, float* __restrict__ gates,
    float* __restrict__ pprob)
{
    __shared__ float pp[4][8];
    const int lane = threadIdx.x & 63, w = threadIdx.x >> 6;
    const int t = blockIdx.x * 4 + w;
    const float* xr = xn2 + (long)t * 1024;
    float sc[8] = {0, 0, 0, 0, 0, 0, 0, 0};
#pragma unroll
    for (int i = 0; i < 4; ++i) {
        int d = i * 256 + lane * 4;
        float4 xv = *(const float4*)(xr + d);
        float xa[4] = {xv.x, xv.y, xv.z, xv.w};
#pragma unroll
        for (int j = 0; j < 4; ++j) {
            float xx = xa[j];
            const float4* gp = (const float4*)(gw + (long)(d + j) * 8);
            float4 g0 = gp[0], g1 = gp[1];
            sc[0] += xx * g0.x; sc[1] += xx * g0.y; sc[2] += xx * g0.z; sc[3] += xx * g0.w;
            sc[4] += xx * g1.x; sc[5] += xx * g1.y; sc[6] += xx * g1.z; sc[7] += xx * g1.w;
        }
    }
#pragma unroll
    for (int e = 0; e < 8; ++e) {
#pragma unroll
        for (int m = 32; m; m >>= 1) sc[e] += __shfl_xor(sc[e], m);
        sc[e] += eb[e];
    }
    if (lane == 0) {
        int i1 = 0; float v1 = sc[0];
        for (int e = 1; e < 8; ++e) if (sc[e] > v1) { v1 = sc[e]; i1 = e; }
        int i2 = (i1 == 0) ? 1 : 0; float v2 = sc[i2];
        for (int e = 0; e < 8; ++e) if (e != i1 && sc[e] > v2) { v2 = sc[e]; i2 = e; }
        float e2 = expf(v2 - v1);
        gates[t * 2] = 1.0f / (1.0f + e2);
        gates[t * 2 + 1] = e2 / (1.0f + e2);
        topidx[t * 2] = i1; topidx[t * 2 + 1] = i2;
        float mxx = sc[0];
        for (int e = 1; e < 8; ++e) mxx = fmaxf(mxx, sc[e]);
        float se = 0.0f, pe[8];
        for (int e = 0; e < 8; ++e) { pe[e] = expf(sc[e] - mxx); se += pe[e]; }
        float inv = 1.0f / se;
        for (int e = 0; e < 8; ++e) pp[w][e] = pe[e] * inv;
    }
    __syncthreads();
    if (threadIdx.x < 8)
        pprob[(long)blockIdx.x * 8 + threadIdx.x] =
            pp[0][threadIdx.x] + pp[1][threadIdx.x] + pp[2][threadIdx.x] + pp[3][threadIdx.x];
}

// ---------- routing: LDS histogram + padded per-expert bases, descs, perm ----------
__global__ __launch_bounds__(256) void k_route(const int* __restrict__ topidx,
    int* __restrict__ rowidx, int* __restrict__ invpos,
    int* __restrict__ ntiles, Desc* __restrict__ desc, int* __restrict__ cnt)
{
    __shared__ int cnt_s[8], base_s[8], fill[8];
    const int tid = threadIdx.x;
    if (tid < 8) { cnt_s[tid] = 0; fill[tid] = 0; }
    __syncthreads();
    for (int i = tid; i < 4096; i += 256)
        atomicAdd(&cnt_s[topidx[i]], 1);
    __syncthreads();
    if (tid == 0) {
        int nt = 0, running = 0;
        for (int e = 0; e < 8; ++e) {
            int ce = cnt_s[e];
            cnt[e] = ce;
            base_s[e] = running;
            int tl = (ce + 127) >> 7;
            for (int j = 0; j < tl; ++j) {
                desc[nt].e = e; desc[nt].base = running + j * 128;
                desc[nt].rows = min(128, ce - j * 128);
                ++nt;
            }
            running += tl * 128;
        }
        *ntiles = nt;
    }
    __syncthreads();
    for (int t = tid; t < 2048; t += 256) {
#pragma unroll
        for (int s = 0; s < 2; ++s) {
            int e = topidx[t * 2 + s];
            int p = base_s[e] + atomicAdd(&fill[e], 1);
            rowidx[p] = t;
            invpos[t * 2 + s] = p;
        }
    }
}

// ---------- SwiGLU activation ----------
__global__ __launch_bounds__(256) void k_act(const __half* __restrict__ h, __half* __restrict__ act)
{
    long idx = (long)blockIdx.x * 256 + threadIdx.x;
    long row = idx >> 8; int c8 = (int)(idx & 255) * 8;
    H8 a, b2, o;
    *(uint4*)&a = *(const uint4*)(h + row * 4096 + c8);
    *(uint4*)&b2 = *(const uint4*)(h + row * 4096 + 2048 + c8);
#pragma unroll
    for (int j = 0; j < 8; ++j) {
        float x = (float)a.h[j], y = (float)b2.h[j];
        o.h[j] = (_Float16)(x / (1.0f + expf(-x)) * y);
    }
    *(uint4*)(act + row * 2048 + c8) = *(uint4*)&o;
}

// ---------- combine ----------
__global__ __launch_bounds__(256) void k_combine(const float* __restrict__ x1,
    const float* __restrict__ eo, const int* __restrict__ invpos,
    const float* __restrict__ gates, float* __restrict__ out)
{
    const int t = blockIdx.x, c = threadIdx.x * 4;
    float g0 = gates[t * 2], g1 = gates[t * 2 + 1];
    int p0 = invpos[t * 2], p1 = invpos[t * 2 + 1];
    float4 xv = *(const float4*)(x1 + (long)t * 1024 + c);
    float4 e0 = *(const float4*)(eo + (long)p0 * 1024 + c);
    float4 e1 = *(const float4*)(eo + (long)p1 * 1024 + c);
    float4 o;
    o.x = xv.x + g0 * e0.x + g1 * e1.x;
    o.y = xv.y + g0 * e0.y + g1 * e1.y;
    o.z = xv.z + g0 * e0.z + g1 * e1.z;
    o.w = xv.w + g0 * e0.w + g1 * e1.w;
    *(float4*)(out + (long)t * 1024 + c) = o;
}

// ---------- loss ----------
__global__ __launch_bounds__(256) void k_loss(const int* __restrict__ cnt,
    const float* __restrict__ pprob, float* __restrict__ out)
{
    __shared__ float m[32][8];
    const int tid = threadIdx.x;
    const int e = tid & 7, g = tid >> 3;
    float local = 0.0f;
    for (int b = g; b < 512; b += 32) local += pprob[b * 8 + e];
    m[g][e] = local;
    __syncthreads();
    if (tid == 0) {
        float us = 0, ps = 0, pe[8], ue[8];
        for (int ee = 0; ee < 8; ++ee) {
            float s = 0;
            for (int gg = 0; gg < 32; ++gg) s += m[gg][ee];
            pe[ee] = s; ps += s;
            ue[ee] = (float)cnt[ee]; us += ue[ee];
        }
        float lb = 0;
        for (int ee = 0; ee < 8; ++ee) lb += (ue[ee] / us) * (pe[ee] / ps);
        out[2097152] = lb * 8.0f;
    }
}

// =====================  launch  =====================
extern "C" void kernel_launch(void* const* d_in, const int* in_sizes, int n_in,
                              void* d_out, int out_size, void* d_ws, size_t ws_size,
                              hipStream_t stream)
{
    const float* x    = (const float*)d_in[0];
    const float* ln1g = (const float*)d_in[1];
    const float* ln1b = (const float*)d_in[2];
    const float* qkvw = (const float*)d_in[3];
    const float* outw = (const float*)d_in[4];
    const float* ln2g = (const float*)d_in[5];
    const float* ln2b = (const float*)d_in[6];
    const float* gw   = (const float*)d_in[7];
    const float* eb   = (const float*)d_in[8];
    const float* w1   = (const float*)d_in[9];
    const float* w2   = (const float*)d_in[10];
    float* out = (float*)d_out;
    char* ws = (char*)d_ws;

    constexpr size_t OFF_QKVWT = 0;                 // u32 [3072][1024]
    constexpr size_t OFF_OUTWT = 12582912;          // u32 [1024][1024]
    constexpr size_t OFF_XN1   = 16777216;          // u32 [2048][1024]; pprob aliases later
    constexpr size_t OFF_QPK   = 25165824;          // u32 [32][1024][64]
    constexpr size_t OFF_KPK   = 33554432;
    constexpr size_t OFF_VTPK  = 41943040;          // u32 [32][64][1024]
    constexpr size_t OFF_OPK   = 50331648;          // u32 [2048][1024]
    constexpr size_t OFF_X1    = 58720256;          // f32 [2048][1024]
    constexpr size_t OFF_XN2F  = 67108864;          // f32
    constexpr size_t OFF_XN2H  = 75497472;          // half [2048][1024]
    constexpr size_t OFF_RC    = 79691776;          // f32 [1024][32]
    constexpr size_t OFF_RS    = 79822848;
    constexpr size_t OFF_IDX   = 79953920;          // int [2048][2]
    constexpr size_t OFF_GATES = 79970304;          // f32 [2048][2]
    constexpr size_t OFF_INVP  = 79986688;          // int [2048][2]
    constexpr size_t OFF_ROWI  = 80003072;          // int [5120]
    constexpr size_t OFF_CNT   = 80023552;          // int [8]
    constexpr size_t OFF_NT    = 80023616;          // int
    constexpr size_t OFF_DESC  = 80023680;          // Desc [40]
    constexpr size_t OFF_R     = 80024704;          // aliased region
    constexpr size_t OFF_QKVF  = OFF_R;                      // f32 [2048][3072] (phase 1)
    constexpr size_t OFF_W1T   = OFF_R;                      // half [8][4096][1024] (phase 3)
    constexpr size_t OFF_W2T   = OFF_R + 67108864;           // half [8][1024][2048]
    constexpr size_t OFF_H     = OFF_R + 100663296;          // half [5120][4096]
    constexpr size_t OFF_ACT   = OFF_R + 142606336;          // half [5120][2048]
    constexpr size_t OFF_EO    = OFF_R + 163577856;          // f32 [5120][1024]
    constexpr size_t OFF_PPROB = OFF_XN1;                    // f32 [512][8]

    uint*  qkvwt = (uint*)(ws + OFF_QKVWT);
    uint*  outwt = (uint*)(ws + OFF_OUTWT);
    uint*  xn1   = (uint*)(ws + OFF_XN1);
    uint*  qpk   = (uint*)(ws + OFF_QPK);
    uint*  kpk   = (uint*)(ws + OFF_KPK);
    uint*  vtpk  = (uint*)(ws + OFF_VTPK);
    uint*  opk   = (uint*)(ws + OFF_OPK);
    float* x1    = (float*)(ws + OFF_X1);
    float* xn2f  = (float*)(ws + OFF_XN2F);
    __half* xn2h = (__half*)(ws + OFF_XN2H);
    float* rc    = (float*)(ws + OFF_RC);
    float* rs    = (float*)(ws + OFF_RS);
    int*   idx   = (int*)(ws + OFF_IDX);
    float* gates = (float*)(ws + OFF_GATES);
    int*   invp  = (int*)(ws + OFF_INVP);
    int*   rowi  = (int*)(ws + OFF_ROWI);
    int*   cnt   = (int*)(ws + OFF_CNT);
    int*   nt    = (int*)(ws + OFF_NT);
    Desc*  desc  = (Desc*)(ws + OFF_DESC);
    float* pprob = (float*)(ws + OFF_PPROB);
    float* qkvf  = (float*)(ws + OFF_QKVF);
    __half* w1t  = (__half*)(ws + OFF_W1T);
    __half* w2t  = (__half*)(ws + OFF_W2T);
    __half* h    = (__half*)(ws + OFF_H);
    __half* act  = (__half*)(ws + OFF_ACT);
    float* eo    = (float*)(ws + OFF_EO);

    // weight transposes (packed split-fp16)
    k_transpose<true><<<dim3(48, 16, 1), 256, 0, stream>>>(qkvw, qkvwt, 1024, 3072);
    k_transpose<true><<<dim3(16, 16, 1), 256, 0, stream>>>(outw, outwt, 1024, 1024);
    k_rope_table<<<dim3(128), 256, 0, stream>>>(rc, rs);

    // LN1 -> packed xn1
    k_ln<0><<<dim3(2048), 256, 0, stream>>>(x, ln1g, ln1b, xn1, nullptr);

    // QKV GEMM: [2048x1024] x [1024x3072] -> f32
    k_gemm_pk<2, 2, 4, 4, EPI_F32><<<dim3(16, 24, 1), 256, 0, stream>>>(
        xn1, 1024, 0, qkvwt, 1024, 0, qkvf, 3072, 0, 2048, 3072, 1024, 1.0f, nullptr);

    // RoPE + layout
    k_rearrange<<<dim3(4096), 256, 0, stream>>>(qkvf, rc, rs, qpk, kpk, vtpk);

    // flash attention -> opk (packed)
    k_flash<<<dim3(16, 32, 1), 256, 0, stream>>>(qpk, kpk, vtpk, opk);

    // x1 = x + o @ out_w   (512 blocks)
    k_gemm_pk<2, 2, 2, 2, EPI_RESID><<<dim3(32, 16, 1), 256, 0, stream>>>(
        opk, 1024, 0, outwt, 1024, 0, x1, 1024, 0, 2048, 1024, 1024, 1.0f, x);

    // LN2 -> xn2 (f32 for gating, fp16 for MoE)
    k_ln<1><<<dim3(2048), 256, 0, stream>>>(x1, ln2g, ln2b, xn2f, xn2h);

    // gating + routing
    k_gate<<<dim3(512), 256, 0, stream>>>(xn2f, gw, eb, idx, gates, pprob);
    k_route<<<dim3(1), 256, 0, stream>>>(idx, rowi, invp, nt, desc, cnt);

    // MoE weight transposes
    k_transpose<false><<<dim3(64, 16, 8), 256, 0, stream>>>(w1, w1t, 1024, 4096);
    k_transpose<false><<<dim3(16, 32, 8), 256, 0, stream>>>(w2, w2t, 2048, 1024);

    // MoE GEMM1 (gathered rows): h = xn2 @ w1[e]
    k_gemm_moe<true, true><<<dim3(40, 32, 1), 256, 0, stream>>>(
        xn2h, 1024, rowi, desc, nt, w1t, 4194304, 1024, h, 4096, 4096, 1024);

    // SwiGLU
    k_act<<<dim3(5120), 256, 0, stream>>>(h, act);

    // MoE GEMM2: eo = act @ w2[e]
    k_gemm_moe<false, false><<<dim3(40, 8, 1), 256, 0, stream>>>(
        act, 2048, nullptr, desc, nt, w2t, 2097152, 2048, eo, 1024, 1024, 2048);

    // combine + loss
    k_combine<<<dim3(2048), 256, 0, stream>>>(x1, eo, invp, gates, out);
    k_loss<<<dim3(1), 256, 0, stream>>>(cnt, pprob, out);
}

// Round 4
// 482.864 us; speedup vs baseline: 1.9048x; 1.1743x over previous
//
#include <hip/hip_runtime.h>
#include <hip/hip_fp16.h>

// UnifiedTransformerBlock on MI355X.
// R4: split-fp16 as SEPARATE hi/lo planes (kills unpk VALU tax), QKV GEMM
// 64x128 tiles (768 blocks), RoPE+scatter fused into QKV epilogue (removes
// qkvf+k_rearrange), MoE GEMMs read w1/w2 fp32 directly with on-the-fly
// transpose-convert (removes both weight transposes), SiLU fused into MoE
// GEMM1 epilogue via h1/h2 column pairing (removes h buffer + k_act).

typedef _Float16 half8 __attribute__((ext_vector_type(8)));
typedef float f32x4 __attribute__((ext_vector_type(4)));

#define DI __device__ __forceinline__

struct Desc { int e, base, rows; };

DI float blockReduceSum(float v, float* red) {
#pragma unroll
    for (int m = 32; m; m >>= 1) v += __shfl_xor(v, m);
    int w = threadIdx.x >> 6;
    if ((threadIdx.x & 63) == 0) red[w] = v;
    __syncthreads();
    v = red[0] + red[1] + red[2] + red[3];
    __syncthreads();
    return v;
}

DI void split2(float v, __half& hi, __half& lo) {
    hi = __float2half(v);
    lo = __float2half((v - __half2float(hi)) * 2048.0f);
}

// ---------- split-fp16 plane GEMM: C = A(MxK) * B^T(NxK) ----------
// A,B given as hi/lo half planes (lo pre-scaled by 2048).
enum { EPI_RESID = 0, EPI_QKV = 1 };

template<int WM, int WN, int FM, int FN, int EPI>
__global__ __launch_bounds__(256, 2)
void k_gemm_pk(const __half* __restrict__ Ah, const __half* __restrict__ Al, int lda,
               const __half* __restrict__ Bh, const __half* __restrict__ Bl, int ldb,
               float* __restrict__ Cf, int ldc, int M, int N, int K,
               const float* __restrict__ resid,
               __half* __restrict__ qh_p, __half* __restrict__ ql_p,
               __half* __restrict__ kh_p, __half* __restrict__ kl_p,
               __half* __restrict__ vth_p, __half* __restrict__ vtl_p,
               const float* __restrict__ rc, const float* __restrict__ rs)
{
    constexpr int BM = WM * FM * 16, BN = WN * FN * 16;
    constexpr int PITCH = 40;                  // halves: 32 + 8 pad
    __shared__ __half AsH[BM * PITCH], AsL[BM * PITCH];
    __shared__ __half BsH[BN * PITCH], BsL[BN * PITCH];
    const int tid = threadIdx.x;
    const int lane = tid & 63, w = tid >> 6;
    const int l15 = lane & 15, g = lane >> 4;
    const int wm = w / WN, wn = w % WN;
    const int m0 = blockIdx.x * BM, n0 = blockIdx.y * BN;

    f32x4 acc0[FM][FN] = {}; f32x4 acc1[FM][FN] = {};

    for (int k0 = 0; k0 < K; k0 += 32) {
        __syncthreads();
#pragma unroll
        for (int it = 0; it < BM / 64; ++it) {
            int c = it * 256 + tid, row = c >> 2, kg = c & 3;
            long src = (long)(m0 + row) * lda + k0 + kg * 8;
            *(uint4*)&AsH[row * PITCH + kg * 8] = *(const uint4*)(Ah + src);
            *(uint4*)&AsL[row * PITCH + kg * 8] = *(const uint4*)(Al + src);
        }
#pragma unroll
        for (int it = 0; it < BN / 64; ++it) {
            int c = it * 256 + tid, row = c >> 2, kg = c & 3;
            long src = (long)(n0 + row) * ldb + k0 + kg * 8;
            *(uint4*)&BsH[row * PITCH + kg * 8] = *(const uint4*)(Bh + src);
            *(uint4*)&BsL[row * PITCH + kg * 8] = *(const uint4*)(Bl + src);
        }
        __syncthreads();
        half8 ah[FM], al[FM];
#pragma unroll
        for (int i = 0; i < FM; ++i) {
            int ar = (wm * FM * 16 + i * 16 + l15) * PITCH + g * 8;
            ah[i] = *(const half8*)&AsH[ar];
            al[i] = *(const half8*)&AsL[ar];
        }
#pragma unroll
        for (int n = 0; n < FN; ++n) {
            int br = (wn * FN * 16 + n * 16 + l15) * PITCH + g * 8;
            half8 bh = *(const half8*)&BsH[br];
            half8 bl = *(const half8*)&BsL[br];
#pragma unroll
            for (int i = 0; i < FM; ++i) {
                acc0[i][n] = __builtin_amdgcn_mfma_f32_16x16x32_f16(ah[i], bh, acc0[i][n], 0, 0, 0);
                acc1[i][n] = __builtin_amdgcn_mfma_f32_16x16x32_f16(ah[i], bl, acc1[i][n], 0, 0, 0);
                acc1[i][n] = __builtin_amdgcn_mfma_f32_16x16x32_f16(al[i], bh, acc1[i][n], 0, 0, 0);
            }
        }
    }

#pragma unroll
    for (int i = 0; i < FM; ++i)
#pragma unroll
    for (int n = 0; n < FN; ++n)
#pragma unroll
    for (int j = 0; j < 4; ++j) {
        float v = acc0[i][n][j] + acc1[i][n][j] * (1.0f / 2048.0f);
        int gm = m0 + wm * FM * 16 + i * 16 + g * 4 + j;
        int gn = n0 + wn * FN * 16 + n * 16 + l15;
        if constexpr (EPI == EPI_RESID) {
            Cf[(long)gm * ldc + gn] = v + resid[(long)gm * ldc + gn];
        } else {
            // QKV epilogue: RoPE for q/k, transpose-scatter for v, split planes.
            int t = gm & 1023, b = gm >> 10;
            float vp = __shfl_xor(v, 1);       // pair column (uniform control flow)
            if (gn < 2048) {
                int col = gn & 1023;
                int i2 = (col & 63) >> 1;
                float cv = rc[t * 32 + i2], sv = rs[t * 32 + i2];
                float rot = cv * v + sv * ((lane & 1) ? vp : -vp);
                __half hi_, lo_; split2(rot, hi_, lo_);
                long o = ((long)(b * 16 + (col >> 6)) * 1024 + t) * 64 + (col & 63);
                if (gn < 1024) { qh_p[o] = hi_; ql_p[o] = lo_; }
                else           { kh_p[o] = hi_; kl_p[o] = lo_; }
            } else {
                int col = gn - 2048;
                __half hi_, lo_; split2(v, hi_, lo_);
                long o = ((long)(b * 16 + (col >> 6)) * 64 + (col & 63)) * 1024 + t;
                vth_p[o] = hi_; vtl_p[o] = lo_;
            }
        }
    }
}

// ---------- flash attention, split-fp16 planes ----------
// grid (16 q-tiles, 32 heads); 4 waves; wave owns 16 q-rows.
__global__ __launch_bounds__(256, 2)
void k_flash(const __half* __restrict__ qh_g, const __half* __restrict__ ql_g,
             const __half* __restrict__ kh_g, const __half* __restrict__ kl_g,
             const __half* __restrict__ vth_g, const __half* __restrict__ vtl_g,
             __half* __restrict__ oh_g, __half* __restrict__ ol_g)
{
    constexpr int P = 72;
    __shared__ __half KsH[64 * P], KsL[64 * P], VsH[64 * P], VsL[64 * P], PsH[64 * P], PsL[64 * P];
    const int tid = threadIdx.x, lane = tid & 63, w = tid >> 6;
    const int l15 = lane & 15, g = lane >> 4;
    const int q0 = blockIdx.x * 64;
    const int bh = blockIdx.y;
    const long base = (long)bh * 65536;

    half8 qhi[2], qlo[2];
    {
        long qoff = base + (long)(q0 + w * 16 + l15) * 64 + g * 8;
        qhi[0] = *(const half8*)(qh_g + qoff); qhi[1] = *(const half8*)(qh_g + qoff + 32);
        qlo[0] = *(const half8*)(ql_g + qoff); qlo[1] = *(const half8*)(ql_g + qoff + 32);
    }

    float m_[4] = {-1e30f, -1e30f, -1e30f, -1e30f};
    float l_[4] = {0.f, 0.f, 0.f, 0.f};
    f32x4 o0[4] = {}, o1[4] = {};

    for (int kt = 0; kt < 16; ++kt) {
        __syncthreads();
#pragma unroll
        for (int it = 0; it < 2; ++it) {
            int c = it * 256 + tid, row = c >> 3, kg = c & 7;
            long src = base + (long)(kt * 64 + row) * 64 + kg * 8;
            *(uint4*)&KsH[row * P + kg * 8] = *(const uint4*)(kh_g + src);
            *(uint4*)&KsL[row * P + kg * 8] = *(const uint4*)(kl_g + src);
            long vs = base + (long)row * 1024 + kt * 64 + kg * 8;
            *(uint4*)&VsH[row * P + kg * 8] = *(const uint4*)(vth_g + vs);
            *(uint4*)&VsL[row * P + kg * 8] = *(const uint4*)(vtl_g + vs);
        }
        __syncthreads();

        f32x4 s0[4] = {}, s1[4] = {};
#pragma unroll
        for (int cf = 0; cf < 4; ++cf) {
            int kr = (cf * 16 + l15) * P + g * 8;
            half8 kh0 = *(const half8*)&KsH[kr], kh1 = *(const half8*)&KsH[kr + 32];
            half8 kl0 = *(const half8*)&KsL[kr], kl1 = *(const half8*)&KsL[kr + 32];
            s0[cf] = __builtin_amdgcn_mfma_f32_16x16x32_f16(qhi[0], kh0, s0[cf], 0, 0, 0);
            s1[cf] = __builtin_amdgcn_mfma_f32_16x16x32_f16(qhi[0], kl0, s1[cf], 0, 0, 0);
            s1[cf] = __builtin_amdgcn_mfma_f32_16x16x32_f16(qlo[0], kh0, s1[cf], 0, 0, 0);
            s0[cf] = __builtin_amdgcn_mfma_f32_16x16x32_f16(qhi[1], kh1, s0[cf], 0, 0, 0);
            s1[cf] = __builtin_amdgcn_mfma_f32_16x16x32_f16(qhi[1], kl1, s1[cf], 0, 0, 0);
            s1[cf] = __builtin_amdgcn_mfma_f32_16x16x32_f16(qlo[1], kh1, s1[cf], 0, 0, 0);
        }

        // online softmax; lane holds rows g*4+j, cols cf*16+l15
#pragma unroll
        for (int j = 0; j < 4; ++j) {
            float sv[4];
#pragma unroll
            for (int cf = 0; cf < 4; ++cf)
                sv[cf] = (s0[cf][j] + s1[cf][j] * (1.0f / 2048.0f)) * 0.125f;
            float mx = fmaxf(fmaxf(sv[0], sv[1]), fmaxf(sv[2], sv[3]));
#pragma unroll
            for (int msk = 8; msk; msk >>= 1) mx = fmaxf(mx, __shfl_xor(mx, msk));
            float mn = fmaxf(m_[j], mx);
            float r = expf(m_[j] - mn);
            m_[j] = mn;
            float rs = 0.f;
#pragma unroll
            for (int cf = 0; cf < 4; ++cf) {
                float p = expf(sv[cf] - mn);
                rs += p;
                __half hi_, lo_; split2(p, hi_, lo_);
                PsH[(w * 16 + g * 4 + j) * P + cf * 16 + l15] = hi_;
                PsL[(w * 16 + g * 4 + j) * P + cf * 16 + l15] = lo_;
            }
#pragma unroll
            for (int msk = 8; msk; msk >>= 1) rs += __shfl_xor(rs, msk);
            l_[j] = l_[j] * r + rs;
#pragma unroll
            for (int df = 0; df < 4; ++df) { o0[df][j] *= r; o1[df][j] *= r; }
        }
        __syncthreads();

        int pr = (w * 16 + l15) * P + g * 8;
        half8 ph0 = *(const half8*)&PsH[pr], ph1 = *(const half8*)&PsH[pr + 32];
        half8 pl0 = *(const half8*)&PsL[pr], pl1 = *(const half8*)&PsL[pr + 32];
#pragma unroll
        for (int df = 0; df < 4; ++df) {
            int vr = (df * 16 + l15) * P + g * 8;
            half8 vh0 = *(const half8*)&VsH[vr], vh1 = *(const half8*)&VsH[vr + 32];
            half8 vl0 = *(const half8*)&VsL[vr], vl1 = *(const half8*)&VsL[vr + 32];
            o0[df] = __builtin_amdgcn_mfma_f32_16x16x32_f16(ph0, vh0, o0[df], 0, 0, 0);
            o1[df] = __builtin_amdgcn_mfma_f32_16x16x32_f16(ph0, vl0, o1[df], 0, 0, 0);
            o1[df] = __builtin_amdgcn_mfma_f32_16x16x32_f16(pl0, vh0, o1[df], 0, 0, 0);
            o0[df] = __builtin_amdgcn_mfma_f32_16x16x32_f16(ph1, vh1, o0[df], 0, 0, 0);
            o1[df] = __builtin_amdgcn_mfma_f32_16x16x32_f16(ph1, vl1, o1[df], 0, 0, 0);
            o1[df] = __builtin_amdgcn_mfma_f32_16x16x32_f16(pl1, vh1, o1[df], 0, 0, 0);
        }
    }

    float invl[4];
#pragma unroll
    for (int j = 0; j < 4; ++j) invl[j] = 1.0f / l_[j];
    const int b = bh >> 4, hh = bh & 15;
#pragma unroll
    for (int df = 0; df < 4; ++df)
#pragma unroll
    for (int j = 0; j < 4; ++j) {
        float v = (o0[df][j] + o1[df][j] * (1.0f / 2048.0f)) * invl[j];
        long orow = (long)b * 1024 + q0 + w * 16 + g * 4 + j;
        int col = hh * 64 + df * 16 + l15;
        __half hi_, lo_; split2(v, hi_, lo_);
        oh_g[orow * 1024 + col] = hi_;
        ol_g[orow * 1024 + col] = lo_;
    }
}

// ---------- MoE grouped GEMM, B = fp32 expert weights read directly ----------
// MODE 0: GEMM1 — B cols paired (h1,h2 interleaved per 16), SiLU fused, act fp16 out.
// MODE 1: GEMM2 — B direct, f32 out.
template<bool GATHER, int MODE>
__global__ __launch_bounds__(256, 2)
void k_gemm_moe(const __half* __restrict__ A, int lda, const int* __restrict__ rowidx,
                const Desc* __restrict__ desc, const int* __restrict__ ntiles,
                const float* __restrict__ Bbase, long sB, int ldb,
                void* __restrict__ Cv, int K)
{
    if ((int)blockIdx.x >= *ntiles) return;
    Desc d = desc[blockIdx.x];
    const float* Bp = Bbase + (long)d.e * sB;
    constexpr int PITCH = 40;
    __shared__ __half As[128 * PITCH];
    __shared__ __half Bs[128 * PITCH];
    const int tid = threadIdx.x, lane = tid & 63, w = tid >> 6;
    const int l15 = lane & 15, g = lane >> 4;
    const int wm = w >> 1, wn = w & 1;
    const int n0 = blockIdx.y * (MODE == 0 ? 64 : 128);   // logical j0 (MODE0) / col0

    f32x4 acc[4][4] = {};
    for (int k0 = 0; k0 < K; k0 += 32) {
        __syncthreads();
#pragma unroll
        for (int it = 0; it < 2; ++it) {
            int c = it * 256 + tid, row = c >> 2, kg = c & 3;
            uint4 v = make_uint4(0, 0, 0, 0);
            if constexpr (GATHER) {
                if (row < d.rows) {
                    int ar = rowidx[d.base + row];
                    v = *(const uint4*)(A + (long)ar * lda + k0 + kg * 8);
                }
            } else {
                v = *(const uint4*)(A + (long)(d.base + row) * lda + k0 + kg * 8);
            }
            *(uint4*)&As[row * PITCH + kg * 8] = v;
        }
        // B: transpose-convert fp32 [k][col] -> Bs[n][k] fp16
#pragma unroll
        for (int it = 0; it < 2; ++it) {
            int c = it * 256 + tid;
            int kp = c >> 5, n4 = c & 31;     // 16 k-pairs x 32 col-groups
            int p0 = n4 * 4;
            int scol;
            if constexpr (MODE == 0) {
                int pb = p0 >> 4, w4 = p0 & 15;
                scol = ((pb & 1) ? 2048 : 0) + n0 + (pb >> 1) * 16 + w4;
            } else {
                scol = n0 + p0;
            }
            const float* b0 = Bp + (long)(k0 + 2 * kp) * ldb + scol;
            float4 r0 = *(const float4*)b0;
            float4 r1 = *(const float4*)(b0 + ldb);
            float a0[4] = {r0.x, r0.y, r0.z, r0.w};
            float a1[4] = {r1.x, r1.y, r1.z, r1.w};
#pragma unroll
            for (int m = 0; m < 4; ++m) {
                __half2 hv = __halves2half2(__float2half(a0[m]), __float2half(a1[m]));
                *(__half2*)&Bs[(p0 + m) * PITCH + 2 * kp] = hv;
            }
        }
        __syncthreads();
        half8 a[4];
#pragma unroll
        for (int i = 0; i < 4; ++i)
            a[i] = *(const half8*)&As[(wm * 64 + i * 16 + l15) * PITCH + g * 8];
#pragma unroll
        for (int n = 0; n < 4; ++n) {
            half8 b = *(const half8*)&Bs[(wn * 64 + n * 16 + l15) * PITCH + g * 8];
#pragma unroll
            for (int i = 0; i < 4; ++i)
                acc[i][n] = __builtin_amdgcn_mfma_f32_16x16x32_f16(a[i], b, acc[i][n], 0, 0, 0);
        }
    }

    if constexpr (MODE == 0) {
#pragma unroll
        for (int i = 0; i < 4; ++i)
#pragma unroll
        for (int p = 0; p < 2; ++p)
#pragma unroll
        for (int j = 0; j < 4; ++j) {
            int rl = wm * 64 + i * 16 + g * 4 + j;
            float h1 = acc[i][2 * p][j], h2 = acc[i][2 * p + 1][j];
            float a = h1 / (1.0f + expf(-h1)) * h2;
            if (rl >= d.rows) a = 0.0f;
            int jc = n0 + wn * 32 + p * 16 + l15;
            ((__half*)Cv)[(long)(d.base + rl) * 2048 + jc] = __float2half(a);
        }
    } else {
#pragma unroll
        for (int i = 0; i < 4; ++i)
#pragma unroll
        for (int n = 0; n < 4; ++n)
#pragma unroll
        for (int j = 0; j < 4; ++j) {
            int rl = wm * 64 + i * 16 + g * 4 + j;
            int gn = n0 + wn * 64 + n * 16 + l15;
            ((float*)Cv)[(long)(d.base + rl) * 1024 + gn] = acc[i][n][j];
        }
    }
}

// ---------- transpose fp32 [R][C] -> [C][R], split-fp16 planes out ----------
__global__ __launch_bounds__(256) void k_transpose_pk(const float* __restrict__ src,
    __half* __restrict__ dsth, __half* __restrict__ dstl, int R, int C)
{
    __shared__ float t[64][65];
    const int tid = threadIdx.x;
    const int c0 = blockIdx.x * 64, r0 = blockIdx.y * 64;
#pragma unroll
    for (int it = 0; it < 4; ++it) {
        int idx = it * 256 + tid;
        int r = idx >> 4, c4 = (idx & 15) * 4;
        float4 v = *(const float4*)(src + (long)(r0 + r) * C + c0 + c4);
        t[r][c4] = v.x; t[r][c4 + 1] = v.y; t[r][c4 + 2] = v.z; t[r][c4 + 3] = v.w;
    }
    __syncthreads();
#pragma unroll
    for (int it = 0; it < 4; ++it) {
        int idx = it * 256 + tid;
        int orow = idx >> 4, oc = (idx & 15) * 4;
        __half hs[4], ls[4];
#pragma unroll
        for (int m = 0; m < 4; ++m) split2(t[oc + m][orow], hs[m], ls[m]);
        long o = (long)(c0 + orow) * R + r0 + oc;
        *(uint2*)&dsth[o] = *(uint2*)hs;
        *(uint2*)&dstl[o] = *(uint2*)ls;
    }
}

// ---------- LayerNorm (D=1024, one block per row) ----------
template<int MODE> // 0: hi/lo plane out; 1: f32 + plain fp16 out
__global__ __launch_bounds__(256) void k_ln(const float* __restrict__ X,
    const float* __restrict__ g, const float* __restrict__ bta,
    void* __restrict__ o1, void* __restrict__ o2)
{
    __shared__ float red[4];
    const long row = blockIdx.x;
    const float* xr = X + row * 1024;
    const int c = threadIdx.x * 4;
    float4 v = *(const float4*)(xr + c);
    float mu = blockReduceSum(v.x + v.y + v.z + v.w, red) * (1.0f / 1024.0f);
    float d0 = v.x - mu, d1 = v.y - mu, d2 = v.z - mu, d3 = v.w - mu;
    float var = blockReduceSum(d0 * d0 + d1 * d1 + d2 * d2 + d3 * d3, red) * (1.0f / 1024.0f);
    float rs = 1.0f / sqrtf(var + 1e-5f);
    float4 gv = *(const float4*)(g + c);
    float4 bv = *(const float4*)(bta + c);
    float y[4] = {d0 * rs * gv.x + bv.x, d1 * rs * gv.y + bv.y,
                  d2 * rs * gv.z + bv.z, d3 * rs * gv.w + bv.w};
    if constexpr (MODE == 0) {
        __half hs[4], ls[4];
#pragma unroll
        for (int m = 0; m < 4; ++m) split2(y[m], hs[m], ls[m]);
        *(uint2*)((__half*)o1 + row * 1024 + c) = *(uint2*)hs;
        *(uint2*)((__half*)o2 + row * 1024 + c) = *(uint2*)ls;
    } else {
        *(float4*)((float*)o1 + row * 1024 + c) = make_float4(y[0], y[1], y[2], y[3]);
        __half hs[4];
#pragma unroll
        for (int m = 0; m < 4; ++m) hs[m] = __float2half(y[m]);
        *(uint2*)((__half*)o2 + row * 1024 + c) = *(uint2*)hs;
    }
}

// ---------- RoPE cos/sin table ----------
__global__ __launch_bounds__(256) void k_rope_table(float* __restrict__ ct, float* __restrict__ st)
{
    int idx = blockIdx.x * 256 + threadIdx.x; // 32768 = 1024 t x 32 i
    int t = idx >> 5, i = idx & 31;
    float inv = 1.0f / (float)pow(10000.0, (double)i / 32.0);
    float ang = (float)t * inv;
    ct[idx] = cosf(ang);
    st[idx] = sinf(ang);
}

// ---------- gating: fp32 scores, top-2, no global atomics ----------
__global__ __launch_bounds__(256) void k_gate(const float* __restrict__ xn2,
    const float* __restrict__ gw, const float* __restrict__ eb,
    int* __restrict__ topidx, float* __restrict__ gates,
    float* __restrict__ pprob)
{
    __shared__ float pp[4][8];
    const int lane = threadIdx.x & 63, w = threadIdx.x >> 6;
    const int t = blockIdx.x * 4 + w;
    const float* xr = xn2 + (long)t * 1024;
    float sc[8] = {0, 0, 0, 0, 0, 0, 0, 0};
#pragma unroll
    for (int i = 0; i < 4; ++i) {
        int d = i * 256 + lane * 4;
        float4 xv = *(const float4*)(xr + d);
        float xa[4] = {xv.x, xv.y, xv.z, xv.w};
#pragma unroll
        for (int j = 0; j < 4; ++j) {
            float xx = xa[j];
            const float4* gp = (const float4*)(gw + (long)(d + j) * 8);
            float4 g0 = gp[0], g1 = gp[1];
            sc[0] += xx * g0.x; sc[1] += xx * g0.y; sc[2] += xx * g0.z; sc[3] += xx * g0.w;
            sc[4] += xx * g1.x; sc[5] += xx * g1.y; sc[6] += xx * g1.z; sc[7] += xx * g1.w;
        }
    }
#pragma unroll
    for (int e = 0; e < 8; ++e) {
#pragma unroll
        for (int m = 32; m; m >>= 1) sc[e] += __shfl_xor(sc[e], m);
        sc[e] += eb[e];
    }
    if (lane == 0) {
        int i1 = 0; float v1 = sc[0];
        for (int e = 1; e < 8; ++e) if (sc[e] > v1) { v1 = sc[e]; i1 = e; }
        int i2 = (i1 == 0) ? 1 : 0; float v2 = sc[i2];
        for (int e = 0; e < 8; ++e) if (e != i1 && sc[e] > v2) { v2 = sc[e]; i2 = e; }
        float e2 = expf(v2 - v1);
        gates[t * 2] = 1.0f / (1.0f + e2);
        gates[t * 2 + 1] = e2 / (1.0f + e2);
        topidx[t * 2] = i1; topidx[t * 2 + 1] = i2;
        float mxx = sc[0];
        for (int e = 1; e < 8; ++e) mxx = fmaxf(mxx, sc[e]);
        float se = 0.0f, pe[8];
        for (int e = 0; e < 8; ++e) { pe[e] = expf(sc[e] - mxx); se += pe[e]; }
        float inv = 1.0f / se;
        for (int e = 0; e < 8; ++e) pp[w][e] = pe[e] * inv;
    }
    __syncthreads();
    if (threadIdx.x < 8)
        pprob[(long)blockIdx.x * 8 + threadIdx.x] =
            pp[0][threadIdx.x] + pp[1][threadIdx.x] + pp[2][threadIdx.x] + pp[3][threadIdx.x];
}

// ---------- routing ----------
__global__ __launch_bounds__(256) void k_route(const int* __restrict__ topidx,
    int* __restrict__ rowidx, int* __restrict__ invpos,
    int* __restrict__ ntiles, Desc* __restrict__ desc, int* __restrict__ cnt)
{
    __shared__ int cnt_s[8], base_s[8], fill[8];
    const int tid = threadIdx.x;
    if (tid < 8) { cnt_s[tid] = 0; fill[tid] = 0; }
    __syncthreads();
    for (int i = tid; i < 4096; i += 256)
        atomicAdd(&cnt_s[topidx[i]], 1);
    __syncthreads();
    if (tid == 0) {
        int nt = 0, running = 0;
        for (int e = 0; e < 8; ++e) {
            int ce = cnt_s[e];
            cnt[e] = ce;
            base_s[e] = running;
            int tl = (ce + 127) >> 7;
            for (int j = 0; j < tl; ++j) {
                desc[nt].e = e; desc[nt].base = running + j * 128;
                desc[nt].rows = min(128, ce - j * 128);
                ++nt;
            }
            running += tl * 128;
        }
        *ntiles = nt;
    }
    __syncthreads();
    for (int t = tid; t < 2048; t += 256) {
#pragma unroll
        for (int s = 0; s < 2; ++s) {
            int e = topidx[t * 2 + s];
            int p = base_s[e] + atomicAdd(&fill[e], 1);
            rowidx[p] = t;
            invpos[t * 2 + s] = p;
        }
    }
}

// ---------- combine ----------
__global__ __launch_bounds__(256) void k_combine(const float* __restrict__ x1,
    const float* __restrict__ eo, const int* __restrict__ invpos,
    const float* __restrict__ gates, float* __restrict__ out)
{
    const int t = blockIdx.x, c = threadIdx.x * 4;
    float g0 = gates[t * 2], g1 = gates[t * 2 + 1];
    int p0 = invpos[t * 2], p1 = invpos[t * 2 + 1];
    float4 xv = *(const float4*)(x1 + (long)t * 1024 + c);
    float4 e0 = *(const float4*)(eo + (long)p0 * 1024 + c);
    float4 e1 = *(const float4*)(eo + (long)p1 * 1024 + c);
    float4 o;
    o.x = xv.x + g0 * e0.x + g1 * e1.x;
    o.y = xv.y + g0 * e0.y + g1 * e1.y;
    o.z = xv.z + g0 * e0.z + g1 * e1.z;
    o.w = xv.w + g0 * e0.w + g1 * e1.w;
    *(float4*)(out + (long)t * 1024 + c) = o;
}

// ---------- loss ----------
__global__ __launch_bounds__(256) void k_loss(const int* __restrict__ cnt,
    const float* __restrict__ pprob, float* __restrict__ out)
{
    __shared__ float m[32][8];
    const int tid = threadIdx.x;
    const int e = tid & 7, g = tid >> 3;
    float local = 0.0f;
    for (int b = g; b < 512; b += 32) local += pprob[b * 8 + e];
    m[g][e] = local;
    __syncthreads();
    if (tid == 0) {
        float us = 0, ps = 0, pe[8], ue[8];
        for (int ee = 0; ee < 8; ++ee) {
            float s = 0;
            for (int gg = 0; gg < 32; ++gg) s += m[gg][ee];
            pe[ee] = s; ps += s;
            ue[ee] = (float)cnt[ee]; us += ue[ee];
        }
        float lb = 0;
        for (int ee = 0; ee < 8; ++ee) lb += (ue[ee] / us) * (pe[ee] / ps);
        out[2097152] = lb * 8.0f;
    }
}

// =====================  launch  =====================
extern "C" void kernel_launch(void* const* d_in, const int* in_sizes, int n_in,
                              void* d_out, int out_size, void* d_ws, size_t ws_size,
                              hipStream_t stream)
{
    const float* x    = (const float*)d_in[0];
    const float* ln1g = (const float*)d_in[1];
    const float* ln1b = (const float*)d_in[2];
    const float* qkvw = (const float*)d_in[3];
    const float* outw = (const float*)d_in[4];
    const float* ln2g = (const float*)d_in[5];
    const float* ln2b = (const float*)d_in[6];
    const float* gw   = (const float*)d_in[7];
    const float* eb   = (const float*)d_in[8];
    const float* w1   = (const float*)d_in[9];
    const float* w2   = (const float*)d_in[10];
    float* out = (float*)d_out;
    char* ws = (char*)d_ws;

    // workspace map (bytes), total ~122 MB
    constexpr size_t OFF_QWTH = 0;          // half [3072][1024]
    constexpr size_t OFF_QWTL = 6291456;
    constexpr size_t OFF_OWTH = 12582912;   // half [1024][1024]
    constexpr size_t OFF_OWTL = 14680064;
    constexpr size_t OFF_XN1H = 16777216;   // half [2048][1024]
    constexpr size_t OFF_XN1L = 20971520;
    constexpr size_t OFF_QH   = 25165824;   // half [32][1024][64]
    constexpr size_t OFF_QL   = 29360128;
    constexpr size_t OFF_KH   = 33554432;
    constexpr size_t OFF_KL   = 37748736;
    constexpr size_t OFF_VTH  = 41943040;   // half [32][64][1024]
    constexpr size_t OFF_VTL  = 46137344;
    constexpr size_t OFF_OH   = 50331648;   // half [2048][1024]
    constexpr size_t OFF_OL   = 54525952;
    constexpr size_t OFF_X1   = 58720256;   // f32 [2048][1024]
    constexpr size_t OFF_XN2F = 67108864;   // f32
    constexpr size_t OFF_XN2H = 75497472;   // half
    constexpr size_t OFF_RC   = 79691776;   // f32 [1024][32]
    constexpr size_t OFF_RS   = 79822848;
    constexpr size_t OFF_IDX  = 79953920;   // int [2048][2]
    constexpr size_t OFF_GATES= 79970304;   // f32 [2048][2]
    constexpr size_t OFF_INVP = 79986688;   // int [2048][2]
    constexpr size_t OFF_ROWI = 80003072;   // int [5120]
    constexpr size_t OFF_CNT  = 80023552;   // int [8]
    constexpr size_t OFF_NT   = 80023616;   // int
    constexpr size_t OFF_DESC = 80023680;   // Desc [40]
    constexpr size_t OFF_PPROB= 80024704;   // f32 [512][8]
    constexpr size_t OFF_ACT  = 80041984;   // half [5120][2048]
    constexpr size_t OFF_EO   = 101013504;  // f32 [5120][1024]

    __half* qwth = (__half*)(ws + OFF_QWTH);
    __half* qwtl = (__half*)(ws + OFF_QWTL);
    __half* owth = (__half*)(ws + OFF_OWTH);
    __half* owtl = (__half*)(ws + OFF_OWTL);
    __half* xn1h = (__half*)(ws + OFF_XN1H);
    __half* xn1l = (__half*)(ws + OFF_XN1L);
    __half* qh   = (__half*)(ws + OFF_QH);
    __half* ql   = (__half*)(ws + OFF_QL);
    __half* kh   = (__half*)(ws + OFF_KH);
    __half* kl   = (__half*)(ws + OFF_KL);
    __half* vth  = (__half*)(ws + OFF_VTH);
    __half* vtl  = (__half*)(ws + OFF_VTL);
    __half* oh   = (__half*)(ws + OFF_OH);
    __half* ol   = (__half*)(ws + OFF_OL);
    float* x1    = (float*)(ws + OFF_X1);
    float* xn2f  = (float*)(ws + OFF_XN2F);
    __half* xn2h = (__half*)(ws + OFF_XN2H);
    float* rc    = (float*)(ws + OFF_RC);
    float* rs    = (float*)(ws + OFF_RS);
    int*   idx   = (int*)(ws + OFF_IDX);
    float* gates = (float*)(ws + OFF_GATES);
    int*   invp  = (int*)(ws + OFF_INVP);
    int*   rowi  = (int*)(ws + OFF_ROWI);
    int*   cnt   = (int*)(ws + OFF_CNT);
    int*   nt    = (int*)(ws + OFF_NT);
    Desc*  desc  = (Desc*)(ws + OFF_DESC);
    float* pprob = (float*)(ws + OFF_PPROB);
    __half* act  = (__half*)(ws + OFF_ACT);
    float* eo    = (float*)(ws + OFF_EO);

    // weight transposes -> split planes
    k_transpose_pk<<<dim3(48, 16, 1), 256, 0, stream>>>(qkvw, qwth, qwtl, 1024, 3072);
    k_transpose_pk<<<dim3(16, 16, 1), 256, 0, stream>>>(outw, owth, owtl, 1024, 1024);
    k_rope_table<<<dim3(128), 256, 0, stream>>>(rc, rs);

    // LN1 -> xn1 planes
    k_ln<0><<<dim3(2048), 256, 0, stream>>>(x, ln1g, ln1b, xn1h, xn1l);

    // QKV GEMM with fused RoPE + q/k/v scatter (64x128 tiles, 768 blocks)
    k_gemm_pk<2, 2, 2, 4, EPI_QKV><<<dim3(32, 24, 1), 256, 0, stream>>>(
        xn1h, xn1l, 1024, qwth, qwtl, 1024, nullptr, 0, 2048, 3072, 1024,
        nullptr, qh, ql, kh, kl, vth, vtl, rc, rs);

    // flash attention -> o planes
    k_flash<<<dim3(16, 32, 1), 256, 0, stream>>>(qh, ql, kh, kl, vth, vtl, oh, ol);

    // x1 = x + o @ out_w
    k_gemm_pk<2, 2, 2, 2, EPI_RESID><<<dim3(32, 16, 1), 256, 0, stream>>>(
        oh, ol, 1024, owth, owtl, 1024, x1, 1024, 2048, 1024, 1024,
        x, nullptr, nullptr, nullptr, nullptr, nullptr, nullptr, nullptr, nullptr);

    // LN2 -> xn2 (f32 for gating, fp16 for MoE)
    k_ln<1><<<dim3(2048), 256, 0, stream>>>(x1, ln2g, ln2b, xn2f, xn2h);

    // gating + routing
    k_gate<<<dim3(512), 256, 0, stream>>>(xn2f, gw, eb, idx, gates, pprob);
    k_route<<<dim3(1), 256, 0, stream>>>(idx, rowi, invp, nt, desc, cnt);

    // MoE GEMM1: act = silu(h1)*h2, B = w1 fp32 direct (paired cols)
    k_gemm_moe<true, 0><<<dim3(40, 32, 1), 256, 0, stream>>>(
        xn2h, 1024, rowi, desc, nt, w1, 4194304, 4096, act, 1024);

    // MoE GEMM2: eo = act @ w2[e], B = w2 fp32 direct
    k_gemm_moe<false, 1><<<dim3(40, 8, 1), 256, 0, stream>>>(
        act, 2048, nullptr, desc, nt, w2, 2097152, 1024, eo, 2048);

    // combine + loss
    k_combine<<<dim3(2048), 256, 0, stream>>>(x1, eo, invp, gates, out);
    k_loss<<<dim3(1), 256, 0, stream>>>(cnt, pprob, out);
}

// Round 5
// 422.901 us; speedup vs baseline: 2.1748x; 1.1418x over previous
//
#include <hip/hip_runtime.h>
#include <hip/hip_fp16.h>

// UnifiedTransformerBlock on MI355X.
// R5: MoE weights converted ONCE to transposed fp16 (k_wconv) — R4's direct
// fp32 B-streaming caused 292MB/dispatch HBM fetch + 16-way LDS bank
// conflicts (4.1e7).  SiLU stays fused in GEMM1 epilogue (pairing done via
// B-row index math on w1t).  QKV fused RoPE epilogue + split-plane GEMMs kept.

typedef _Float16 half8 __attribute__((ext_vector_type(8)));
typedef float f32x4 __attribute__((ext_vector_type(4)));

#define DI __device__ __forceinline__

struct Desc { int e, base, rows; };

DI float blockReduceSum(float v, float* red) {
#pragma unroll
    for (int m = 32; m; m >>= 1) v += __shfl_xor(v, m);
    int w = threadIdx.x >> 6;
    if ((threadIdx.x & 63) == 0) red[w] = v;
    __syncthreads();
    v = red[0] + red[1] + red[2] + red[3];
    __syncthreads();
    return v;
}

DI void split2(float v, __half& hi, __half& lo) {
    hi = __float2half(v);
    lo = __float2half((v - __half2float(hi)) * 2048.0f);
}

// ---------- split-fp16 plane GEMM: C = A(MxK) * B^T(NxK) ----------
enum { EPI_RESID = 0, EPI_QKV = 1 };

template<int WM, int WN, int FM, int FN, int EPI>
__global__ __launch_bounds__(256, 2)
void k_gemm_pk(const __half* __restrict__ Ah, const __half* __restrict__ Al, int lda,
               const __half* __restrict__ Bh, const __half* __restrict__ Bl, int ldb,
               float* __restrict__ Cf, int ldc, int M, int N, int K,
               const float* __restrict__ resid,
               __half* __restrict__ qh_p, __half* __restrict__ ql_p,
               __half* __restrict__ kh_p, __half* __restrict__ kl_p,
               __half* __restrict__ vth_p, __half* __restrict__ vtl_p,
               const float* __restrict__ rc, const float* __restrict__ rs)
{
    constexpr int BM = WM * FM * 16, BN = WN * FN * 16;
    constexpr int PITCH = 40;                  // halves: 32 + 8 pad
    __shared__ __half AsH[BM * PITCH], AsL[BM * PITCH];
    __shared__ __half BsH[BN * PITCH], BsL[BN * PITCH];
    const int tid = threadIdx.x;
    const int lane = tid & 63, w = tid >> 6;
    const int l15 = lane & 15, g = lane >> 4;
    const int wm = w / WN, wn = w % WN;
    const int m0 = blockIdx.x * BM, n0 = blockIdx.y * BN;

    f32x4 acc0[FM][FN] = {}; f32x4 acc1[FM][FN] = {};

    for (int k0 = 0; k0 < K; k0 += 32) {
        __syncthreads();
#pragma unroll
        for (int it = 0; it < BM / 64; ++it) {
            int c = it * 256 + tid, row = c >> 2, kg = c & 3;
            long src = (long)(m0 + row) * lda + k0 + kg * 8;
            *(uint4*)&AsH[row * PITCH + kg * 8] = *(const uint4*)(Ah + src);
            *(uint4*)&AsL[row * PITCH + kg * 8] = *(const uint4*)(Al + src);
        }
#pragma unroll
        for (int it = 0; it < BN / 64; ++it) {
            int c = it * 256 + tid, row = c >> 2, kg = c & 3;
            long src = (long)(n0 + row) * ldb + k0 + kg * 8;
            *(uint4*)&BsH[row * PITCH + kg * 8] = *(const uint4*)(Bh + src);
            *(uint4*)&BsL[row * PITCH + kg * 8] = *(const uint4*)(Bl + src);
        }
        __syncthreads();
        half8 ah[FM], al[FM];
#pragma unroll
        for (int i = 0; i < FM; ++i) {
            int ar = (wm * FM * 16 + i * 16 + l15) * PITCH + g * 8;
            ah[i] = *(const half8*)&AsH[ar];
            al[i] = *(const half8*)&AsL[ar];
        }
#pragma unroll
        for (int n = 0; n < FN; ++n) {
            int br = (wn * FN * 16 + n * 16 + l15) * PITCH + g * 8;
            half8 bh = *(const half8*)&BsH[br];
            half8 bl = *(const half8*)&BsL[br];
#pragma unroll
            for (int i = 0; i < FM; ++i) {
                acc0[i][n] = __builtin_amdgcn_mfma_f32_16x16x32_f16(ah[i], bh, acc0[i][n], 0, 0, 0);
                acc1[i][n] = __builtin_amdgcn_mfma_f32_16x16x32_f16(ah[i], bl, acc1[i][n], 0, 0, 0);
                acc1[i][n] = __builtin_amdgcn_mfma_f32_16x16x32_f16(al[i], bh, acc1[i][n], 0, 0, 0);
            }
        }
    }

#pragma unroll
    for (int i = 0; i < FM; ++i)
#pragma unroll
    for (int n = 0; n < FN; ++n)
#pragma unroll
    for (int j = 0; j < 4; ++j) {
        float v = acc0[i][n][j] + acc1[i][n][j] * (1.0f / 2048.0f);
        int gm = m0 + wm * FM * 16 + i * 16 + g * 4 + j;
        int gn = n0 + wn * FN * 16 + n * 16 + l15;
        if constexpr (EPI == EPI_RESID) {
            Cf[(long)gm * ldc + gn] = v + resid[(long)gm * ldc + gn];
        } else {
            // QKV epilogue: RoPE for q/k, transpose-scatter for v, split planes.
            int t = gm & 1023, b = gm >> 10;
            float vp = __shfl_xor(v, 1);       // pair column (uniform control flow)
            if (gn < 2048) {
                int col = gn & 1023;
                int i2 = (col & 63) >> 1;
                float cv = rc[t * 32 + i2], sv = rs[t * 32 + i2];
                float rot = cv * v + sv * ((lane & 1) ? vp : -vp);
                __half hi_, lo_; split2(rot, hi_, lo_);
                long o = ((long)(b * 16 + (col >> 6)) * 1024 + t) * 64 + (col & 63);
                if (gn < 1024) { qh_p[o] = hi_; ql_p[o] = lo_; }
                else           { kh_p[o] = hi_; kl_p[o] = lo_; }
            } else {
                int col = gn - 2048;
                __half hi_, lo_; split2(v, hi_, lo_);
                long o = ((long)(b * 16 + (col >> 6)) * 64 + (col & 63)) * 1024 + t;
                vth_p[o] = hi_; vtl_p[o] = lo_;
            }
        }
    }
}

// ---------- flash attention, split-fp16 planes ----------
__global__ __launch_bounds__(256, 2)
void k_flash(const __half* __restrict__ qh_g, const __half* __restrict__ ql_g,
             const __half* __restrict__ kh_g, const __half* __restrict__ kl_g,
             const __half* __restrict__ vth_g, const __half* __restrict__ vtl_g,
             __half* __restrict__ oh_g, __half* __restrict__ ol_g)
{
    constexpr int P = 72;
    __shared__ __half KsH[64 * P], KsL[64 * P], VsH[64 * P], VsL[64 * P], PsH[64 * P], PsL[64 * P];
    const int tid = threadIdx.x, lane = tid & 63, w = tid >> 6;
    const int l15 = lane & 15, g = lane >> 4;
    const int q0 = blockIdx.x * 64;
    const int bh = blockIdx.y;
    const long base = (long)bh * 65536;

    half8 qhi[2], qlo[2];
    {
        long qoff = base + (long)(q0 + w * 16 + l15) * 64 + g * 8;
        qhi[0] = *(const half8*)(qh_g + qoff); qhi[1] = *(const half8*)(qh_g + qoff + 32);
        qlo[0] = *(const half8*)(ql_g + qoff); qlo[1] = *(const half8*)(ql_g + qoff + 32);
    }

    float m_[4] = {-1e30f, -1e30f, -1e30f, -1e30f};
    float l_[4] = {0.f, 0.f, 0.f, 0.f};
    f32x4 o0[4] = {}, o1[4] = {};

    for (int kt = 0; kt < 16; ++kt) {
        __syncthreads();
#pragma unroll
        for (int it = 0; it < 2; ++it) {
            int c = it * 256 + tid, row = c >> 3, kg = c & 7;
            long src = base + (long)(kt * 64 + row) * 64 + kg * 8;
            *(uint4*)&KsH[row * P + kg * 8] = *(const uint4*)(kh_g + src);
            *(uint4*)&KsL[row * P + kg * 8] = *(const uint4*)(kl_g + src);
            long vs = base + (long)row * 1024 + kt * 64 + kg * 8;
            *(uint4*)&VsH[row * P + kg * 8] = *(const uint4*)(vth_g + vs);
            *(uint4*)&VsL[row * P + kg * 8] = *(const uint4*)(vtl_g + vs);
        }
        __syncthreads();

        f32x4 s0[4] = {}, s1[4] = {};
#pragma unroll
        for (int cf = 0; cf < 4; ++cf) {
            int kr = (cf * 16 + l15) * P + g * 8;
            half8 kh0 = *(const half8*)&KsH[kr], kh1 = *(const half8*)&KsH[kr + 32];
            half8 kl0 = *(const half8*)&KsL[kr], kl1 = *(const half8*)&KsL[kr + 32];
            s0[cf] = __builtin_amdgcn_mfma_f32_16x16x32_f16(qhi[0], kh0, s0[cf], 0, 0, 0);
            s1[cf] = __builtin_amdgcn_mfma_f32_16x16x32_f16(qhi[0], kl0, s1[cf], 0, 0, 0);
            s1[cf] = __builtin_amdgcn_mfma_f32_16x16x32_f16(qlo[0], kh0, s1[cf], 0, 0, 0);
            s0[cf] = __builtin_amdgcn_mfma_f32_16x16x32_f16(qhi[1], kh1, s0[cf], 0, 0, 0);
            s1[cf] = __builtin_amdgcn_mfma_f32_16x16x32_f16(qhi[1], kl1, s1[cf], 0, 0, 0);
            s1[cf] = __builtin_amdgcn_mfma_f32_16x16x32_f16(qlo[1], kh1, s1[cf], 0, 0, 0);
        }

#pragma unroll
        for (int j = 0; j < 4; ++j) {
            float sv[4];
#pragma unroll
            for (int cf = 0; cf < 4; ++cf)
                sv[cf] = (s0[cf][j] + s1[cf][j] * (1.0f / 2048.0f)) * 0.125f;
            float mx = fmaxf(fmaxf(sv[0], sv[1]), fmaxf(sv[2], sv[3]));
#pragma unroll
            for (int msk = 8; msk; msk >>= 1) mx = fmaxf(mx, __shfl_xor(mx, msk));
            float mn = fmaxf(m_[j], mx);
            float r = expf(m_[j] - mn);
            m_[j] = mn;
            float rs = 0.f;
#pragma unroll
            for (int cf = 0; cf < 4; ++cf) {
                float p = expf(sv[cf] - mn);
                rs += p;
                __half hi_, lo_; split2(p, hi_, lo_);
                PsH[(w * 16 + g * 4 + j) * P + cf * 16 + l15] = hi_;
                PsL[(w * 16 + g * 4 + j) * P + cf * 16 + l15] = lo_;
            }
#pragma unroll
            for (int msk = 8; msk; msk >>= 1) rs += __shfl_xor(rs, msk);
            l_[j] = l_[j] * r + rs;
#pragma unroll
            for (int df = 0; df < 4; ++df) { o0[df][j] *= r; o1[df][j] *= r; }
        }
        __syncthreads();

        int pr = (w * 16 + l15) * P + g * 8;
        half8 ph0 = *(const half8*)&PsH[pr], ph1 = *(const half8*)&PsH[pr + 32];
        half8 pl0 = *(const half8*)&PsL[pr], pl1 = *(const half8*)&PsL[pr + 32];
#pragma unroll
        for (int df = 0; df < 4; ++df) {
            int vr = (df * 16 + l15) * P + g * 8;
            half8 vh0 = *(const half8*)&VsH[vr], vh1 = *(const half8*)&VsH[vr + 32];
            half8 vl0 = *(const half8*)&VsL[vr], vl1 = *(const half8*)&VsL[vr + 32];
            o0[df] = __builtin_amdgcn_mfma_f32_16x16x32_f16(ph0, vh0, o0[df], 0, 0, 0);
            o1[df] = __builtin_amdgcn_mfma_f32_16x16x32_f16(ph0, vl0, o1[df], 0, 0, 0);
            o1[df] = __builtin_amdgcn_mfma_f32_16x16x32_f16(pl0, vh0, o1[df], 0, 0, 0);
            o0[df] = __builtin_amdgcn_mfma_f32_16x16x32_f16(ph1, vh1, o0[df], 0, 0, 0);
            o1[df] = __builtin_amdgcn_mfma_f32_16x16x32_f16(ph1, vl1, o1[df], 0, 0, 0);
            o1[df] = __builtin_amdgcn_mfma_f32_16x16x32_f16(pl1, vh1, o1[df], 0, 0, 0);
        }
    }

    float invl[4];
#pragma unroll
    for (int j = 0; j < 4; ++j) invl[j] = 1.0f / l_[j];
    const int b = bh >> 4, hh = bh & 15;
#pragma unroll
    for (int df = 0; df < 4; ++df)
#pragma unroll
    for (int j = 0; j < 4; ++j) {
        float v = (o0[df][j] + o1[df][j] * (1.0f / 2048.0f)) * invl[j];
        long orow = (long)b * 1024 + q0 + w * 16 + g * 4 + j;
        int col = hh * 64 + df * 16 + l15;
        __half hi_, lo_; split2(v, hi_, lo_);
        oh_g[orow * 1024 + col] = hi_;
        ol_g[orow * 1024 + col] = lo_;
    }
}

// ---------- one-time weight convert: fp32 [R][C] -> fp16 [C][R] ----------
__global__ __launch_bounds__(256) void k_wconv(const float* __restrict__ src,
                                               __half* __restrict__ dst, int R, int C)
{
    src += (long)blockIdx.z * R * C;
    dst += (long)blockIdx.z * R * C;
    __shared__ float t[64][65];
    const int tid = threadIdx.x;
    const int c0 = blockIdx.x * 64, r0 = blockIdx.y * 64;
#pragma unroll
    for (int it = 0; it < 4; ++it) {
        int idx = it * 256 + tid;
        int r = idx >> 4, c4 = (idx & 15) * 4;
        float4 v = *(const float4*)(src + (long)(r0 + r) * C + c0 + c4);
        t[r][c4] = v.x; t[r][c4 + 1] = v.y; t[r][c4 + 2] = v.z; t[r][c4 + 3] = v.w;
    }
    __syncthreads();
#pragma unroll
    for (int it = 0; it < 2; ++it) {
        int idx = it * 256 + tid;
        int orow = idx >> 3, oc = (idx & 7) * 8;
        __half v[8];
#pragma unroll
        for (int j = 0; j < 8; ++j) v[j] = __float2half(t[oc + j][orow]);
        *(uint4*)(dst + (long)(c0 + orow) * R + r0 + oc) = *(uint4*)v;
    }
}

// ---------- MoE grouped GEMM, B = fp16 transposed weights [n][k] ----------
// MODE 0: GEMM1 — B rows remapped (h1/h2 16-col pairing), SiLU fused, fp16 out.
// MODE 1: GEMM2 — straight rows, f32 out.
template<bool GATHER, int MODE>
__global__ __launch_bounds__(256, 2)
void k_gemm_moe(const __half* __restrict__ A, int lda, const int* __restrict__ rowidx,
                const Desc* __restrict__ desc, const int* __restrict__ ntiles,
                const __half* __restrict__ Bbase, long sB, int ldb,
                void* __restrict__ Cv, int K)
{
    if ((int)blockIdx.x >= *ntiles) return;
    Desc d = desc[blockIdx.x];
    const __half* Bp = Bbase + (long)d.e * sB;
    constexpr int PITCH = 40;
    __shared__ __half As[128 * PITCH];
    __shared__ __half Bs[128 * PITCH];
    const int tid = threadIdx.x, lane = tid & 63, w = tid >> 6;
    const int l15 = lane & 15, g = lane >> 4;
    const int wm = w >> 1, wn = w & 1;
    const int n0 = blockIdx.y * (MODE == 0 ? 64 : 128);   // logical j0 / col0

    f32x4 acc[4][4] = {};
    for (int k0 = 0; k0 < K; k0 += 32) {
        __syncthreads();
#pragma unroll
        for (int it = 0; it < 2; ++it) {
            int c = it * 256 + tid, row = c >> 2, kg = c & 3;
            uint4 v = make_uint4(0, 0, 0, 0);
            if constexpr (GATHER) {
                if (row < d.rows) {
                    int ar = rowidx[d.base + row];
                    v = *(const uint4*)(A + (long)ar * lda + k0 + kg * 8);
                }
            } else {
                v = *(const uint4*)(A + (long)(d.base + row) * lda + k0 + kg * 8);
            }
            *(uint4*)&As[row * PITCH + kg * 8] = v;
        }
#pragma unroll
        for (int it = 0; it < 2; ++it) {
            int c = it * 256 + tid, row = c >> 2, kg = c & 3;
            int srcrow;
            if constexpr (MODE == 0) {
                int pb = row >> 4, w4 = row & 15;
                srcrow = ((pb & 1) ? 2048 : 0) + n0 + (pb >> 1) * 16 + w4;
            } else {
                srcrow = n0 + row;
            }
            *(uint4*)&Bs[row * PITCH + kg * 8] =
                *(const uint4*)(Bp + (long)srcrow * ldb + k0 + kg * 8);
        }
        __syncthreads();
        half8 a[4];
#pragma unroll
        for (int i = 0; i < 4; ++i)
            a[i] = *(const half8*)&As[(wm * 64 + i * 16 + l15) * PITCH + g * 8];
#pragma unroll
        for (int n = 0; n < 4; ++n) {
            half8 b = *(const half8*)&Bs[(wn * 64 + n * 16 + l15) * PITCH + g * 8];
#pragma unroll
            for (int i = 0; i < 4; ++i)
                acc[i][n] = __builtin_amdgcn_mfma_f32_16x16x32_f16(a[i], b, acc[i][n], 0, 0, 0);
        }
    }

    if constexpr (MODE == 0) {
#pragma unroll
        for (int i = 0; i < 4; ++i)
#pragma unroll
        for (int p = 0; p < 2; ++p)
#pragma unroll
        for (int j = 0; j < 4; ++j) {
            int rl = wm * 64 + i * 16 + g * 4 + j;
            float h1 = acc[i][2 * p][j], h2 = acc[i][2 * p + 1][j];
            float a = h1 / (1.0f + expf(-h1)) * h2;
            if (rl >= d.rows) a = 0.0f;
            int jc = n0 + wn * 32 + p * 16 + l15;
            ((__half*)Cv)[(long)(d.base + rl) * 2048 + jc] = __float2half(a);
        }
    } else {
#pragma unroll
        for (int i = 0; i < 4; ++i)
#pragma unroll
        for (int n = 0; n < 4; ++n)
#pragma unroll
        for (int j = 0; j < 4; ++j) {
            int rl = wm * 64 + i * 16 + g * 4 + j;
            int gn = n0 + wn * 64 + n * 16 + l15;
            ((float*)Cv)[(long)(d.base + rl) * 1024 + gn] = acc[i][n][j];
        }
    }
}

// ---------- transpose fp32 [R][C] -> [C][R], split-fp16 planes out ----------
__global__ __launch_bounds__(256) void k_transpose_pk(const float* __restrict__ src,
    __half* __restrict__ dsth, __half* __restrict__ dstl, int R, int C)
{
    __shared__ float t[64][65];
    const int tid = threadIdx.x;
    const int c0 = blockIdx.x * 64, r0 = blockIdx.y * 64;
#pragma unroll
    for (int it = 0; it < 4; ++it) {
        int idx = it * 256 + tid;
        int r = idx >> 4, c4 = (idx & 15) * 4;
        float4 v = *(const float4*)(src + (long)(r0 + r) * C + c0 + c4);
        t[r][c4] = v.x; t[r][c4 + 1] = v.y; t[r][c4 + 2] = v.z; t[r][c4 + 3] = v.w;
    }
    __syncthreads();
#pragma unroll
    for (int it = 0; it < 4; ++it) {
        int idx = it * 256 + tid;
        int orow = idx >> 4, oc = (idx & 15) * 4;
        __half hs[4], ls[4];
#pragma unroll
        for (int m = 0; m < 4; ++m) split2(t[oc + m][orow], hs[m], ls[m]);
        long o = (long)(c0 + orow) * R + r0 + oc;
        *(uint2*)&dsth[o] = *(uint2*)hs;
        *(uint2*)&dstl[o] = *(uint2*)ls;
    }
}

// ---------- LayerNorm (D=1024, one block per row) ----------
template<int MODE> // 0: hi/lo plane out; 1: f32 + plain fp16 out
__global__ __launch_bounds__(256) void k_ln(const float* __restrict__ X,
    const float* __restrict__ g, const float* __restrict__ bta,
    void* __restrict__ o1, void* __restrict__ o2)
{
    __shared__ float red[4];
    const long row = blockIdx.x;
    const float* xr = X + row * 1024;
    const int c = threadIdx.x * 4;
    float4 v = *(const float4*)(xr + c);
    float mu = blockReduceSum(v.x + v.y + v.z + v.w, red) * (1.0f / 1024.0f);
    float d0 = v.x - mu, d1 = v.y - mu, d2 = v.z - mu, d3 = v.w - mu;
    float var = blockReduceSum(d0 * d0 + d1 * d1 + d2 * d2 + d3 * d3, red) * (1.0f / 1024.0f);
    float rs = 1.0f / sqrtf(var + 1e-5f);
    float4 gv = *(const float4*)(g + c);
    float4 bv = *(const float4*)(bta + c);
    float y[4] = {d0 * rs * gv.x + bv.x, d1 * rs * gv.y + bv.y,
                  d2 * rs * gv.z + bv.z, d3 * rs * gv.w + bv.w};
    if constexpr (MODE == 0) {
        __half hs[4], ls[4];
#pragma unroll
        for (int m = 0; m < 4; ++m) split2(y[m], hs[m], ls[m]);
        *(uint2*)((__half*)o1 + row * 1024 + c) = *(uint2*)hs;
        *(uint2*)((__half*)o2 + row * 1024 + c) = *(uint2*)ls;
    } else {
        *(float4*)((float*)o1 + row * 1024 + c) = make_float4(y[0], y[1], y[2], y[3]);
        __half hs[4];
#pragma unroll
        for (int m = 0; m < 4; ++m) hs[m] = __float2half(y[m]);
        *(uint2*)((__half*)o2 + row * 1024 + c) = *(uint2*)hs;
    }
}

// ---------- RoPE cos/sin table ----------
__global__ __launch_bounds__(256) void k_rope_table(float* __restrict__ ct, float* __restrict__ st)
{
    int idx = blockIdx.x * 256 + threadIdx.x; // 32768 = 1024 t x 32 i
    int t = idx >> 5, i = idx & 31;
    float inv = 1.0f / (float)pow(10000.0, (double)i / 32.0);
    float ang = (float)t * inv;
    ct[idx] = cosf(ang);
    st[idx] = sinf(ang);
}

// ---------- gating: fp32 scores, top-2, no global atomics ----------
__global__ __launch_bounds__(256) void k_gate(const float* __restrict__ xn2,
    const float* __restrict__ gw, const float* __restrict__ eb,
    int* __restrict__ topidx, float* __restrict__ gates,
    float* __restrict__ pprob)
{
    __shared__ float pp[4][8];
    const int lane = threadIdx.x & 63, w = threadIdx.x >> 6;
    const int t = blockIdx.x * 4 + w;
    const float* xr = xn2 + (long)t * 1024;
    float sc[8] = {0, 0, 0, 0, 0, 0, 0, 0};
#pragma unroll
    for (int i = 0; i < 4; ++i) {
        int d = i * 256 + lane * 4;
        float4 xv = *(const float4*)(xr + d);
        float xa[4] = {xv.x, xv.y, xv.z, xv.w};
#pragma unroll
        for (int j = 0; j < 4; ++j) {
            float xx = xa[j];
            const float4* gp = (const float4*)(gw + (long)(d + j) * 8);
            float4 g0 = gp[0], g1 = gp[1];
            sc[0] += xx * g0.x; sc[1] += xx * g0.y; sc[2] += xx * g0.z; sc[3] += xx * g0.w;
            sc[4] += xx * g1.x; sc[5] += xx * g1.y; sc[6] += xx * g1.z; sc[7] += xx * g1.w;
        }
    }
#pragma unroll
    for (int e = 0; e < 8; ++e) {
#pragma unroll
        for (int m = 32; m; m >>= 1) sc[e] += __shfl_xor(sc[e], m);
        sc[e] += eb[e];
    }
    if (lane == 0) {
        int i1 = 0; float v1 = sc[0];
        for (int e = 1; e < 8; ++e) if (sc[e] > v1) { v1 = sc[e]; i1 = e; }
        int i2 = (i1 == 0) ? 1 : 0; float v2 = sc[i2];
        for (int e = 0; e < 8; ++e) if (e != i1 && sc[e] > v2) { v2 = sc[e]; i2 = e; }
        float e2 = expf(v2 - v1);
        gates[t * 2] = 1.0f / (1.0f + e2);
        gates[t * 2 + 1] = e2 / (1.0f + e2);
        topidx[t * 2] = i1; topidx[t * 2 + 1] = i2;
        float mxx = sc[0];
        for (int e = 1; e < 8; ++e) mxx = fmaxf(mxx, sc[e]);
        float se = 0.0f, pe[8];
        for (int e = 0; e < 8; ++e) { pe[e] = expf(sc[e] - mxx); se += pe[e]; }
        float inv = 1.0f / se;
        for (int e = 0; e < 8; ++e) pp[w][e] = pe[e] * inv;
    }
    __syncthreads();
    if (threadIdx.x < 8)
        pprob[(long)blockIdx.x * 8 + threadIdx.x] =
            pp[0][threadIdx.x] + pp[1][threadIdx.x] + pp[2][threadIdx.x] + pp[3][threadIdx.x];
}

// ---------- routing ----------
__global__ __launch_bounds__(256) void k_route(const int* __restrict__ topidx,
    int* __restrict__ rowidx, int* __restrict__ invpos,
    int* __restrict__ ntiles, Desc* __restrict__ desc, int* __restrict__ cnt)
{
    __shared__ int cnt_s[8], base_s[8], fill[8];
    const int tid = threadIdx.x;
    if (tid < 8) { cnt_s[tid] = 0; fill[tid] = 0; }
    __syncthreads();
    for (int i = tid; i < 4096; i += 256)
        atomicAdd(&cnt_s[topidx[i]], 1);
    __syncthreads();
    if (tid == 0) {
        int nt = 0, running = 0;
        for (int e = 0; e < 8; ++e) {
            int ce = cnt_s[e];
            cnt[e] = ce;
            base_s[e] = running;
            int tl = (ce + 127) >> 7;
            for (int j = 0; j < tl; ++j) {
                desc[nt].e = e; desc[nt].base = running + j * 128;
                desc[nt].rows = min(128, ce - j * 128);
                ++nt;
            }
            running += tl * 128;
        }
        *ntiles = nt;
    }
    __syncthreads();
    for (int t = tid; t < 2048; t += 256) {
#pragma unroll
        for (int s = 0; s < 2; ++s) {
            int e = topidx[t * 2 + s];
            int p = base_s[e] + atomicAdd(&fill[e], 1);
            rowidx[p] = t;
            invpos[t * 2 + s] = p;
        }
    }
}

// ---------- combine ----------
__global__ __launch_bounds__(256) void k_combine(const float* __restrict__ x1,
    const float* __restrict__ eo, const int* __restrict__ invpos,
    const float* __restrict__ gates, float* __restrict__ out)
{
    const int t = blockIdx.x, c = threadIdx.x * 4;
    float g0 = gates[t * 2], g1 = gates[t * 2 + 1];
    int p0 = invpos[t * 2], p1 = invpos[t * 2 + 1];
    float4 xv = *(const float4*)(x1 + (long)t * 1024 + c);
    float4 e0 = *(const float4*)(eo + (long)p0 * 1024 + c);
    float4 e1 = *(const float4*)(eo + (long)p1 * 1024 + c);
    float4 o;
    o.x = xv.x + g0 * e0.x + g1 * e1.x;
    o.y = xv.y + g0 * e0.y + g1 * e1.y;
    o.z = xv.z + g0 * e0.z + g1 * e1.z;
    o.w = xv.w + g0 * e0.w + g1 * e1.w;
    *(float4*)(out + (long)t * 1024 + c) = o;
}

// ---------- loss ----------
__global__ __launch_bounds__(256) void k_loss(const int* __restrict__ cnt,
    const float* __restrict__ pprob, float* __restrict__ out)
{
    __shared__ float m[32][8];
    const int tid = threadIdx.x;
    const int e = tid & 7, g = tid >> 3;
    float local = 0.0f;
    for (int b = g; b < 512; b += 32) local += pprob[b * 8 + e];
    m[g][e] = local;
    __syncthreads();
    if (tid == 0) {
        float us = 0, ps = 0, pe[8], ue[8];
        for (int ee = 0; ee < 8; ++ee) {
            float s = 0;
            for (int gg = 0; gg < 32; ++gg) s += m[gg][ee];
            pe[ee] = s; ps += s;
            ue[ee] = (float)cnt[ee]; us += ue[ee];
        }
        float lb = 0;
        for (int ee = 0; ee < 8; ++ee) lb += (ue[ee] / us) * (pe[ee] / ps);
        out[2097152] = lb * 8.0f;
    }
}

// =====================  launch  =====================
extern "C" void kernel_launch(void* const* d_in, const int* in_sizes, int n_in,
                              void* d_out, int out_size, void* d_ws, size_t ws_size,
                              hipStream_t stream)
{
    const float* x    = (const float*)d_in[0];
    const float* ln1g = (const float*)d_in[1];
    const float* ln1b = (const float*)d_in[2];
    const float* qkvw = (const float*)d_in[3];
    const float* outw = (const float*)d_in[4];
    const float* ln2g = (const float*)d_in[5];
    const float* ln2b = (const float*)d_in[6];
    const float* gw   = (const float*)d_in[7];
    const float* eb   = (const float*)d_in[8];
    const float* w1   = (const float*)d_in[9];
    const float* w2   = (const float*)d_in[10];
    float* out = (float*)d_out;
    char* ws = (char*)d_ws;

    // workspace map (bytes), total ~222 MB
    constexpr size_t OFF_QWTH = 0;          // half [3072][1024]
    constexpr size_t OFF_QWTL = 6291456;
    constexpr size_t OFF_OWTH = 12582912;   // half [1024][1024]
    constexpr size_t OFF_OWTL = 14680064;
    constexpr size_t OFF_XN1H = 16777216;   // half [2048][1024]
    constexpr size_t OFF_XN1L = 20971520;
    constexpr size_t OFF_QH   = 25165824;   // half [32][1024][64]
    constexpr size_t OFF_QL   = 29360128;
    constexpr size_t OFF_KH   = 33554432;
    constexpr size_t OFF_KL   = 37748736;
    constexpr size_t OFF_VTH  = 41943040;   // half [32][64][1024]
    constexpr size_t OFF_VTL  = 46137344;
    constexpr size_t OFF_OH   = 50331648;   // half [2048][1024]
    constexpr size_t OFF_OL   = 54525952;
    constexpr size_t OFF_X1   = 58720256;   // f32 [2048][1024]
    constexpr size_t OFF_XN2F = 67108864;   // f32
    constexpr size_t OFF_XN2H = 75497472;   // half
    constexpr size_t OFF_RC   = 79691776;   // f32 [1024][32]
    constexpr size_t OFF_RS   = 79822848;
    constexpr size_t OFF_IDX  = 79953920;   // int [2048][2]
    constexpr size_t OFF_GATES= 79970304;   // f32 [2048][2]
    constexpr size_t OFF_INVP = 79986688;   // int [2048][2]
    constexpr size_t OFF_ROWI = 80003072;   // int [5120]
    constexpr size_t OFF_CNT  = 80023552;   // int [8]
    constexpr size_t OFF_NT   = 80023616;   // int
    constexpr size_t OFF_DESC = 80023680;   // Desc [40]
    constexpr size_t OFF_PPROB= 80024704;   // f32 [512][8]
    constexpr size_t OFF_ACT  = 80041984;   // half [5120][2048]
    constexpr size_t OFF_EO   = 101013504;  // f32 [5120][1024]
    constexpr size_t OFF_W1T  = 121985024;  // half [8][4096][1024]
    constexpr size_t OFF_W2T  = 189093888;  // half [8][1024][2048]

    __half* qwth = (__half*)(ws + OFF_QWTH);
    __half* qwtl = (__half*)(ws + OFF_QWTL);
    __half* owth = (__half*)(ws + OFF_OWTH);
    __half* owtl = (__half*)(ws + OFF_OWTL);
    __half* xn1h = (__half*)(ws + OFF_XN1H);
    __half* xn1l = (__half*)(ws + OFF_XN1L);
    __half* qh   = (__half*)(ws + OFF_QH);
    __half* ql   = (__half*)(ws + OFF_QL);
    __half* kh   = (__half*)(ws + OFF_KH);
    __half* kl   = (__half*)(ws + OFF_KL);
    __half* vth  = (__half*)(ws + OFF_VTH);
    __half* vtl  = (__half*)(ws + OFF_VTL);
    __half* oh   = (__half*)(ws + OFF_OH);
    __half* ol   = (__half*)(ws + OFF_OL);
    float* x1    = (float*)(ws + OFF_X1);
    float* xn2f  = (float*)(ws + OFF_XN2F);
    __half* xn2h = (__half*)(ws + OFF_XN2H);
    float* rc    = (float*)(ws + OFF_RC);
    float* rs    = (float*)(ws + OFF_RS);
    int*   idx   = (int*)(ws + OFF_IDX);
    float* gates = (float*)(ws + OFF_GATES);
    int*   invp  = (int*)(ws + OFF_INVP);
    int*   rowi  = (int*)(ws + OFF_ROWI);
    int*   cnt   = (int*)(ws + OFF_CNT);
    int*   nt    = (int*)(ws + OFF_NT);
    Desc*  desc  = (Desc*)(ws + OFF_DESC);
    float* pprob = (float*)(ws + OFF_PPROB);
    __half* act  = (__half*)(ws + OFF_ACT);
    float* eo    = (float*)(ws + OFF_EO);
    __half* w1t  = (__half*)(ws + OFF_W1T);
    __half* w2t  = (__half*)(ws + OFF_W2T);

    // weight transposes -> split planes (attention) / plain fp16 (MoE)
    k_transpose_pk<<<dim3(48, 16, 1), 256, 0, stream>>>(qkvw, qwth, qwtl, 1024, 3072);
    k_transpose_pk<<<dim3(16, 16, 1), 256, 0, stream>>>(outw, owth, owtl, 1024, 1024);
    k_wconv<<<dim3(64, 16, 8), 256, 0, stream>>>(w1, w1t, 1024, 4096);
    k_wconv<<<dim3(16, 32, 8), 256, 0, stream>>>(w2, w2t, 2048, 1024);
    k_rope_table<<<dim3(128), 256, 0, stream>>>(rc, rs);

    // LN1 -> xn1 planes
    k_ln<0><<<dim3(2048), 256, 0, stream>>>(x, ln1g, ln1b, xn1h, xn1l);

    // QKV GEMM with fused RoPE + q/k/v scatter (64x128 tiles, 768 blocks)
    k_gemm_pk<2, 2, 2, 4, EPI_QKV><<<dim3(32, 24, 1), 256, 0, stream>>>(
        xn1h, xn1l, 1024, qwth, qwtl, 1024, nullptr, 0, 2048, 3072, 1024,
        nullptr, qh, ql, kh, kl, vth, vtl, rc, rs);

    // flash attention -> o planes
    k_flash<<<dim3(16, 32, 1), 256, 0, stream>>>(qh, ql, kh, kl, vth, vtl, oh, ol);

    // x1 = x + o @ out_w
    k_gemm_pk<2, 2, 2, 2, EPI_RESID><<<dim3(32, 16, 1), 256, 0, stream>>>(
        oh, ol, 1024, owth, owtl, 1024, x1, 1024, 2048, 1024, 1024,
        x, nullptr, nullptr, nullptr, nullptr, nullptr, nullptr, nullptr, nullptr);

    // LN2 -> xn2 (f32 for gating, fp16 for MoE)
    k_ln<1><<<dim3(2048), 256, 0, stream>>>(x1, ln2g, ln2b, xn2f, xn2h);

    // gating + routing
    k_gate<<<dim3(512), 256, 0, stream>>>(xn2f, gw, eb, idx, gates, pprob);
    k_route<<<dim3(1), 256, 0, stream>>>(idx, rowi, invp, nt, desc, cnt);

    // MoE GEMM1: act = silu(h1)*h2, B = w1t fp16 (paired-row addressing)
    k_gemm_moe<true, 0><<<dim3(40, 32, 1), 256, 0, stream>>>(
        xn2h, 1024, rowi, desc, nt, w1t, 4194304, 1024, act, 1024);

    // MoE GEMM2: eo = act @ w2[e], B = w2t fp16
    k_gemm_moe<false, 1><<<dim3(40, 8, 1), 256, 0, stream>>>(
        act, 2048, nullptr, desc, nt, w2t, 2097152, 2048, eo, 2048);

    // combine + loss
    k_combine<<<dim3(2048), 256, 0, stream>>>(x1, eo, invp, gates, out);
    k_loss<<<dim3(1), 256, 0, stream>>>(cnt, pprob, out);
}

// Round 6
// 411.155 us; speedup vs baseline: 2.2370x; 1.0286x over previous
//
#include <hip/hip_runtime.h>
#include <hip/hip_fp16.h>

// UnifiedTransformerBlock on MI355X.
// R6: MoE desc[] reordered round-robin by expert so tile x -> XCD x%8
// (gridX=40 = 0 mod 8): expert-k's weight panel + token rows stay hot in
// XCD k's private L2 across all N-chunks (R5 counters showed 2x B/A
// re-fetch: 155MB vs ~75MB ideal).  MoE GEMM2 retiled 128x64 -> 640 blocks
// (was 320 = 1.25/CU, grid-starved at same cost as GEMM1 w/ half FLOPs).

typedef _Float16 half8 __attribute__((ext_vector_type(8)));
typedef float f32x4 __attribute__((ext_vector_type(4)));

#define DI __device__ __forceinline__

struct Desc { int e, base, rows; };

DI float blockReduceSum(float v, float* red) {
#pragma unroll
    for (int m = 32; m; m >>= 1) v += __shfl_xor(v, m);
    int w = threadIdx.x >> 6;
    if ((threadIdx.x & 63) == 0) red[w] = v;
    __syncthreads();
    v = red[0] + red[1] + red[2] + red[3];
    __syncthreads();
    return v;
}

DI void split2(float v, __half& hi, __half& lo) {
    hi = __float2half(v);
    lo = __float2half((v - __half2float(hi)) * 2048.0f);
}

// ---------- split-fp16 plane GEMM: C = A(MxK) * B^T(NxK) ----------
enum { EPI_RESID = 0, EPI_QKV = 1 };

template<int WM, int WN, int FM, int FN, int EPI>
__global__ __launch_bounds__(256, 2)
void k_gemm_pk(const __half* __restrict__ Ah, const __half* __restrict__ Al, int lda,
               const __half* __restrict__ Bh, const __half* __restrict__ Bl, int ldb,
               float* __restrict__ Cf, int ldc, int M, int N, int K,
               const float* __restrict__ resid,
               __half* __restrict__ qh_p, __half* __restrict__ ql_p,
               __half* __restrict__ kh_p, __half* __restrict__ kl_p,
               __half* __restrict__ vth_p, __half* __restrict__ vtl_p,
               const float* __restrict__ rc, const float* __restrict__ rs)
{
    constexpr int BM = WM * FM * 16, BN = WN * FN * 16;
    constexpr int PITCH = 40;                  // halves: 32 + 8 pad
    __shared__ __half AsH[BM * PITCH], AsL[BM * PITCH];
    __shared__ __half BsH[BN * PITCH], BsL[BN * PITCH];
    const int tid = threadIdx.x;
    const int lane = tid & 63, w = tid >> 6;
    const int l15 = lane & 15, g = lane >> 4;
    const int wm = w / WN, wn = w % WN;
    const int m0 = blockIdx.x * BM, n0 = blockIdx.y * BN;

    f32x4 acc0[FM][FN] = {}; f32x4 acc1[FM][FN] = {};

    for (int k0 = 0; k0 < K; k0 += 32) {
        __syncthreads();
#pragma unroll
        for (int it = 0; it < BM / 64; ++it) {
            int c = it * 256 + tid, row = c >> 2, kg = c & 3;
            long src = (long)(m0 + row) * lda + k0 + kg * 8;
            *(uint4*)&AsH[row * PITCH + kg * 8] = *(const uint4*)(Ah + src);
            *(uint4*)&AsL[row * PITCH + kg * 8] = *(const uint4*)(Al + src);
        }
#pragma unroll
        for (int it = 0; it < BN / 64; ++it) {
            int c = it * 256 + tid, row = c >> 2, kg = c & 3;
            long src = (long)(n0 + row) * ldb + k0 + kg * 8;
            *(uint4*)&BsH[row * PITCH + kg * 8] = *(const uint4*)(Bh + src);
            *(uint4*)&BsL[row * PITCH + kg * 8] = *(const uint4*)(Bl + src);
        }
        __syncthreads();
        half8 ah[FM], al[FM];
#pragma unroll
        for (int i = 0; i < FM; ++i) {
            int ar = (wm * FM * 16 + i * 16 + l15) * PITCH + g * 8;
            ah[i] = *(const half8*)&AsH[ar];
            al[i] = *(const half8*)&AsL[ar];
        }
#pragma unroll
        for (int n = 0; n < FN; ++n) {
            int br = (wn * FN * 16 + n * 16 + l15) * PITCH + g * 8;
            half8 bh = *(const half8*)&BsH[br];
            half8 bl = *(const half8*)&BsL[br];
#pragma unroll
            for (int i = 0; i < FM; ++i) {
                acc0[i][n] = __builtin_amdgcn_mfma_f32_16x16x32_f16(ah[i], bh, acc0[i][n], 0, 0, 0);
                acc1[i][n] = __builtin_amdgcn_mfma_f32_16x16x32_f16(ah[i], bl, acc1[i][n], 0, 0, 0);
                acc1[i][n] = __builtin_amdgcn_mfma_f32_16x16x32_f16(al[i], bh, acc1[i][n], 0, 0, 0);
            }
        }
    }

#pragma unroll
    for (int i = 0; i < FM; ++i)
#pragma unroll
    for (int n = 0; n < FN; ++n)
#pragma unroll
    for (int j = 0; j < 4; ++j) {
        float v = acc0[i][n][j] + acc1[i][n][j] * (1.0f / 2048.0f);
        int gm = m0 + wm * FM * 16 + i * 16 + g * 4 + j;
        int gn = n0 + wn * FN * 16 + n * 16 + l15;
        if constexpr (EPI == EPI_RESID) {
            Cf[(long)gm * ldc + gn] = v + resid[(long)gm * ldc + gn];
        } else {
            // QKV epilogue: RoPE for q/k, transpose-scatter for v, split planes.
            int t = gm & 1023, b = gm >> 10;
            float vp = __shfl_xor(v, 1);       // pair column (uniform control flow)
            if (gn < 2048) {
                int col = gn & 1023;
                int i2 = (col & 63) >> 1;
                float cv = rc[t * 32 + i2], sv = rs[t * 32 + i2];
                float rot = cv * v + sv * ((lane & 1) ? vp : -vp);
                __half hi_, lo_; split2(rot, hi_, lo_);
                long o = ((long)(b * 16 + (col >> 6)) * 1024 + t) * 64 + (col & 63);
                if (gn < 1024) { qh_p[o] = hi_; ql_p[o] = lo_; }
                else           { kh_p[o] = hi_; kl_p[o] = lo_; }
            } else {
                int col = gn - 2048;
                __half hi_, lo_; split2(v, hi_, lo_);
                long o = ((long)(b * 16 + (col >> 6)) * 64 + (col & 63)) * 1024 + t;
                vth_p[o] = hi_; vtl_p[o] = lo_;
            }
        }
    }
}

// ---------- flash attention, split-fp16 planes ----------
__global__ __launch_bounds__(256, 2)
void k_flash(const __half* __restrict__ qh_g, const __half* __restrict__ ql_g,
             const __half* __restrict__ kh_g, const __half* __restrict__ kl_g,
             const __half* __restrict__ vth_g, const __half* __restrict__ vtl_g,
             __half* __restrict__ oh_g, __half* __restrict__ ol_g)
{
    constexpr int P = 72;
    __shared__ __half KsH[64 * P], KsL[64 * P], VsH[64 * P], VsL[64 * P], PsH[64 * P], PsL[64 * P];
    const int tid = threadIdx.x, lane = tid & 63, w = tid >> 6;
    const int l15 = lane & 15, g = lane >> 4;
    const int q0 = blockIdx.x * 64;
    const int bh = blockIdx.y;
    const long base = (long)bh * 65536;

    half8 qhi[2], qlo[2];
    {
        long qoff = base + (long)(q0 + w * 16 + l15) * 64 + g * 8;
        qhi[0] = *(const half8*)(qh_g + qoff); qhi[1] = *(const half8*)(qh_g + qoff + 32);
        qlo[0] = *(const half8*)(ql_g + qoff); qlo[1] = *(const half8*)(ql_g + qoff + 32);
    }

    float m_[4] = {-1e30f, -1e30f, -1e30f, -1e30f};
    float l_[4] = {0.f, 0.f, 0.f, 0.f};
    f32x4 o0[4] = {}, o1[4] = {};

    for (int kt = 0; kt < 16; ++kt) {
        __syncthreads();
#pragma unroll
        for (int it = 0; it < 2; ++it) {
            int c = it * 256 + tid, row = c >> 3, kg = c & 7;
            long src = base + (long)(kt * 64 + row) * 64 + kg * 8;
            *(uint4*)&KsH[row * P + kg * 8] = *(const uint4*)(kh_g + src);
            *(uint4*)&KsL[row * P + kg * 8] = *(const uint4*)(kl_g + src);
            long vs = base + (long)row * 1024 + kt * 64 + kg * 8;
            *(uint4*)&VsH[row * P + kg * 8] = *(const uint4*)(vth_g + vs);
            *(uint4*)&VsL[row * P + kg * 8] = *(const uint4*)(vtl_g + vs);
        }
        __syncthreads();

        f32x4 s0[4] = {}, s1[4] = {};
#pragma unroll
        for (int cf = 0; cf < 4; ++cf) {
            int kr = (cf * 16 + l15) * P + g * 8;
            half8 kh0 = *(const half8*)&KsH[kr], kh1 = *(const half8*)&KsH[kr + 32];
            half8 kl0 = *(const half8*)&KsL[kr], kl1 = *(const half8*)&KsL[kr + 32];
            s0[cf] = __builtin_amdgcn_mfma_f32_16x16x32_f16(qhi[0], kh0, s0[cf], 0, 0, 0);
            s1[cf] = __builtin_amdgcn_mfma_f32_16x16x32_f16(qhi[0], kl0, s1[cf], 0, 0, 0);
            s1[cf] = __builtin_amdgcn_mfma_f32_16x16x32_f16(qlo[0], kh0, s1[cf], 0, 0, 0);
            s0[cf] = __builtin_amdgcn_mfma_f32_16x16x32_f16(qhi[1], kh1, s0[cf], 0, 0, 0);
            s1[cf] = __builtin_amdgcn_mfma_f32_16x16x32_f16(qhi[1], kl1, s1[cf], 0, 0, 0);
            s1[cf] = __builtin_amdgcn_mfma_f32_16x16x32_f16(qlo[1], kh1, s1[cf], 0, 0, 0);
        }

#pragma unroll
        for (int j = 0; j < 4; ++j) {
            float sv[4];
#pragma unroll
            for (int cf = 0; cf < 4; ++cf)
                sv[cf] = (s0[cf][j] + s1[cf][j] * (1.0f / 2048.0f)) * 0.125f;
            float mx = fmaxf(fmaxf(sv[0], sv[1]), fmaxf(sv[2], sv[3]));
#pragma unroll
            for (int msk = 8; msk; msk >>= 1) mx = fmaxf(mx, __shfl_xor(mx, msk));
            float mn = fmaxf(m_[j], mx);
            float r = expf(m_[j] - mn);
            m_[j] = mn;
            float rs = 0.f;
#pragma unroll
            for (int cf = 0; cf < 4; ++cf) {
                float p = expf(sv[cf] - mn);
                rs += p;
                __half hi_, lo_; split2(p, hi_, lo_);
                PsH[(w * 16 + g * 4 + j) * P + cf * 16 + l15] = hi_;
                PsL[(w * 16 + g * 4 + j) * P + cf * 16 + l15] = lo_;
            }
#pragma unroll
            for (int msk = 8; msk; msk >>= 1) rs += __shfl_xor(rs, msk);
            l_[j] = l_[j] * r + rs;
#pragma unroll
            for (int df = 0; df < 4; ++df) { o0[df][j] *= r; o1[df][j] *= r; }
        }
        __syncthreads();

        int pr = (w * 16 + l15) * P + g * 8;
        half8 ph0 = *(const half8*)&PsH[pr], ph1 = *(const half8*)&PsH[pr + 32];
        half8 pl0 = *(const half8*)&PsL[pr], pl1 = *(const half8*)&PsL[pr + 32];
#pragma unroll
        for (int df = 0; df < 4; ++df) {
            int vr = (df * 16 + l15) * P + g * 8;
            half8 vh0 = *(const half8*)&VsH[vr], vh1 = *(const half8*)&VsH[vr + 32];
            half8 vl0 = *(const half8*)&VsL[vr], vl1 = *(const half8*)&VsL[vr + 32];
            o0[df] = __builtin_amdgcn_mfma_f32_16x16x32_f16(ph0, vh0, o0[df], 0, 0, 0);
            o1[df] = __builtin_amdgcn_mfma_f32_16x16x32_f16(ph0, vl0, o1[df], 0, 0, 0);
            o1[df] = __builtin_amdgcn_mfma_f32_16x16x32_f16(pl0, vh0, o1[df], 0, 0, 0);
            o0[df] = __builtin_amdgcn_mfma_f32_16x16x32_f16(ph1, vh1, o0[df], 0, 0, 0);
            o1[df] = __builtin_amdgcn_mfma_f32_16x16x32_f16(ph1, vl1, o1[df], 0, 0, 0);
            o1[df] = __builtin_amdgcn_mfma_f32_16x16x32_f16(pl1, vh1, o1[df], 0, 0, 0);
        }
    }

    float invl[4];
#pragma unroll
    for (int j = 0; j < 4; ++j) invl[j] = 1.0f / l_[j];
    const int b = bh >> 4, hh = bh & 15;
#pragma unroll
    for (int df = 0; df < 4; ++df)
#pragma unroll
    for (int j = 0; j < 4; ++j) {
        float v = (o0[df][j] + o1[df][j] * (1.0f / 2048.0f)) * invl[j];
        long orow = (long)b * 1024 + q0 + w * 16 + g * 4 + j;
        int col = hh * 64 + df * 16 + l15;
        __half hi_, lo_; split2(v, hi_, lo_);
        oh_g[orow * 1024 + col] = hi_;
        ol_g[orow * 1024 + col] = lo_;
    }
}

// ---------- one-time weight convert: fp32 [R][C] -> fp16 [C][R] ----------
__global__ __launch_bounds__(256) void k_wconv(const float* __restrict__ src,
                                               __half* __restrict__ dst, int R, int C)
{
    src += (long)blockIdx.z * R * C;
    dst += (long)blockIdx.z * R * C;
    __shared__ float t[64][65];
    const int tid = threadIdx.x;
    const int c0 = blockIdx.x * 64, r0 = blockIdx.y * 64;
#pragma unroll
    for (int it = 0; it < 4; ++it) {
        int idx = it * 256 + tid;
        int r = idx >> 4, c4 = (idx & 15) * 4;
        float4 v = *(const float4*)(src + (long)(r0 + r) * C + c0 + c4);
        t[r][c4] = v.x; t[r][c4 + 1] = v.y; t[r][c4 + 2] = v.z; t[r][c4 + 3] = v.w;
    }
    __syncthreads();
#pragma unroll
    for (int it = 0; it < 2; ++it) {
        int idx = it * 256 + tid;
        int orow = idx >> 3, oc = (idx & 7) * 8;
        __half v[8];
#pragma unroll
        for (int j = 0; j < 8; ++j) v[j] = __float2half(t[oc + j][orow]);
        *(uint4*)(dst + (long)(c0 + orow) * R + r0 + oc) = *(uint4*)v;
    }
}

// ---------- MoE grouped GEMM, B = fp16 transposed weights [n][k] ----------
// MODE 0: GEMM1 — B rows remapped (h1/h2 16-col pairing), SiLU fused, fp16 out.
// MODE 1: GEMM2 — straight rows, f32 out.
// BM = (4/WN)*FM*16, BN = WN*FN*16.
template<bool GATHER, int MODE, int FM, int FN, int WN>
__global__ __launch_bounds__(256, 2)
void k_gemm_moe(const __half* __restrict__ A, int lda, const int* __restrict__ rowidx,
                const Desc* __restrict__ desc, const int* __restrict__ ntiles,
                const __half* __restrict__ Bbase, long sB, int ldb,
                void* __restrict__ Cv, int K)
{
    if ((int)blockIdx.x >= *ntiles) return;
    Desc d = desc[blockIdx.x];
    const __half* Bp = Bbase + (long)d.e * sB;
    constexpr int WM = 4 / WN;
    constexpr int BM = WM * FM * 16, BN = WN * FN * 16;
    constexpr int PITCH = 40;
    __shared__ __half As[BM * PITCH];
    __shared__ __half Bs[BN * PITCH];
    const int tid = threadIdx.x, lane = tid & 63, w = tid >> 6;
    const int l15 = lane & 15, g = lane >> 4;
    const int wm = w / WN, wn = w % WN;
    const int n0 = blockIdx.y * (MODE == 0 ? BN / 2 : BN);   // logical j0 / col0

    f32x4 acc[FM][FN] = {};
    for (int k0 = 0; k0 < K; k0 += 32) {
        __syncthreads();
#pragma unroll
        for (int it = 0; it < BM / 64; ++it) {
            int c = it * 256 + tid, row = c >> 2, kg = c & 3;
            uint4 v = make_uint4(0, 0, 0, 0);
            if constexpr (GATHER) {
                if (row < d.rows) {
                    int ar = rowidx[d.base + row];
                    v = *(const uint4*)(A + (long)ar * lda + k0 + kg * 8);
                }
            } else {
                v = *(const uint4*)(A + (long)(d.base + row) * lda + k0 + kg * 8);
            }
            *(uint4*)&As[row * PITCH + kg * 8] = v;
        }
#pragma unroll
        for (int it = 0; it < BN / 64; ++it) {
            int c = it * 256 + tid, row = c >> 2, kg = c & 3;
            int srcrow;
            if constexpr (MODE == 0) {
                int pb = row >> 4, w4 = row & 15;
                srcrow = ((pb & 1) ? 2048 : 0) + n0 + (pb >> 1) * 16 + w4;
            } else {
                srcrow = n0 + row;
            }
            *(uint4*)&Bs[row * PITCH + kg * 8] =
                *(const uint4*)(Bp + (long)srcrow * ldb + k0 + kg * 8);
        }
        __syncthreads();
        half8 a[FM];
#pragma unroll
        for (int i = 0; i < FM; ++i)
            a[i] = *(const half8*)&As[(wm * FM * 16 + i * 16 + l15) * PITCH + g * 8];
#pragma unroll
        for (int n = 0; n < FN; ++n) {
            half8 b = *(const half8*)&Bs[(wn * FN * 16 + n * 16 + l15) * PITCH + g * 8];
#pragma unroll
            for (int i = 0; i < FM; ++i)
                acc[i][n] = __builtin_amdgcn_mfma_f32_16x16x32_f16(a[i], b, acc[i][n], 0, 0, 0);
        }
    }

    if constexpr (MODE == 0) {
#pragma unroll
        for (int i = 0; i < FM; ++i)
#pragma unroll
        for (int p = 0; p < FN / 2; ++p)
#pragma unroll
        for (int j = 0; j < 4; ++j) {
            int rl = wm * FM * 16 + i * 16 + g * 4 + j;
            float h1 = acc[i][2 * p][j], h2 = acc[i][2 * p + 1][j];
            float a = h1 / (1.0f + expf(-h1)) * h2;
            if (rl >= d.rows) a = 0.0f;
            int jc = n0 + wn * (FN * 8) + p * 16 + l15;
            ((__half*)Cv)[(long)(d.base + rl) * 2048 + jc] = __float2half(a);
        }
    } else {
#pragma unroll
        for (int i = 0; i < FM; ++i)
#pragma unroll
        for (int n = 0; n < FN; ++n)
#pragma unroll
        for (int j = 0; j < 4; ++j) {
            int rl = wm * FM * 16 + i * 16 + g * 4 + j;
            int gn = n0 + wn * FN * 16 + n * 16 + l15;
            ((float*)Cv)[(long)(d.base + rl) * 1024 + gn] = acc[i][n][j];
        }
    }
}

// ---------- transpose fp32 [R][C] -> [C][R], split-fp16 planes out ----------
__global__ __launch_bounds__(256) void k_transpose_pk(const float* __restrict__ src,
    __half* __restrict__ dsth, __half* __restrict__ dstl, int R, int C)
{
    __shared__ float t[64][65];
    const int tid = threadIdx.x;
    const int c0 = blockIdx.x * 64, r0 = blockIdx.y * 64;
#pragma unroll
    for (int it = 0; it < 4; ++it) {
        int idx = it * 256 + tid;
        int r = idx >> 4, c4 = (idx & 15) * 4;
        float4 v = *(const float4*)(src + (long)(r0 + r) * C + c0 + c4);
        t[r][c4] = v.x; t[r][c4 + 1] = v.y; t[r][c4 + 2] = v.z; t[r][c4 + 3] = v.w;
    }
    __syncthreads();
#pragma unroll
    for (int it = 0; it < 4; ++it) {
        int idx = it * 256 + tid;
        int orow = idx >> 4, oc = (idx & 15) * 4;
        __half hs[4], ls[4];
#pragma unroll
        for (int m = 0; m < 4; ++m) split2(t[oc + m][orow], hs[m], ls[m]);
        long o = (long)(c0 + orow) * R + r0 + oc;
        *(uint2*)&dsth[o] = *(uint2*)hs;
        *(uint2*)&dstl[o] = *(uint2*)ls;
    }
}

// ---------- LayerNorm (D=1024, one block per row) ----------
template<int MODE> // 0: hi/lo plane out; 1: f32 + plain fp16 out
__global__ __launch_bounds__(256) void k_ln(const float* __restrict__ X,
    const float* __restrict__ g, const float* __restrict__ bta,
    void* __restrict__ o1, void* __restrict__ o2)
{
    __shared__ float red[4];
    const long row = blockIdx.x;
    const float* xr = X + row * 1024;
    const int c = threadIdx.x * 4;
    float4 v = *(const float4*)(xr + c);
    float mu = blockReduceSum(v.x + v.y + v.z + v.w, red) * (1.0f / 1024.0f);
    float d0 = v.x - mu, d1 = v.y - mu, d2 = v.z - mu, d3 = v.w - mu;
    float var = blockReduceSum(d0 * d0 + d1 * d1 + d2 * d2 + d3 * d3, red) * (1.0f / 1024.0f);
    float rs = 1.0f / sqrtf(var + 1e-5f);
    float4 gv = *(const float4*)(g + c);
    float4 bv = *(const float4*)(bta + c);
    float y[4] = {d0 * rs * gv.x + bv.x, d1 * rs * gv.y + bv.y,
                  d2 * rs * gv.z + bv.z, d3 * rs * gv.w + bv.w};
    if constexpr (MODE == 0) {
        __half hs[4], ls[4];
#pragma unroll
        for (int m = 0; m < 4; ++m) split2(y[m], hs[m], ls[m]);
        *(uint2*)((__half*)o1 + row * 1024 + c) = *(uint2*)hs;
        *(uint2*)((__half*)o2 + row * 1024 + c) = *(uint2*)ls;
    } else {
        *(float4*)((float*)o1 + row * 1024 + c) = make_float4(y[0], y[1], y[2], y[3]);
        __half hs[4];
#pragma unroll
        for (int m = 0; m < 4; ++m) hs[m] = __float2half(y[m]);
        *(uint2*)((__half*)o2 + row * 1024 + c) = *(uint2*)hs;
    }
}

// ---------- RoPE cos/sin table ----------
__global__ __launch_bounds__(256) void k_rope_table(float* __restrict__ ct, float* __restrict__ st)
{
    int idx = blockIdx.x * 256 + threadIdx.x; // 32768 = 1024 t x 32 i
    int t = idx >> 5, i = idx & 31;
    float inv = 1.0f / (float)pow(10000.0, (double)i / 32.0);
    float ang = (float)t * inv;
    ct[idx] = cosf(ang);
    st[idx] = sinf(ang);
}

// ---------- gating: fp32 scores, top-2, no global atomics ----------
__global__ __launch_bounds__(256) void k_gate(const float* __restrict__ xn2,
    const float* __restrict__ gw, const float* __restrict__ eb,
    int* __restrict__ topidx, float* __restrict__ gates,
    float* __restrict__ pprob)
{
    __shared__ float pp[4][8];
    const int lane = threadIdx.x & 63, w = threadIdx.x >> 6;
    const int t = blockIdx.x * 4 + w;
    const float* xr = xn2 + (long)t * 1024;
    float sc[8] = {0, 0, 0, 0, 0, 0, 0, 0};
#pragma unroll
    for (int i = 0; i < 4; ++i) {
        int d = i * 256 + lane * 4;
        float4 xv = *(const float4*)(xr + d);
        float xa[4] = {xv.x, xv.y, xv.z, xv.w};
#pragma unroll
        for (int j = 0; j < 4; ++j) {
            float xx = xa[j];
            const float4* gp = (const float4*)(gw + (long)(d + j) * 8);
            float4 g0 = gp[0], g1 = gp[1];
            sc[0] += xx * g0.x; sc[1] += xx * g0.y; sc[2] += xx * g0.z; sc[3] += xx * g0.w;
            sc[4] += xx * g1.x; sc[5] += xx * g1.y; sc[6] += xx * g1.z; sc[7] += xx * g1.w;
        }
    }
#pragma unroll
    for (int e = 0; e < 8; ++e) {
#pragma unroll
        for (int m = 32; m; m >>= 1) sc[e] += __shfl_xor(sc[e], m);
        sc[e] += eb[e];
    }
    if (lane == 0) {
        int i1 = 0; float v1 = sc[0];
        for (int e = 1; e < 8; ++e) if (sc[e] > v1) { v1 = sc[e]; i1 = e; }
        int i2 = (i1 == 0) ? 1 : 0; float v2 = sc[i2];
        for (int e = 0; e < 8; ++e) if (e != i1 && sc[e] > v2) { v2 = sc[e]; i2 = e; }
        float e2 = expf(v2 - v1);
        gates[t * 2] = 1.0f / (1.0f + e2);
        gates[t * 2 + 1] = e2 / (1.0f + e2);
        topidx[t * 2] = i1; topidx[t * 2 + 1] = i2;
        float mxx = sc[0];
        for (int e = 1; e < 8; ++e) mxx = fmaxf(mxx, sc[e]);
        float se = 0.0f, pe[8];
        for (int e = 0; e < 8; ++e) { pe[e] = expf(sc[e] - mxx); se += pe[e]; }
        float inv = 1.0f / se;
        for (int e = 0; e < 8; ++e) pp[w][e] = pe[e] * inv;
    }
    __syncthreads();
    if (threadIdx.x < 8)
        pprob[(long)blockIdx.x * 8 + threadIdx.x] =
            pp[0][threadIdx.x] + pp[1][threadIdx.x] + pp[2][threadIdx.x] + pp[3][threadIdx.x];
}

// ---------- routing: desc[] emitted round-robin over experts so that
// desc index i -> expert ~i%8 -> XCD i%8 (gridX % 8 == 0) ----------
__global__ __launch_bounds__(256) void k_route(const int* __restrict__ topidx,
    int* __restrict__ rowidx, int* __restrict__ invpos,
    int* __restrict__ ntiles, Desc* __restrict__ desc, int* __restrict__ cnt)
{
    __shared__ int cnt_s[8], base_s[8], fill[8];
    const int tid = threadIdx.x;
    if (tid < 8) { cnt_s[tid] = 0; fill[tid] = 0; }
    __syncthreads();
    for (int i = tid; i < 4096; i += 256)
        atomicAdd(&cnt_s[topidx[i]], 1);
    __syncthreads();
    if (tid == 0) {
        int tl[8]; int running = 0, maxT = 0;
        for (int e = 0; e < 8; ++e) {
            int ce = cnt_s[e];
            cnt[e] = ce;
            base_s[e] = running;
            tl[e] = (ce + 127) >> 7;
            running += tl[e] * 128;
            if (tl[e] > maxT) maxT = tl[e];
        }
        int nt = 0;
        for (int r = 0; r < maxT; ++r)
            for (int e = 0; e < 8; ++e)
                if (r < tl[e]) {
                    desc[nt].e = e;
                    desc[nt].base = base_s[e] + r * 128;
                    desc[nt].rows = min(128, cnt_s[e] - r * 128);
                    ++nt;
                }
        *ntiles = nt;
    }
    __syncthreads();
    for (int t = tid; t < 2048; t += 256) {
#pragma unroll
        for (int s = 0; s < 2; ++s) {
            int e = topidx[t * 2 + s];
            int p = base_s[e] + atomicAdd(&fill[e], 1);
            rowidx[p] = t;
            invpos[t * 2 + s] = p;
        }
    }
}

// ---------- combine ----------
__global__ __launch_bounds__(256) void k_combine(const float* __restrict__ x1,
    const float* __restrict__ eo, const int* __restrict__ invpos,
    const float* __restrict__ gates, float* __restrict__ out)
{
    const int t = blockIdx.x, c = threadIdx.x * 4;
    float g0 = gates[t * 2], g1 = gates[t * 2 + 1];
    int p0 = invpos[t * 2], p1 = invpos[t * 2 + 1];
    float4 xv = *(const float4*)(x1 + (long)t * 1024 + c);
    float4 e0 = *(const float4*)(eo + (long)p0 * 1024 + c);
    float4 e1 = *(const float4*)(eo + (long)p1 * 1024 + c);
    float4 o;
    o.x = xv.x + g0 * e0.x + g1 * e1.x;
    o.y = xv.y + g0 * e0.y + g1 * e1.y;
    o.z = xv.z + g0 * e0.z + g1 * e1.z;
    o.w = xv.w + g0 * e0.w + g1 * e1.w;
    *(float4*)(out + (long)t * 1024 + c) = o;
}

// ---------- loss ----------
__global__ __launch_bounds__(256) void k_loss(const int* __restrict__ cnt,
    const float* __restrict__ pprob, float* __restrict__ out)
{
    __shared__ float m[32][8];
    const int tid = threadIdx.x;
    const int e = tid & 7, g = tid >> 3;
    float local = 0.0f;
    for (int b = g; b < 512; b += 32) local += pprob[b * 8 + e];
    m[g][e] = local;
    __syncthreads();
    if (tid == 0) {
        float us = 0, ps = 0, pe[8], ue[8];
        for (int ee = 0; ee < 8; ++ee) {
            float s = 0;
            for (int gg = 0; gg < 32; ++gg) s += m[gg][ee];
            pe[ee] = s; ps += s;
            ue[ee] = (float)cnt[ee]; us += ue[ee];
        }
        float lb = 0;
        for (int ee = 0; ee < 8; ++ee) lb += (ue[ee] / us) * (pe[ee] / ps);
        out[2097152] = lb * 8.0f;
    }
}

// =====================  launch  =====================
extern "C" void kernel_launch(void* const* d_in, const int* in_sizes, int n_in,
                              void* d_out, int out_size, void* d_ws, size_t ws_size,
                              hipStream_t stream)
{
    const float* x    = (const float*)d_in[0];
    const float* ln1g = (const float*)d_in[1];
    const float* ln1b = (const float*)d_in[2];
    const float* qkvw = (const float*)d_in[3];
    const float* outw = (const float*)d_in[4];
    const float* ln2g = (const float*)d_in[5];
    const float* ln2b = (const float*)d_in[6];
    const float* gw   = (const float*)d_in[7];
    const float* eb   = (const float*)d_in[8];
    const float* w1   = (const float*)d_in[9];
    const float* w2   = (const float*)d_in[10];
    float* out = (float*)d_out;
    char* ws = (char*)d_ws;

    // workspace map (bytes), total ~222 MB
    constexpr size_t OFF_QWTH = 0;          // half [3072][1024]
    constexpr size_t OFF_QWTL = 6291456;
    constexpr size_t OFF_OWTH = 12582912;   // half [1024][1024]
    constexpr size_t OFF_OWTL = 14680064;
    constexpr size_t OFF_XN1H = 16777216;   // half [2048][1024]
    constexpr size_t OFF_XN1L = 20971520;
    constexpr size_t OFF_QH   = 25165824;   // half [32][1024][64]
    constexpr size_t OFF_QL   = 29360128;
    constexpr size_t OFF_KH   = 33554432;
    constexpr size_t OFF_KL   = 37748736;
    constexpr size_t OFF_VTH  = 41943040;   // half [32][64][1024]
    constexpr size_t OFF_VTL  = 46137344;
    constexpr size_t OFF_OH   = 50331648;   // half [2048][1024]
    constexpr size_t OFF_OL   = 54525952;
    constexpr size_t OFF_X1   = 58720256;   // f32 [2048][1024]
    constexpr size_t OFF_XN2F = 67108864;   // f32
    constexpr size_t OFF_XN2H = 75497472;   // half
    constexpr size_t OFF_RC   = 79691776;   // f32 [1024][32]
    constexpr size_t OFF_RS   = 79822848;
    constexpr size_t OFF_IDX  = 79953920;   // int [2048][2]
    constexpr size_t OFF_GATES= 79970304;   // f32 [2048][2]
    constexpr size_t OFF_INVP = 79986688;   // int [2048][2]
    constexpr size_t OFF_ROWI = 80003072;   // int [5120]
    constexpr size_t OFF_CNT  = 80023552;   // int [8]
    constexpr size_t OFF_NT   = 80023616;   // int
    constexpr size_t OFF_DESC = 80023680;   // Desc [40]
    constexpr size_t OFF_PPROB= 80024704;   // f32 [512][8]
    constexpr size_t OFF_ACT  = 80041984;   // half [5120][2048]
    constexpr size_t OFF_EO   = 101013504;  // f32 [5120][1024]
    constexpr size_t OFF_W1T  = 121985024;  // half [8][4096][1024]
    constexpr size_t OFF_W2T  = 189093888;  // half [8][1024][2048]

    __half* qwth = (__half*)(ws + OFF_QWTH);
    __half* qwtl = (__half*)(ws + OFF_QWTL);
    __half* owth = (__half*)(ws + OFF_OWTH);
    __half* owtl = (__half*)(ws + OFF_OWTL);
    __half* xn1h = (__half*)(ws + OFF_XN1H);
    __half* xn1l = (__half*)(ws + OFF_XN1L);
    __half* qh   = (__half*)(ws + OFF_QH);
    __half* ql   = (__half*)(ws + OFF_QL);
    __half* kh   = (__half*)(ws + OFF_KH);
    __half* kl   = (__half*)(ws + OFF_KL);
    __half* vth  = (__half*)(ws + OFF_VTH);
    __half* vtl  = (__half*)(ws + OFF_VTL);
    __half* oh   = (__half*)(ws + OFF_OH);
    __half* ol   = (__half*)(ws + OFF_OL);
    float* x1    = (float*)(ws + OFF_X1);
    float* xn2f  = (float*)(ws + OFF_XN2F);
    __half* xn2h = (__half*)(ws + OFF_XN2H);
    float* rc    = (float*)(ws + OFF_RC);
    float* rs    = (float*)(ws + OFF_RS);
    int*   idx   = (int*)(ws + OFF_IDX);
    float* gates = (float*)(ws + OFF_GATES);
    int*   invp  = (int*)(ws + OFF_INVP);
    int*   rowi  = (int*)(ws + OFF_ROWI);
    int*   cnt   = (int*)(ws + OFF_CNT);
    int*   nt    = (int*)(ws + OFF_NT);
    Desc*  desc  = (Desc*)(ws + OFF_DESC);
    float* pprob = (float*)(ws + OFF_PPROB);
    __half* act  = (__half*)(ws + OFF_ACT);
    float* eo    = (float*)(ws + OFF_EO);
    __half* w1t  = (__half*)(ws + OFF_W1T);
    __half* w2t  = (__half*)(ws + OFF_W2T);

    // weight transposes -> split planes (attention) / plain fp16 (MoE)
    k_transpose_pk<<<dim3(48, 16, 1), 256, 0, stream>>>(qkvw, qwth, qwtl, 1024, 3072);
    k_transpose_pk<<<dim3(16, 16, 1), 256, 0, stream>>>(outw, owth, owtl, 1024, 1024);
    k_wconv<<<dim3(64, 16, 8), 256, 0, stream>>>(w1, w1t, 1024, 4096);
    k_wconv<<<dim3(16, 32, 8), 256, 0, stream>>>(w2, w2t, 2048, 1024);
    k_rope_table<<<dim3(128), 256, 0, stream>>>(rc, rs);

    // LN1 -> xn1 planes
    k_ln<0><<<dim3(2048), 256, 0, stream>>>(x, ln1g, ln1b, xn1h, xn1l);

    // QKV GEMM with fused RoPE + q/k/v scatter (64x128 tiles, 768 blocks)
    k_gemm_pk<2, 2, 2, 4, EPI_QKV><<<dim3(32, 24, 1), 256, 0, stream>>>(
        xn1h, xn1l, 1024, qwth, qwtl, 1024, nullptr, 0, 2048, 3072, 1024,
        nullptr, qh, ql, kh, kl, vth, vtl, rc, rs);

    // flash attention -> o planes
    k_flash<<<dim3(16, 32, 1), 256, 0, stream>>>(qh, ql, kh, kl, vth, vtl, oh, ol);

    // x1 = x + o @ out_w
    k_gemm_pk<2, 2, 2, 2, EPI_RESID><<<dim3(32, 16, 1), 256, 0, stream>>>(
        oh, ol, 1024, owth, owtl, 1024, x1, 1024, 2048, 1024, 1024,
        x, nullptr, nullptr, nullptr, nullptr, nullptr, nullptr, nullptr, nullptr);

    // LN2 -> xn2 (f32 for gating, fp16 for MoE)
    k_ln<1><<<dim3(2048), 256, 0, stream>>>(x1, ln2g, ln2b, xn2f, xn2h);

    // gating + routing
    k_gate<<<dim3(512), 256, 0, stream>>>(xn2f, gw, eb, idx, gates, pprob);
    k_route<<<dim3(1), 256, 0, stream>>>(idx, rowi, invp, nt, desc, cnt);

    // MoE GEMM1: act = silu(h1)*h2, 128x128 tiles, expert->XCD affinity
    k_gemm_moe<true, 0, 4, 4, 2><<<dim3(40, 32, 1), 256, 0, stream>>>(
        xn2h, 1024, rowi, desc, nt, w1t, 4194304, 1024, act, 1024);

    // MoE GEMM2: eo = act @ w2[e], 128x64 tiles -> 640 blocks
    k_gemm_moe<false, 1, 2, 4, 1><<<dim3(40, 16, 1), 256, 0, stream>>>(
        act, 2048, nullptr, desc, nt, w2t, 2097152, 2048, eo, 2048);

    // combine + loss
    k_combine<<<dim3(2048), 256, 0, stream>>>(x1, eo, invp, gates, out);
    k_loss<<<dim3(1), 256, 0, stream>>>(cnt, pprob, out);
}